// Round 3
// baseline (1934.538 us; speedup 1.0000x reference)
//
#include <hip/hip_runtime.h>

typedef __attribute__((ext_vector_type(8))) short short8;
typedef __attribute__((ext_vector_type(4))) short short4v;
typedef __attribute__((ext_vector_type(4))) float f32x4;

__device__ __forceinline__ unsigned short f2bf(float f) {
  union { float f; unsigned u; } v; v.f = f;
  unsigned r = v.u + 0x7FFFu + ((v.u >> 16) & 1u);
  return (unsigned short)(r >> 16);
}

__device__ __forceinline__ void gload16(const void* g, void* l) {
  __builtin_amdgcn_global_load_lds(
      (const __attribute__((address_space(1))) void*)g,
      (__attribute__((address_space(3))) void*)l, 16, 0, 0);
}

// ---------------------------------------------------------------------------
// Kernel 0: x (fp32) -> x_bf16, vectorized 8 elems/thread
// ---------------------------------------------------------------------------
__global__ __launch_bounds__(256) void conv_x(const float* __restrict__ x,
                                              unsigned short* __restrict__ xb) {
  const long total = 25165824;                        // 201326592 / 8
  long stride = (long)gridDim.x * 256;
  for (long u = blockIdx.x * 256 + threadIdx.x; u < total; u += stride) {
    const float* p = x + u * 8;
    float4 a = *(const float4*)p;
    float4 b = *(const float4*)(p + 4);
    short8 h;
    h[0] = (short)f2bf(a.x); h[1] = (short)f2bf(a.y);
    h[2] = (short)f2bf(a.z); h[3] = (short)f2bf(a.w);
    h[4] = (short)f2bf(b.x); h[5] = (short)f2bf(b.y);
    h[6] = (short)f2bf(b.z); h[7] = (short)f2bf(b.w);
    *(short8*)(xb + u * 8) = h;
  }
}

// ---------------------------------------------------------------------------
// Kernel 1: Wt[n][k] = bf16( [Wk | Wv](k, n) )   (B^T layout, n in [0,1536))
// ---------------------------------------------------------------------------
__global__ __launch_bounds__(256) void prep_w(const float* __restrict__ Wk,
                                              const float* __restrict__ Wv,
                                              unsigned short* __restrict__ Wt) {
  int idx = blockIdx.x * 256 + threadIdx.x;           // 1536*768 elements
  int n = idx / 768, k = idx - n * 768;
  float w = (n < 768) ? Wk[k * 768 + n] : Wv[k * 768 + (n - 768)];
  Wt[idx] = f2bf(w);
}

// ---------------------------------------------------------------------------
// Kernel 2: q = scale * x[:, :10] @ Wq  -> q_ws[b][h][16][64] bf16 (rows 10..15 = 0)
// ---------------------------------------------------------------------------
__global__ __launch_bounds__(256) void q_proj(const float* __restrict__ x,
                                              const float* __restrict__ Wq,
                                              unsigned short* __restrict__ q_ws) {
  int b = blockIdx.x, tid = threadIdx.x;
  __shared__ float xr[7680];
  const float* xp = x + (long)b * 4096 * 768;
  for (int i = tid; i < 7680; i += 256) xr[i] = xp[i];
  for (int i = tid; i < 12 * 6 * 64; i += 256) {
    int h = i / 384, rem = i - h * 384;
    int t = 10 + rem / 64, d = rem & 63;
    q_ws[(((long)(b * 12 + h) * 16 + t) << 6) + d] = 0;
  }
  __syncthreads();
  float acc[10][3];
#pragma unroll
  for (int t = 0; t < 10; ++t) { acc[t][0] = 0.f; acc[t][1] = 0.f; acc[t][2] = 0.f; }
  for (int k = 0; k < 768; ++k) {
    const float* wr = Wq + (long)k * 768;
    float w0 = wr[tid], w1 = wr[tid + 256], w2 = wr[tid + 512];
#pragma unroll
    for (int t = 0; t < 10; ++t) {
      float xv = xr[t * 768 + k];
      acc[t][0] += xv * w0; acc[t][1] += xv * w1; acc[t][2] += xv * w2;
    }
  }
#pragma unroll
  for (int t = 0; t < 10; ++t) {
#pragma unroll
    for (int j = 0; j < 3; ++j) {
      int c = tid + j * 256;
      int h = c >> 6, d = c & 63;
      q_ws[(((long)(b * 12 + h) * 16 + t) << 6) + d] = f2bf(acc[t][j] * 0.125f);
    }
  }
}

// ---------------------------------------------------------------------------
// Kernel 3 (R3): 128x128 tile, BK=32, DOUBLE-buffered gload_lds with
// issue-early staging (1 barrier / K-step) + involution-swizzled LDS chunks
// (linear LDS dest, pre-swizzled global source, swizzled frag reads).
// ---------------------------------------------------------------------------
__global__ __launch_bounds__(256) void gemm_kv3(const unsigned short* __restrict__ xb,
                                                const unsigned short* __restrict__ Wt,
                                                unsigned short* __restrict__ k_ws,
                                                float* __restrict__ v_out) {
  __shared__ unsigned short Asm[2][4096];             // [buf][128 rows * 32 k]
  __shared__ unsigned short Bsm[2][4096];
  int bid = blockIdx.x;
  int lb = (bid & 7) * 3072 + (bid >> 3);             // XCD swizzle (24576 % 8 == 0)
  int mt = lb / 12, nt = lb - mt * 12;
  long m0 = (long)mt * 128; int n0 = nt * 128;
  int tid = threadIdx.x, lane = tid & 63;
  int uw = __builtin_amdgcn_readfirstlane(tid >> 6);  // uniform wave id
  int wm = uw >> 1, wn = uw & 1;
  int r16 = lane & 15, gk = lane >> 4;

  const unsigned short* xs = xb + m0 * 768;
  const unsigned short* wp = Wt + (long)n0 * 768;

  int srow = lane >> 2;                               // row within 16-row chunk
  int sg = ((lane & 3) ^ ((srow >> 1) & 3)) << 3;     // swizzled SOURCE chunk (elems)
  int sw = (gk ^ ((r16 >> 1) & 3)) << 3;              // swizzled READ chunk (elems)

  f32x4 acc[4][4];
#pragma unroll
  for (int i = 0; i < 4; ++i)
#pragma unroll
    for (int j = 0; j < 4; ++j) acc[i][j] = (f32x4){0.f, 0.f, 0.f, 0.f};

  // prologue: stage K-tile 0 into buf 0
  {
    int kb = 0;
#pragma unroll
    for (int i = 0; i < 2; ++i) {
      int c = i * 4 + uw;
      gload16(xs + (long)(c * 16 + srow) * 768 + kb + sg, &Asm[0][c * 512]);
      gload16(wp + (long)(c * 16 + srow) * 768 + kb + sg, &Bsm[0][c * 512]);
    }
  }
  __syncthreads();

  for (int ks = 0; ks < 24; ++ks) {
    int cur = ks & 1;
    if (ks + 1 < 24) {                                // issue next tile EARLY
      int kb = (ks + 1) * 32;
#pragma unroll
      for (int i = 0; i < 2; ++i) {
        int c = i * 4 + uw;
        gload16(xs + (long)(c * 16 + srow) * 768 + kb + sg, &Asm[cur ^ 1][c * 512]);
        gload16(wp + (long)(c * 16 + srow) * 768 + kb + sg, &Bsm[cur ^ 1][c * 512]);
      }
    }
    short8 af[4], bfr[4];
#pragma unroll
    for (int mi = 0; mi < 4; ++mi)
      af[mi] = *(const short8*)&Asm[cur][(wm * 64 + mi * 16 + r16) * 32 + sw];
#pragma unroll
    for (int ni = 0; ni < 4; ++ni)
      bfr[ni] = *(const short8*)&Bsm[cur][(wn * 64 + ni * 16 + r16) * 32 + sw];
#pragma unroll
    for (int mi = 0; mi < 4; ++mi)
#pragma unroll
      for (int ni = 0; ni < 4; ++ni)
        acc[mi][ni] = __builtin_amdgcn_mfma_f32_16x16x32_bf16(af[mi], bfr[ni], acc[mi][ni], 0, 0, 0);
    __syncthreads();                                  // drains stage; buf[cur^1] ready
  }

  // ---- epilogue: D col = lane&15, row = (lane>>4)*4 + r ----
  bool is_k = (n0 < 768);
  int cb = is_k ? n0 : n0 - 768;
#pragma unroll
  for (int ni = 0; ni < 4; ++ni) {
    int cc = cb + wn * 64 + ni * 16 + r16;
    int h = cc >> 6, d = cc & 63;
#pragma unroll
    for (int mi = 0; mi < 4; ++mi) {
#pragma unroll
      for (int r = 0; r < 4; ++r) {
        long m = m0 + wm * 64 + mi * 16 + gk * 4 + r;
        int b = (int)(m >> 12), n = (int)(m & 4095);
        long off = ((long)(b * 12 + h) * 4096 + n) * 64 + d;
        float val = acc[mi][ni][r];
        if (is_k) k_ws[off] = f2bf(val);
        else      v_out[off] = val;
      }
    }
  }
}

// ---------------------------------------------------------------------------
// Kernel 3-FALLBACK (R1 version, used when ws_size is too small)
// ---------------------------------------------------------------------------
__global__ __launch_bounds__(256) void gemm_kv(const float* __restrict__ x,
                                               const unsigned short* __restrict__ Wt,
                                               unsigned short* __restrict__ k_ws,
                                               float* __restrict__ v_out) {
  __shared__ char lds[32768];
  int bid = blockIdx.x;
  int lb = (bid & 7) * 3072 + (bid >> 3);
  int mt = lb / 12, nt = lb - mt * 12;
  long m0 = (long)mt * 128; int n0 = nt * 128;
  int tid = threadIdx.x, lane = tid & 63;
  int wid = tid >> 6, wm = wid >> 1, wn = wid & 1;
  int rlo = lane & 15, gk = lane >> 4;

  const float* xs = x + m0 * 768;
  const unsigned short* wp = Wt + (long)n0 * 768;

  int arow0 = tid >> 3, ak4 = (tid & 7) << 2;
  int bn = tid >> 1, bg = (tid & 1) << 1;

  f32x4 acc[4][4];
#pragma unroll
  for (int i = 0; i < 4; ++i)
#pragma unroll
    for (int j = 0; j < 4; ++j) acc[i][j] = (f32x4){0.f, 0.f, 0.f, 0.f};

  float4 fA[4]; short8 wB[2];
#pragma unroll
  for (int it = 0; it < 4; ++it) {
    int row = it * 32 + arow0;
    fA[it] = *(const float4*)(xs + (long)row * 768 + ak4);
  }
#pragma unroll
  for (int i = 0; i < 2; ++i)
    wB[i] = *(const short8*)(wp + (long)bn * 768 + (bg + i) * 8);
#pragma unroll
  for (int it = 0; it < 4; ++it) {
    int row = it * 32 + arow0;
    short4v h;
    h[0] = (short)f2bf(fA[it].x); h[1] = (short)f2bf(fA[it].y);
    h[2] = (short)f2bf(fA[it].z); h[3] = (short)f2bf(fA[it].w);
    *(short4v*)(lds + row * 64 + ((ak4 * 2) ^ (((row >> 1) & 3) << 4))) = h;
  }
#pragma unroll
  for (int i = 0; i < 2; ++i)
    *(short8*)(lds + 16384 + bn * 64 + (((bg + i) * 16) ^ (((bn >> 1) & 3) << 4))) = wB[i];
  __syncthreads();

#pragma unroll 2
  for (int ks = 0; ks < 24; ++ks) {
    char* Ab = lds + (ks & 1) * 8192;
    char* Bb = lds + 16384 + (ks & 1) * 8192;
    bool pf = (ks + 1 < 24);
    if (pf) {
#pragma unroll
      for (int it = 0; it < 4; ++it) {
        int row = it * 32 + arow0;
        fA[it] = *(const float4*)(xs + (long)row * 768 + (ks + 1) * 32 + ak4);
      }
#pragma unroll
      for (int i = 0; i < 2; ++i)
        wB[i] = *(const short8*)(wp + (long)bn * 768 + (ks + 1) * 32 + (bg + i) * 8);
    }
    short8 af[4], bfr[4];
#pragma unroll
    for (int mi = 0; mi < 4; ++mi) {
      int row = wm * 64 + mi * 16 + rlo;
      af[mi] = *(const short8*)(Ab + row * 64 + ((gk * 16) ^ (((row >> 1) & 3) << 4)));
    }
#pragma unroll
    for (int ni = 0; ni < 4; ++ni) {
      int n = wn * 64 + ni * 16 + rlo;
      bfr[ni] = *(const short8*)(Bb + n * 64 + ((gk * 16) ^ (((n >> 1) & 3) << 4)));
    }
#pragma unroll
    for (int mi = 0; mi < 4; ++mi)
#pragma unroll
      for (int ni = 0; ni < 4; ++ni)
        acc[mi][ni] = __builtin_amdgcn_mfma_f32_16x16x32_bf16(af[mi], bfr[ni], acc[mi][ni], 0, 0, 0);
    if (pf) {
      char* An = lds + ((ks + 1) & 1) * 8192;
      char* Bn = lds + 16384 + ((ks + 1) & 1) * 8192;
#pragma unroll
      for (int it = 0; it < 4; ++it) {
        int row = it * 32 + arow0;
        short4v h;
        h[0] = (short)f2bf(fA[it].x); h[1] = (short)f2bf(fA[it].y);
        h[2] = (short)f2bf(fA[it].z); h[3] = (short)f2bf(fA[it].w);
        *(short4v*)(An + row * 64 + ((ak4 * 2) ^ (((row >> 1) & 3) << 4))) = h;
      }
#pragma unroll
      for (int i = 0; i < 2; ++i)
        *(short8*)(Bn + bn * 64 + (((bg + i) * 16) ^ (((bn >> 1) & 3) << 4))) = wB[i];
    }
    __syncthreads();
  }

  bool is_k = (n0 < 768);
  int cb = is_k ? n0 : n0 - 768;
#pragma unroll
  for (int ni = 0; ni < 4; ++ni) {
    int cc = cb + wn * 64 + ni * 16 + rlo;
    int h = cc >> 6, d = cc & 63;
#pragma unroll
    for (int mi = 0; mi < 4; ++mi) {
#pragma unroll
      for (int r = 0; r < 4; ++r) {
        long m = m0 + wm * 64 + mi * 16 + gk * 4 + r;
        int b = (int)(m >> 12), n = (int)(m & 4095);
        long off = ((long)(b * 12 + h) * 4096 + n) * 64 + d;
        float val = acc[mi][ni][r];
        if (is_k) k_ws[off] = f2bf(val);
        else      v_out[off] = val;
      }
    }
  }
}

// ---------------------------------------------------------------------------
// Kernel 4: fused attention per (b,h). 512 threads / 8 waves.
// ---------------------------------------------------------------------------
__global__ __launch_bounds__(512) void attn_fused(const unsigned short* __restrict__ k_ws,
                                                  const unsigned short* __restrict__ q_ws,
                                                  const float* __restrict__ v_glob,
                                                  float* __restrict__ attn_out,
                                                  float* __restrict__ preproj) {
  __shared__ float red[8][16];
  __shared__ float rowmax[16];
  __shared__ float rowinv[16];
  __shared__ float scratch[8 * 256];

  int tid = threadIdx.x, lane = tid & 63, w = tid >> 6;
  int bh = blockIdx.x;
  int r16 = lane & 15, gk = lane >> 4;
  int trc = (r16 < 10) ? r16 : 9;

  const unsigned short* kp = k_ws + (long)bh * (4096 * 64);
  const unsigned short* qp = q_ws + (long)bh * 1024;
  float* sraw = attn_out + (long)bh * 40960;
  const float* vp = v_glob + (long)bh * (4096 * 64);

  short8 qf0 = *(const short8*)(qp + r16 * 64 + gk * 8);
  short8 qf1 = *(const short8*)(qp + r16 * 64 + 32 + gk * 8);

  // ---- Phase 1: scores + row max ----
  float pmax = -3.0e38f;
  for (int ch = 0; ch < 32; ++ch) {
    int n0 = (w * 32 + ch) << 4;
    short8 kf0 = *(const short8*)(kp + (long)(n0 + r16) * 64 + gk * 8);
    short8 kf1 = *(const short8*)(kp + (long)(n0 + r16) * 64 + 32 + gk * 8);
    f32x4 d4 = (f32x4){0.f, 0.f, 0.f, 0.f};
    d4 = __builtin_amdgcn_mfma_f32_16x16x32_bf16(kf0, qf0, d4, 0, 0, 0);
    d4 = __builtin_amdgcn_mfma_f32_16x16x32_bf16(kf1, qf1, d4, 0, 0, 0);
    float sv[4];
#pragma unroll
    for (int r = 0; r < 4; ++r) {
      int n = n0 + gk * 4 + r;
      float s = d4[r];
      if (n < 10 && n != r16) s = -1e30f;
      sv[r] = s;
      pmax = fmaxf(pmax, s);
    }
    if (r16 < 10)
      *(float4*)(sraw + r16 * 4096 + n0 + gk * 4) = make_float4(sv[0], sv[1], sv[2], sv[3]);
  }
  pmax = fmaxf(pmax, __shfl_xor(pmax, 16));
  pmax = fmaxf(pmax, __shfl_xor(pmax, 32));
  if (lane < 16) red[w][lane] = pmax;
  __syncthreads();
  if (tid < 16) {
    float m = red[0][tid];
#pragma unroll
    for (int i = 1; i < 8; ++i) m = fmaxf(m, red[i][tid]);
    rowmax[tid] = m;
  }
  __syncthreads();

  // ---- Phase 2: row sum ----
  float mx = rowmax[trc];
  float psum = 0.f;
  for (int ch = 0; ch < 16; ++ch) {
    int n0 = ((w * 16 + ch) << 5) + gk * 8;
    float4 a = *(const float4*)(sraw + trc * 4096 + n0);
    float4 b2 = *(const float4*)(sraw + trc * 4096 + n0 + 4);
    psum += __expf(a.x - mx) + __expf(a.y - mx) + __expf(a.z - mx) + __expf(a.w - mx)
          + __expf(b2.x - mx) + __expf(b2.y - mx) + __expf(b2.z - mx) + __expf(b2.w - mx);
  }
  psum += __shfl_xor(psum, 16);
  psum += __shfl_xor(psum, 32);
  if (lane < 16) red[w][lane] = psum;
  __syncthreads();
  if (tid < 16) {
    float s = 0.f;
#pragma unroll
    for (int i = 0; i < 8; ++i) s += red[i][tid];
    rowinv[tid] = 1.0f / s;
  }
  __syncthreads();

  // ---- Phase 3: PV ----
  int dc = w & 3, half = w >> 2;
  int d0 = dc << 4;
  float inv = rowinv[trc];
  f32x4 acc = (f32x4){0.f, 0.f, 0.f, 0.f};
  for (int kk = 0; kk < 64; ++kk) {
    int nr = half * 2048 + kk * 32 + gk * 8;
    float4 s0 = *(const float4*)(sraw + trc * 4096 + nr);
    float4 s1 = *(const float4*)(sraw + trc * 4096 + nr + 4);
    short8 pa;
    pa[0] = (short)f2bf(__expf(s0.x - mx) * inv);
    pa[1] = (short)f2bf(__expf(s0.y - mx) * inv);
    pa[2] = (short)f2bf(__expf(s0.z - mx) * inv);
    pa[3] = (short)f2bf(__expf(s0.w - mx) * inv);
    pa[4] = (short)f2bf(__expf(s1.x - mx) * inv);
    pa[5] = (short)f2bf(__expf(s1.y - mx) * inv);
    pa[6] = (short)f2bf(__expf(s1.z - mx) * inv);
    pa[7] = (short)f2bf(__expf(s1.w - mx) * inv);
    short8 vb;
    const float* vrow = vp + (long)nr * 64 + d0 + r16;
#pragma unroll
    for (int j = 0; j < 8; ++j) vb[j] = (short)f2bf(vrow[j * 64]);
    acc = __builtin_amdgcn_mfma_f32_16x16x32_bf16(pa, vb, acc, 0, 0, 0);
  }
#pragma unroll
  for (int r = 0; r < 4; ++r)
    scratch[w * 256 + (gk * 4 + r) * 16 + r16] = acc[r];
  __syncthreads();

  int b = bh / 12, h = bh - b * 12;
  for (int idx = tid; idx < 640; idx += 512) {
    int tt = idx >> 6, d = idx & 63;
    int c = d >> 4, dl = d & 15;
    float s = scratch[c * 256 + tt * 16 + dl] + scratch[(c + 4) * 256 + tt * 16 + dl];
    preproj[((long)b * 10 + tt) * 768 + h * 64 + d] = s;
  }

  // ---- Phase 4: normalize raw scores in place ----
  if (r16 < 10) {
    for (int ch = 0; ch < 16; ++ch) {
      int nn = ((w * 16 + ch) << 5) + gk * 8;
      float* sp = sraw + r16 * 4096 + nn;
      float4 a = *(const float4*)(sp);
      float4 b2 = *(const float4*)(sp + 4);
      a.x = __expf(a.x - mx) * inv;  a.y = __expf(a.y - mx) * inv;
      a.z = __expf(a.z - mx) * inv;  a.w = __expf(a.w - mx) * inv;
      b2.x = __expf(b2.x - mx) * inv; b2.y = __expf(b2.y - mx) * inv;
      b2.z = __expf(b2.z - mx) * inv; b2.w = __expf(b2.w - mx) * inv;
      *(float4*)(sp) = a;
      *(float4*)(sp + 4) = b2;
    }
  }
}

// ---------------------------------------------------------------------------
// Kernel 5: x_cls = preproj @ Wp + bp
// ---------------------------------------------------------------------------
__global__ __launch_bounds__(256) void proj_out_k(const float* __restrict__ preproj,
                                                  const float* __restrict__ Wp,
                                                  const float* __restrict__ bp,
                                                  float* __restrict__ out0) {
  int b = blockIdx.x, tid = threadIdx.x;
  __shared__ float xr[7680];
  const float* pp = preproj + (long)b * 7680;
  for (int i = tid; i < 7680; i += 256) xr[i] = pp[i];
  __syncthreads();
  float acc[10][3];
#pragma unroll
  for (int t = 0; t < 10; ++t) { acc[t][0] = 0.f; acc[t][1] = 0.f; acc[t][2] = 0.f; }
  for (int k = 0; k < 768; ++k) {
    const float* wr = Wp + (long)k * 768;
    float w0 = wr[tid], w1 = wr[tid + 256], w2 = wr[tid + 512];
#pragma unroll
    for (int t = 0; t < 10; ++t) {
      float xv = xr[t * 768 + k];
      acc[t][0] += xv * w0; acc[t][1] += xv * w1; acc[t][2] += xv * w2;
    }
  }
  float b0 = bp[tid], b1 = bp[tid + 256], b2 = bp[tid + 512];
  float* op = out0 + (long)b * 7680;
#pragma unroll
  for (int t = 0; t < 10; ++t) {
    op[t * 768 + tid]       = acc[t][0] + b0;
    op[t * 768 + tid + 256] = acc[t][1] + b1;
    op[t * 768 + tid + 512] = acc[t][2] + b2;
  }
}

// ---------------------------------------------------------------------------
extern "C" void kernel_launch(void* const* d_in, const int* in_sizes, int n_in,
                              void* d_out, int out_size, void* d_ws, size_t ws_size,
                              hipStream_t stream) {
  (void)in_sizes; (void)n_in; (void)out_size;
  const float* x  = (const float*)d_in[0];
  const float* Wq = (const float*)d_in[1];
  const float* Wk = (const float*)d_in[2];
  const float* Wv = (const float*)d_in[3];
  const float* Wp = (const float*)d_in[4];
  const float* bp = (const float*)d_in[5];

  float* out      = (float*)d_out;
  float* attn_out = out + 491520;                 // [64,12,10,4096]
  float* v_out    = out + 31948800;               // [64,12,4096,64]

  char* ws = (char*)d_ws;
  const size_t NEED_BIG = 811204608;              // x_bf16 + k_ws + small

  if (ws_size >= NEED_BIG) {
    unsigned short* x_bf16 = (unsigned short*)(ws);               // 402,653,184 B
    unsigned short* k_ws = (unsigned short*)(ws + 402653184);     // 402,653,184 B
    unsigned short* q_ws = (unsigned short*)(ws + 805306368);     //   1,572,864 B
    unsigned short* Wt   = (unsigned short*)(ws + 806879232);     //   2,359,296 B
    float* preproj       = (float*)(ws + 809238528);              //   1,966,080 B

    conv_x<<<dim3(2048), dim3(256), 0, stream>>>(x, x_bf16);
    prep_w<<<dim3(4608), dim3(256), 0, stream>>>(Wk, Wv, Wt);
    q_proj<<<dim3(64), dim3(256), 0, stream>>>(x, Wq, q_ws);
    gemm_kv3<<<dim3(24576), dim3(256), 0, stream>>>(x_bf16, Wt, k_ws, v_out);
    attn_fused<<<dim3(768), dim3(512), 0, stream>>>(k_ws, q_ws, v_out, attn_out, preproj);
    proj_out_k<<<dim3(64), dim3(256), 0, stream>>>(preproj, Wp, bp, out);
  } else {
    unsigned short* k_ws = (unsigned short*)(ws);                 // 402,653,184 B
    unsigned short* q_ws = (unsigned short*)(ws + 402653184);
    unsigned short* Wt   = (unsigned short*)(ws + 404226048);
    float* preproj       = (float*)(ws + 406585344);

    prep_w<<<dim3(4608), dim3(256), 0, stream>>>(Wk, Wv, Wt);
    q_proj<<<dim3(64), dim3(256), 0, stream>>>(x, Wq, q_ws);
    gemm_kv<<<dim3(24576), dim3(256), 0, stream>>>(x, Wt, k_ws, v_out);
    attn_fused<<<dim3(768), dim3(512), 0, stream>>>(k_ws, q_ws, v_out, attn_out, preproj);
    proj_out_k<<<dim3(64), dim3(256), 0, stream>>>(preproj, Wp, bp, out);
  }
}

// Round 4
// 1864.789 us; speedup vs baseline: 1.0374x; 1.0374x over previous
//
#include <hip/hip_runtime.h>

typedef __attribute__((ext_vector_type(8))) short short8;
typedef __attribute__((ext_vector_type(4))) short short4v;
typedef __attribute__((ext_vector_type(4))) float f32x4;

__device__ __forceinline__ unsigned short f2bf(float f) {
  union { float f; unsigned u; } v; v.f = f;
  unsigned r = v.u + 0x7FFFu + ((v.u >> 16) & 1u);
  return (unsigned short)(r >> 16);
}

__device__ __forceinline__ void gload16(const void* g, void* l) {
  __builtin_amdgcn_global_load_lds(
      (const __attribute__((address_space(1))) void*)g,
      (__attribute__((address_space(3))) void*)l, 16, 0, 0);
}

// ---------------------------------------------------------------------------
// Kernel 0: x (fp32) -> x_bf16, vectorized 8 elems/thread
// ---------------------------------------------------------------------------
__global__ __launch_bounds__(256) void conv_x(const float* __restrict__ x,
                                              unsigned short* __restrict__ xb) {
  const long total = 25165824;                        // 201326592 / 8
  long stride = (long)gridDim.x * 256;
  for (long u = blockIdx.x * 256 + threadIdx.x; u < total; u += stride) {
    const float* p = x + u * 8;
    float4 a = *(const float4*)p;
    float4 b = *(const float4*)(p + 4);
    short8 h;
    h[0] = (short)f2bf(a.x); h[1] = (short)f2bf(a.y);
    h[2] = (short)f2bf(a.z); h[3] = (short)f2bf(a.w);
    h[4] = (short)f2bf(b.x); h[5] = (short)f2bf(b.y);
    h[6] = (short)f2bf(b.z); h[7] = (short)f2bf(b.w);
    *(short8*)(xb + u * 8) = h;
  }
}

// ---------------------------------------------------------------------------
// Kernel 1: Wt[n][k] = bf16( [Wk | Wv](k, n) )   (B^T layout, n in [0,1536))
// ---------------------------------------------------------------------------
__global__ __launch_bounds__(256) void prep_w(const float* __restrict__ Wk,
                                              const float* __restrict__ Wv,
                                              unsigned short* __restrict__ Wt) {
  int idx = blockIdx.x * 256 + threadIdx.x;           // 1536*768 elements
  int n = idx / 768, k = idx - n * 768;
  float w = (n < 768) ? Wk[k * 768 + n] : Wv[k * 768 + (n - 768)];
  Wt[idx] = f2bf(w);
}

// ---------------------------------------------------------------------------
// Kernel 2: q = scale * x[:, :10] @ Wq  -> q_ws[b][h][16][64] bf16 (rows 10..15 = 0)
// ---------------------------------------------------------------------------
__global__ __launch_bounds__(256) void q_proj(const float* __restrict__ x,
                                              const float* __restrict__ Wq,
                                              unsigned short* __restrict__ q_ws) {
  int b = blockIdx.x, tid = threadIdx.x;
  __shared__ float xr[7680];
  const float* xp = x + (long)b * 4096 * 768;
  for (int i = tid; i < 7680; i += 256) xr[i] = xp[i];
  for (int i = tid; i < 12 * 6 * 64; i += 256) {
    int h = i / 384, rem = i - h * 384;
    int t = 10 + rem / 64, d = rem & 63;
    q_ws[(((long)(b * 12 + h) * 16 + t) << 6) + d] = 0;
  }
  __syncthreads();
  float acc[10][3];
#pragma unroll
  for (int t = 0; t < 10; ++t) { acc[t][0] = 0.f; acc[t][1] = 0.f; acc[t][2] = 0.f; }
  for (int k = 0; k < 768; ++k) {
    const float* wr = Wq + (long)k * 768;
    float w0 = wr[tid], w1 = wr[tid + 256], w2 = wr[tid + 512];
#pragma unroll
    for (int t = 0; t < 10; ++t) {
      float xv = xr[t * 768 + k];
      acc[t][0] += xv * w0; acc[t][1] += xv * w1; acc[t][2] += xv * w2;
    }
  }
#pragma unroll
  for (int t = 0; t < 10; ++t) {
#pragma unroll
    for (int j = 0; j < 3; ++j) {
      int c = tid + j * 256;
      int h = c >> 6, d = c & 63;
      q_ws[(((long)(b * 12 + h) * 16 + t) << 6) + d] = f2bf(acc[t][j] * 0.125f);
    }
  }
}

// ---------------------------------------------------------------------------
// Kernel 3 (R4): 128x128 tile, BK=32. Double-buffer via FOUR static LDS
// arrays (compile-time bases), issue-early gload_lds staging, ONE barrier
// per K-step, involution-swizzled chunks.
// ---------------------------------------------------------------------------
__global__ __launch_bounds__(256) void gemm_kv4(const unsigned short* __restrict__ xb,
                                                const unsigned short* __restrict__ Wt,
                                                unsigned short* __restrict__ k_ws,
                                                float* __restrict__ v_out) {
  __shared__ unsigned short A0[4096];                 // 8 KB each
  __shared__ unsigned short A1[4096];
  __shared__ unsigned short B0[4096];
  __shared__ unsigned short B1[4096];
  int bid = blockIdx.x;
  int lb = (bid & 7) * 3072 + (bid >> 3);             // XCD swizzle (24576 % 8 == 0)
  int mt = lb / 12, nt = lb - mt * 12;
  long m0 = (long)mt * 128; int n0 = nt * 128;
  int tid = threadIdx.x, lane = tid & 63;
  int uw = __builtin_amdgcn_readfirstlane(tid >> 6);  // uniform wave id
  int wm = uw >> 1, wn = uw & 1;
  int r16 = lane & 15, gk = lane >> 4;

  const unsigned short* xs = xb + m0 * 768;
  const unsigned short* wp = Wt + (long)n0 * 768;

  int srow = lane >> 2;                               // row within 16-row chunk
  int sg = ((lane & 3) ^ ((srow >> 1) & 3)) << 3;     // swizzled SOURCE chunk (elems)
  int sw = (gk ^ ((r16 >> 1) & 3)) << 3;              // swizzled READ chunk (elems)

  int c0 = uw, c1 = uw + 4;                           // this wave's two 16-row chunks
  long ga0 = (long)(c0 * 16 + srow) * 768 + sg;
  long ga1 = (long)(c1 * 16 + srow) * 768 + sg;

  f32x4 acc[4][4];
#pragma unroll
  for (int i = 0; i < 4; ++i)
#pragma unroll
    for (int j = 0; j < 4; ++j) acc[i][j] = (f32x4){0.f, 0.f, 0.f, 0.f};

  // prologue: stage K-tile 0 into buf 0
  gload16(xs + ga0, &A0[c0 * 512]);
  gload16(xs + ga1, &A0[c1 * 512]);
  gload16(wp + ga0, &B0[c0 * 512]);
  gload16(wp + ga1, &B0[c1 * 512]);
  __syncthreads();

#define FRAGS_MFMA(Abuf, Bbuf)                                                  \
  {                                                                             \
    short8 af[4], bfr[4];                                                       \
    _Pragma("unroll")                                                           \
    for (int mi = 0; mi < 4; ++mi)                                              \
      af[mi] = *(const short8*)&Abuf[(wm * 64 + mi * 16 + r16) * 32 + sw];      \
    _Pragma("unroll")                                                           \
    for (int ni = 0; ni < 4; ++ni)                                              \
      bfr[ni] = *(const short8*)&Bbuf[(wn * 64 + ni * 16 + r16) * 32 + sw];     \
    _Pragma("unroll")                                                           \
    for (int mi = 0; mi < 4; ++mi)                                              \
      _Pragma("unroll")                                                         \
      for (int ni = 0; ni < 4; ++ni)                                            \
        acc[mi][ni] = __builtin_amdgcn_mfma_f32_16x16x32_bf16(af[mi], bfr[ni],  \
                                                              acc[mi][ni], 0, 0, 0); \
  }

#define STAGE(Abuf, Bbuf, kb)                                                   \
  {                                                                             \
    gload16(xs + ga0 + (kb), &Abuf[c0 * 512]);                                  \
    gload16(xs + ga1 + (kb), &Abuf[c1 * 512]);                                  \
    gload16(wp + ga0 + (kb), &Bbuf[c0 * 512]);                                  \
    gload16(wp + ga1 + (kb), &Bbuf[c1 * 512]);                                  \
  }

#pragma unroll 1
  for (int t = 0; t < 24; t += 2) {
    STAGE(A1, B1, (t + 1) * 32);                      // tile t+1 (t+1<=23 always)
    FRAGS_MFMA(A0, B0);                               // consume tile t
    __syncthreads();
    if (t < 22) STAGE(A0, B0, (t + 2) * 32);          // tile t+2
    FRAGS_MFMA(A1, B1);                               // consume tile t+1
    __syncthreads();
  }
#undef FRAGS_MFMA
#undef STAGE

  // ---- epilogue: D col = lane&15, row = (lane>>4)*4 + r ----
  bool is_k = (n0 < 768);
  int cb = is_k ? n0 : n0 - 768;
#pragma unroll
  for (int ni = 0; ni < 4; ++ni) {
    int cc = cb + wn * 64 + ni * 16 + r16;
    int h = cc >> 6, d = cc & 63;
#pragma unroll
    for (int mi = 0; mi < 4; ++mi) {
#pragma unroll
      for (int r = 0; r < 4; ++r) {
        long m = m0 + wm * 64 + mi * 16 + gk * 4 + r;
        int b = (int)(m >> 12), n = (int)(m & 4095);
        long off = ((long)(b * 12 + h) * 4096 + n) * 64 + d;
        float val = acc[mi][ni][r];
        if (is_k) k_ws[off] = f2bf(val);
        else      v_out[off] = val;
      }
    }
  }
}

// ---------------------------------------------------------------------------
// Kernel 3-FALLBACK (R1 version, used when ws_size is too small)
// ---------------------------------------------------------------------------
__global__ __launch_bounds__(256) void gemm_kv(const float* __restrict__ x,
                                               const unsigned short* __restrict__ Wt,
                                               unsigned short* __restrict__ k_ws,
                                               float* __restrict__ v_out) {
  __shared__ char lds[32768];
  int bid = blockIdx.x;
  int lb = (bid & 7) * 3072 + (bid >> 3);
  int mt = lb / 12, nt = lb - mt * 12;
  long m0 = (long)mt * 128; int n0 = nt * 128;
  int tid = threadIdx.x, lane = tid & 63;
  int wid = tid >> 6, wm = wid >> 1, wn = wid & 1;
  int rlo = lane & 15, gk = lane >> 4;

  const float* xs = x + m0 * 768;
  const unsigned short* wp = Wt + (long)n0 * 768;

  int arow0 = tid >> 3, ak4 = (tid & 7) << 2;
  int bn = tid >> 1, bg = (tid & 1) << 1;

  f32x4 acc[4][4];
#pragma unroll
  for (int i = 0; i < 4; ++i)
#pragma unroll
    for (int j = 0; j < 4; ++j) acc[i][j] = (f32x4){0.f, 0.f, 0.f, 0.f};

  float4 fA[4]; short8 wB[2];
#pragma unroll
  for (int it = 0; it < 4; ++it) {
    int row = it * 32 + arow0;
    fA[it] = *(const float4*)(xs + (long)row * 768 + ak4);
  }
#pragma unroll
  for (int i = 0; i < 2; ++i)
    wB[i] = *(const short8*)(wp + (long)bn * 768 + (bg + i) * 8);
#pragma unroll
  for (int it = 0; it < 4; ++it) {
    int row = it * 32 + arow0;
    short4v h;
    h[0] = (short)f2bf(fA[it].x); h[1] = (short)f2bf(fA[it].y);
    h[2] = (short)f2bf(fA[it].z); h[3] = (short)f2bf(fA[it].w);
    *(short4v*)(lds + row * 64 + ((ak4 * 2) ^ (((row >> 1) & 3) << 4))) = h;
  }
#pragma unroll
  for (int i = 0; i < 2; ++i)
    *(short8*)(lds + 16384 + bn * 64 + (((bg + i) * 16) ^ (((bn >> 1) & 3) << 4))) = wB[i];
  __syncthreads();

#pragma unroll 2
  for (int ks = 0; ks < 24; ++ks) {
    char* Ab = lds + (ks & 1) * 8192;
    char* Bb = lds + 16384 + (ks & 1) * 8192;
    bool pf = (ks + 1 < 24);
    if (pf) {
#pragma unroll
      for (int it = 0; it < 4; ++it) {
        int row = it * 32 + arow0;
        fA[it] = *(const float4*)(xs + (long)row * 768 + (ks + 1) * 32 + ak4);
      }
#pragma unroll
      for (int i = 0; i < 2; ++i)
        wB[i] = *(const short8*)(wp + (long)bn * 768 + (ks + 1) * 32 + (bg + i) * 8);
    }
    short8 af[4], bfr[4];
#pragma unroll
    for (int mi = 0; mi < 4; ++mi) {
      int row = wm * 64 + mi * 16 + rlo;
      af[mi] = *(const short8*)(Ab + row * 64 + ((gk * 16) ^ (((row >> 1) & 3) << 4)));
    }
#pragma unroll
    for (int ni = 0; ni < 4; ++ni) {
      int n = wn * 64 + ni * 16 + rlo;
      bfr[ni] = *(const short8*)(Bb + n * 64 + ((gk * 16) ^ (((n >> 1) & 3) << 4)));
    }
#pragma unroll
    for (int mi = 0; mi < 4; ++mi)
#pragma unroll
      for (int ni = 0; ni < 4; ++ni)
        acc[mi][ni] = __builtin_amdgcn_mfma_f32_16x16x32_bf16(af[mi], bfr[ni], acc[mi][ni], 0, 0, 0);
    if (pf) {
      char* An = lds + ((ks + 1) & 1) * 8192;
      char* Bn = lds + 16384 + ((ks + 1) & 1) * 8192;
#pragma unroll
      for (int it = 0; it < 4; ++it) {
        int row = it * 32 + arow0;
        short4v h;
        h[0] = (short)f2bf(fA[it].x); h[1] = (short)f2bf(fA[it].y);
        h[2] = (short)f2bf(fA[it].z); h[3] = (short)f2bf(fA[it].w);
        *(short4v*)(An + row * 64 + ((ak4 * 2) ^ (((row >> 1) & 3) << 4))) = h;
      }
#pragma unroll
      for (int i = 0; i < 2; ++i)
        *(short8*)(Bn + bn * 64 + (((bg + i) * 16) ^ (((bn >> 1) & 3) << 4))) = wB[i];
    }
    __syncthreads();
  }

  bool is_k = (n0 < 768);
  int cb = is_k ? n0 : n0 - 768;
#pragma unroll
  for (int ni = 0; ni < 4; ++ni) {
    int cc = cb + wn * 64 + ni * 16 + rlo;
    int h = cc >> 6, d = cc & 63;
#pragma unroll
    for (int mi = 0; mi < 4; ++mi) {
#pragma unroll
      for (int r = 0; r < 4; ++r) {
        long m = m0 + wm * 64 + mi * 16 + gk * 4 + r;
        int b = (int)(m >> 12), n = (int)(m & 4095);
        long off = ((long)(b * 12 + h) * 4096 + n) * 64 + d;
        float val = acc[mi][ni][r];
        if (is_k) k_ws[off] = f2bf(val);
        else      v_out[off] = val;
      }
    }
  }
}

// ---------------------------------------------------------------------------
// Kernel 4: fused attention per (b,h). 512 threads / 8 waves.
// Phase 3 writes the normalized attn in-place (old phase 4 deleted).
// ---------------------------------------------------------------------------
__global__ __launch_bounds__(512) void attn_fused(const unsigned short* __restrict__ k_ws,
                                                  const unsigned short* __restrict__ q_ws,
                                                  const float* __restrict__ v_glob,
                                                  float* __restrict__ attn_out,
                                                  float* __restrict__ preproj) {
  __shared__ float red[8][16];
  __shared__ float rowmax[16];
  __shared__ float rowinv[16];
  __shared__ float scratch[8 * 256];

  int tid = threadIdx.x, lane = tid & 63, w = tid >> 6;
  int bh = blockIdx.x;
  int r16 = lane & 15, gk = lane >> 4;
  int trc = (r16 < 10) ? r16 : 9;

  const unsigned short* kp = k_ws + (long)bh * (4096 * 64);
  const unsigned short* qp = q_ws + (long)bh * 1024;
  float* sraw = attn_out + (long)bh * 40960;
  const float* vp = v_glob + (long)bh * (4096 * 64);

  short8 qf0 = *(const short8*)(qp + r16 * 64 + gk * 8);
  short8 qf1 = *(const short8*)(qp + r16 * 64 + 32 + gk * 8);

  // ---- Phase 1: scores + row max ----
  float pmax = -3.0e38f;
  for (int ch = 0; ch < 32; ++ch) {
    int n0 = (w * 32 + ch) << 4;
    short8 kf0 = *(const short8*)(kp + (long)(n0 + r16) * 64 + gk * 8);
    short8 kf1 = *(const short8*)(kp + (long)(n0 + r16) * 64 + 32 + gk * 8);
    f32x4 d4 = (f32x4){0.f, 0.f, 0.f, 0.f};
    d4 = __builtin_amdgcn_mfma_f32_16x16x32_bf16(kf0, qf0, d4, 0, 0, 0);
    d4 = __builtin_amdgcn_mfma_f32_16x16x32_bf16(kf1, qf1, d4, 0, 0, 0);
    float sv[4];
#pragma unroll
    for (int r = 0; r < 4; ++r) {
      int n = n0 + gk * 4 + r;
      float s = d4[r];
      if (n < 10 && n != r16) s = -1e30f;
      sv[r] = s;
      pmax = fmaxf(pmax, s);
    }
    if (r16 < 10)
      *(float4*)(sraw + r16 * 4096 + n0 + gk * 4) = make_float4(sv[0], sv[1], sv[2], sv[3]);
  }
  pmax = fmaxf(pmax, __shfl_xor(pmax, 16));
  pmax = fmaxf(pmax, __shfl_xor(pmax, 32));
  if (lane < 16) red[w][lane] = pmax;
  __syncthreads();
  if (tid < 16) {
    float m = red[0][tid];
#pragma unroll
    for (int i = 1; i < 8; ++i) m = fmaxf(m, red[i][tid]);
    rowmax[tid] = m;
  }
  __syncthreads();

  // ---- Phase 2: row sum ----
  float mx = rowmax[trc];
  float psum = 0.f;
  for (int ch = 0; ch < 16; ++ch) {
    int n0 = ((w * 16 + ch) << 5) + gk * 8;
    float4 a = *(const float4*)(sraw + trc * 4096 + n0);
    float4 b2 = *(const float4*)(sraw + trc * 4096 + n0 + 4);
    psum += __expf(a.x - mx) + __expf(a.y - mx) + __expf(a.z - mx) + __expf(a.w - mx)
          + __expf(b2.x - mx) + __expf(b2.y - mx) + __expf(b2.z - mx) + __expf(b2.w - mx);
  }
  psum += __shfl_xor(psum, 16);
  psum += __shfl_xor(psum, 32);
  if (lane < 16) red[w][lane] = psum;
  __syncthreads();
  if (tid < 16) {
    float s = 0.f;
#pragma unroll
    for (int i = 0; i < 8; ++i) s += red[i][tid];
    rowinv[tid] = 1.0f / s;
  }
  __syncthreads();

  // ---- Phase 3: PV + in-place normalized write (final attn) ----
  int dc = w & 3, half = w >> 2;
  int d0 = dc << 4;
  float inv = rowinv[trc];
  f32x4 acc = (f32x4){0.f, 0.f, 0.f, 0.f};
  for (int kk = 0; kk < 64; ++kk) {
    int nr = half * 2048 + kk * 32 + gk * 8;
    float* sp = sraw + trc * 4096 + nr;
    float4 s0 = *(const float4*)(sp);
    float4 s1 = *(const float4*)(sp + 4);
    float p0 = __expf(s0.x - mx) * inv, p1 = __expf(s0.y - mx) * inv;
    float p2 = __expf(s0.z - mx) * inv, p3 = __expf(s0.w - mx) * inv;
    float p4 = __expf(s1.x - mx) * inv, p5 = __expf(s1.y - mx) * inv;
    float p6 = __expf(s1.z - mx) * inv, p7 = __expf(s1.w - mx) * inv;
    if (r16 < 10) {
      *(float4*)(sp)     = make_float4(p0, p1, p2, p3);
      *(float4*)(sp + 4) = make_float4(p4, p5, p6, p7);
    }
    short8 pa;
    pa[0] = (short)f2bf(p0); pa[1] = (short)f2bf(p1);
    pa[2] = (short)f2bf(p2); pa[3] = (short)f2bf(p3);
    pa[4] = (short)f2bf(p4); pa[5] = (short)f2bf(p5);
    pa[6] = (short)f2bf(p6); pa[7] = (short)f2bf(p7);
    short8 vb;
    const float* vrow = vp + (long)nr * 64 + d0 + r16;
#pragma unroll
    for (int j = 0; j < 8; ++j) vb[j] = (short)f2bf(vrow[j * 64]);
    acc = __builtin_amdgcn_mfma_f32_16x16x32_bf16(pa, vb, acc, 0, 0, 0);
  }
#pragma unroll
  for (int r = 0; r < 4; ++r)
    scratch[w * 256 + (gk * 4 + r) * 16 + r16] = acc[r];
  __syncthreads();

  int b = bh / 12, h = bh - b * 12;
  for (int idx = tid; idx < 640; idx += 512) {
    int tt = idx >> 6, d = idx & 63;
    int c = d >> 4, dl = d & 15;
    float s = scratch[c * 256 + tt * 16 + dl] + scratch[(c + 4) * 256 + tt * 16 + dl];
    preproj[((long)b * 10 + tt) * 768 + h * 64 + d] = s;
  }
}

// ---------------------------------------------------------------------------
// Kernel 5: x_cls = preproj @ Wp + bp
// ---------------------------------------------------------------------------
__global__ __launch_bounds__(256) void proj_out_k(const float* __restrict__ preproj,
                                                  const float* __restrict__ Wp,
                                                  const float* __restrict__ bp,
                                                  float* __restrict__ out0) {
  int b = blockIdx.x, tid = threadIdx.x;
  __shared__ float xr[7680];
  const float* pp = preproj + (long)b * 7680;
  for (int i = tid; i < 7680; i += 256) xr[i] = pp[i];
  __syncthreads();
  float acc[10][3];
#pragma unroll
  for (int t = 0; t < 10; ++t) { acc[t][0] = 0.f; acc[t][1] = 0.f; acc[t][2] = 0.f; }
  for (int k = 0; k < 768; ++k) {
    const float* wr = Wp + (long)k * 768;
    float w0 = wr[tid], w1 = wr[tid + 256], w2 = wr[tid + 512];
#pragma unroll
    for (int t = 0; t < 10; ++t) {
      float xv = xr[t * 768 + k];
      acc[t][0] += xv * w0; acc[t][1] += xv * w1; acc[t][2] += xv * w2;
    }
  }
  float b0 = bp[tid], b1 = bp[tid + 256], b2 = bp[tid + 512];
  float* op = out0 + (long)b * 7680;
#pragma unroll
  for (int t = 0; t < 10; ++t) {
    op[t * 768 + tid]       = acc[t][0] + b0;
    op[t * 768 + tid + 256] = acc[t][1] + b1;
    op[t * 768 + tid + 512] = acc[t][2] + b2;
  }
}

// ---------------------------------------------------------------------------
extern "C" void kernel_launch(void* const* d_in, const int* in_sizes, int n_in,
                              void* d_out, int out_size, void* d_ws, size_t ws_size,
                              hipStream_t stream) {
  (void)in_sizes; (void)n_in; (void)out_size;
  const float* x  = (const float*)d_in[0];
  const float* Wq = (const float*)d_in[1];
  const float* Wk = (const float*)d_in[2];
  const float* Wv = (const float*)d_in[3];
  const float* Wp = (const float*)d_in[4];
  const float* bp = (const float*)d_in[5];

  float* out      = (float*)d_out;
  float* attn_out = out + 491520;                 // [64,12,10,4096]
  float* v_out    = out + 31948800;               // [64,12,4096,64]

  char* ws = (char*)d_ws;
  const size_t NEED_BIG = 811204608;              // x_bf16 + k_ws + small

  if (ws_size >= NEED_BIG) {
    unsigned short* x_bf16 = (unsigned short*)(ws);               // 402,653,184 B
    unsigned short* k_ws = (unsigned short*)(ws + 402653184);     // 402,653,184 B
    unsigned short* q_ws = (unsigned short*)(ws + 805306368);     //   1,572,864 B
    unsigned short* Wt   = (unsigned short*)(ws + 806879232);     //   2,359,296 B
    float* preproj       = (float*)(ws + 809238528);              //   1,966,080 B

    conv_x<<<dim3(2048), dim3(256), 0, stream>>>(x, x_bf16);
    prep_w<<<dim3(4608), dim3(256), 0, stream>>>(Wk, Wv, Wt);
    q_proj<<<dim3(64), dim3(256), 0, stream>>>(x, Wq, q_ws);
    gemm_kv4<<<dim3(24576), dim3(256), 0, stream>>>(x_bf16, Wt, k_ws, v_out);
    attn_fused<<<dim3(768), dim3(512), 0, stream>>>(k_ws, q_ws, v_out, attn_out, preproj);
    proj_out_k<<<dim3(64), dim3(256), 0, stream>>>(preproj, Wp, bp, out);
  } else {
    unsigned short* k_ws = (unsigned short*)(ws);                 // 402,653,184 B
    unsigned short* q_ws = (unsigned short*)(ws + 402653184);
    unsigned short* Wt   = (unsigned short*)(ws + 404226048);
    float* preproj       = (float*)(ws + 406585344);

    prep_w<<<dim3(4608), dim3(256), 0, stream>>>(Wk, Wv, Wt);
    q_proj<<<dim3(64), dim3(256), 0, stream>>>(x, Wq, q_ws);
    gemm_kv<<<dim3(24576), dim3(256), 0, stream>>>(x, Wt, k_ws, v_out);
    attn_fused<<<dim3(768), dim3(512), 0, stream>>>(k_ws, q_ws, v_out, attn_out, preproj);
    proj_out_k<<<dim3(64), dim3(256), 0, stream>>>(preproj, Wp, bp, out);
  }
}

// Round 5
// 1774.668 us; speedup vs baseline: 1.0901x; 1.0508x over previous
//
#include <hip/hip_runtime.h>

typedef __attribute__((ext_vector_type(8))) short short8;
typedef __attribute__((ext_vector_type(4))) short short4v;
typedef __attribute__((ext_vector_type(4))) float f32x4;

__device__ __forceinline__ unsigned short f2bf(float f) {
  union { float f; unsigned u; } v; v.f = f;
  unsigned r = v.u + 0x7FFFu + ((v.u >> 16) & 1u);
  return (unsigned short)(r >> 16);
}

__device__ __forceinline__ void gload16(const void* g, void* l) {
  __builtin_amdgcn_global_load_lds(
      (const __attribute__((address_space(1))) void*)g,
      (__attribute__((address_space(3))) void*)l, 16, 0, 0);
}

// ---------------------------------------------------------------------------
// Kernel 0: x (fp32) -> x_bf16, vectorized 8 elems/thread
// ---------------------------------------------------------------------------
__global__ __launch_bounds__(256) void conv_x(const float* __restrict__ x,
                                              unsigned short* __restrict__ xb) {
  const long total = 25165824;                        // 201326592 / 8
  long stride = (long)gridDim.x * 256;
  for (long u = blockIdx.x * 256 + threadIdx.x; u < total; u += stride) {
    const float* p = x + u * 8;
    float4 a = *(const float4*)p;
    float4 b = *(const float4*)(p + 4);
    short8 h;
    h[0] = (short)f2bf(a.x); h[1] = (short)f2bf(a.y);
    h[2] = (short)f2bf(a.z); h[3] = (short)f2bf(a.w);
    h[4] = (short)f2bf(b.x); h[5] = (short)f2bf(b.y);
    h[6] = (short)f2bf(b.z); h[7] = (short)f2bf(b.w);
    *(short8*)(xb + u * 8) = h;
  }
}

// ---------------------------------------------------------------------------
// Kernel 1: Wt[n][k] = bf16( [Wk | Wv](k, n) )   (B^T layout, n in [0,1536))
// ---------------------------------------------------------------------------
__global__ __launch_bounds__(256) void prep_w(const float* __restrict__ Wk,
                                              const float* __restrict__ Wv,
                                              unsigned short* __restrict__ Wt) {
  int idx = blockIdx.x * 256 + threadIdx.x;           // 1536*768 elements
  int n = idx / 768, k = idx - n * 768;
  float w = (n < 768) ? Wk[k * 768 + n] : Wv[k * 768 + (n - 768)];
  Wt[idx] = f2bf(w);
}

// ---------------------------------------------------------------------------
// Kernel 2: q = scale * x[:, :10] @ Wq  -> q_ws[b][h][16][64] bf16 (rows 10..15 = 0)
// ---------------------------------------------------------------------------
__global__ __launch_bounds__(256) void q_proj(const float* __restrict__ x,
                                              const float* __restrict__ Wq,
                                              unsigned short* __restrict__ q_ws) {
  int b = blockIdx.x, tid = threadIdx.x;
  __shared__ float xr[7680];
  const float* xp = x + (long)b * 4096 * 768;
  for (int i = tid; i < 7680; i += 256) xr[i] = xp[i];
  for (int i = tid; i < 12 * 6 * 64; i += 256) {
    int h = i / 384, rem = i - h * 384;
    int t = 10 + rem / 64, d = rem & 63;
    q_ws[(((long)(b * 12 + h) * 16 + t) << 6) + d] = 0;
  }
  __syncthreads();
  float acc[10][3];
#pragma unroll
  for (int t = 0; t < 10; ++t) { acc[t][0] = 0.f; acc[t][1] = 0.f; acc[t][2] = 0.f; }
  for (int k = 0; k < 768; ++k) {
    const float* wr = Wq + (long)k * 768;
    float w0 = wr[tid], w1 = wr[tid + 256], w2 = wr[tid + 512];
#pragma unroll
    for (int t = 0; t < 10; ++t) {
      float xv = xr[t * 768 + k];
      acc[t][0] += xv * w0; acc[t][1] += xv * w1; acc[t][2] += xv * w2;
    }
  }
#pragma unroll
  for (int t = 0; t < 10; ++t) {
#pragma unroll
    for (int j = 0; j < 3; ++j) {
      int c = tid + j * 256;
      int h = c >> 6, d = c & 63;
      q_ws[(((long)(b * 12 + h) * 16 + t) << 6) + d] = f2bf(acc[t][j] * 0.125f);
    }
  }
}

// ---------------------------------------------------------------------------
// Kernel 3 (R5): 128x128 tile, BK=32, TRIPLE-buffered gload_lds with counted
// vmcnt(4) barriers (loads stay in flight across barriers; never drained to 0
// in the main loop) + involution-swizzled chunks + LDS-staged coalesced
// epilogue (256B/128B contiguous stores).
// ---------------------------------------------------------------------------
__global__ __launch_bounds__(256) void gemm_kv5(const unsigned short* __restrict__ xb,
                                                const unsigned short* __restrict__ Wt,
                                                unsigned short* __restrict__ k_ws,
                                                float* __restrict__ v_out) {
  __shared__ char smem[49152];                        // 6 x 8KB static slots
#define A0 ((unsigned short*)(smem + 0))
#define B0 ((unsigned short*)(smem + 8192))
#define A1 ((unsigned short*)(smem + 16384))
#define B1 ((unsigned short*)(smem + 24576))
#define A2 ((unsigned short*)(smem + 32768))
#define B2 ((unsigned short*)(smem + 40960))

  int bid = blockIdx.x;
  int lb = (bid & 7) * 3072 + (bid >> 3);             // XCD swizzle (24576 % 8 == 0)
  int mt = lb / 12, nt = lb - mt * 12;
  long m0 = (long)mt * 128; int n0 = nt * 128;
  int tid = threadIdx.x, lane = tid & 63;
  int uw = __builtin_amdgcn_readfirstlane(tid >> 6);  // uniform wave id
  int wm = uw >> 1, wn = uw & 1;
  int r16 = lane & 15, gk = lane >> 4;

  const unsigned short* xs = xb + m0 * 768;
  const unsigned short* wp = Wt + (long)n0 * 768;

  int srow = lane >> 2;                               // row within 16-row chunk
  int sg = ((lane & 3) ^ ((srow >> 1) & 3)) << 3;     // swizzled SOURCE chunk (elems)
  int sw = (gk ^ ((r16 >> 1) & 3)) << 3;              // swizzled READ chunk (elems)

  int c0 = uw, c1 = uw + 4;                           // this wave's two 16-row chunks
  const unsigned short* pA0 = xs + (long)(c0 * 16 + srow) * 768 + sg;
  const unsigned short* pA1 = xs + (long)(c1 * 16 + srow) * 768 + sg;
  const unsigned short* pB0 = wp + (long)(c0 * 16 + srow) * 768 + sg;
  const unsigned short* pB1 = wp + (long)(c1 * 16 + srow) * 768 + sg;

  f32x4 acc[4][4];
#pragma unroll
  for (int i = 0; i < 4; ++i)
#pragma unroll
    for (int j = 0; j < 4; ++j) acc[i][j] = (f32x4){0.f, 0.f, 0.f, 0.f};

#define STAGE(Ab, Bb, OFF)                                                      \
  {                                                                             \
    gload16(pA0 + (OFF), &Ab[c0 * 512]);                                        \
    gload16(pA1 + (OFF), &Ab[c1 * 512]);                                        \
    gload16(pB0 + (OFF), &Bb[c0 * 512]);                                        \
    gload16(pB1 + (OFF), &Bb[c1 * 512]);                                        \
  }
#define COMPUTE(Ab, Bb)                                                         \
  {                                                                             \
    short8 af[4], bfr[4];                                                       \
    _Pragma("unroll")                                                           \
    for (int mi = 0; mi < 4; ++mi)                                              \
      af[mi] = *(const short8*)&Ab[(wm * 64 + mi * 16 + r16) * 32 + sw];        \
    _Pragma("unroll")                                                           \
    for (int ni = 0; ni < 4; ++ni)                                              \
      bfr[ni] = *(const short8*)&Bb[(wn * 64 + ni * 16 + r16) * 32 + sw];       \
    _Pragma("unroll")                                                           \
    for (int mi = 0; mi < 4; ++mi)                                              \
      _Pragma("unroll")                                                         \
      for (int ni = 0; ni < 4; ++ni)                                            \
        acc[mi][ni] = __builtin_amdgcn_mfma_f32_16x16x32_bf16(af[mi], bfr[ni],  \
                                                              acc[mi][ni], 0, 0, 0); \
  }
#define WB4 asm volatile("s_waitcnt vmcnt(4) lgkmcnt(0)\n\ts_barrier" ::: "memory")
#define WB0 asm volatile("s_waitcnt vmcnt(0) lgkmcnt(0)\n\ts_barrier" ::: "memory")

  // prologue: tiles 0,1 in flight; wait for tile 0 only
  STAGE(A0, B0, 0);
  STAGE(A1, B1, 32);
  WB4;

#pragma unroll 1
  for (int g = 0; g < 7; ++g) {
    // t=3g:   stage tile 3g+2 -> buf2 (stays in flight across barrier)
    STAGE(A2, B2, 64);  COMPUTE(A0, B0); WB4;
    // t=3g+1: stage tile 3g+3 -> buf0
    STAGE(A0, B0, 96);  COMPUTE(A1, B1); WB4;
    // t=3g+2: stage tile 3g+4 -> buf1
    STAGE(A1, B1, 128); COMPUTE(A2, B2); WB4;
    pA0 += 96; pA1 += 96; pB0 += 96; pB1 += 96;
  }
  // t=21: stage tile 23 -> buf2
  STAGE(A2, B2, 64); COMPUTE(A0, B0); WB4;
  // t=22 (tile 22 in buf1); drain tile 23
  COMPUTE(A1, B1); WB0;
  // t=23 (tile 23 in buf2)
  COMPUTE(A2, B2);

#undef STAGE
#undef COMPUTE
#undef WB4
#undef WB0

  // ---- epilogue: stage each wave's 16x64 sub-tile in private LDS scratch,
  //      then fully-coalesced vector stores. scr reuses A0/B0 (dead). ----
  float* scr = (float*)(smem + uw * 4096);            // 4KB per wave
  bool is_k = (n0 < 768);                             // uniform per block
  int cb = is_k ? n0 : n0 - 768;
  int hq = (cb >> 6) + wn;                            // uniform per wave
  int b12h = 0;                                       // computed per row below

#pragma unroll
  for (int mi = 0; mi < 4; ++mi) {
#pragma unroll
    for (int ni = 0; ni < 4; ++ni)
#pragma unroll
      for (int r = 0; r < 4; ++r)
        scr[(gk * 4 + r) * 64 + ni * 16 + r16] = acc[mi][ni][r];
    long mbase = m0 + wm * 64 + mi * 16;
    if (is_k) {
#pragma unroll
      for (int p = 0; p < 2; ++p) {
        int row = p * 8 + (lane >> 3), d0 = (lane & 7) << 3;
        long m = mbase + row;
        int b = (int)(m >> 12), n = (int)(m & 4095);
        float4 aa = *(const float4*)&scr[row * 64 + d0];
        float4 bb = *(const float4*)&scr[row * 64 + d0 + 4];
        short8 hh;
        hh[0] = (short)f2bf(aa.x); hh[1] = (short)f2bf(aa.y);
        hh[2] = (short)f2bf(aa.z); hh[3] = (short)f2bf(aa.w);
        hh[4] = (short)f2bf(bb.x); hh[5] = (short)f2bf(bb.y);
        hh[6] = (short)f2bf(bb.z); hh[7] = (short)f2bf(bb.w);
        *(short8*)&k_ws[((long)(b * 12 + hq) * 4096 + n) * 64 + d0] = hh;
      }
    } else {
#pragma unroll
      for (int p = 0; p < 4; ++p) {
        int row = p * 4 + (lane >> 4), d0 = (lane & 15) << 2;
        long m = mbase + row;
        int b = (int)(m >> 12), n = (int)(m & 4095);
        float4 aa = *(const float4*)&scr[row * 64 + d0];
        *(float4*)&v_out[((long)(b * 12 + hq) * 4096 + n) * 64 + d0] = aa;
      }
    }
    // wave-private scratch: in-wave lgkm ordering handled by compiler
  }
  (void)b12h;
#undef A0
#undef B0
#undef A1
#undef B1
#undef A2
#undef B2
}

// ---------------------------------------------------------------------------
// Kernel 3-FALLBACK (R1 version, used when ws_size is too small)
// ---------------------------------------------------------------------------
__global__ __launch_bounds__(256) void gemm_kv(const float* __restrict__ x,
                                               const unsigned short* __restrict__ Wt,
                                               unsigned short* __restrict__ k_ws,
                                               float* __restrict__ v_out) {
  __shared__ char lds[32768];
  int bid = blockIdx.x;
  int lb = (bid & 7) * 3072 + (bid >> 3);
  int mt = lb / 12, nt = lb - mt * 12;
  long m0 = (long)mt * 128; int n0 = nt * 128;
  int tid = threadIdx.x, lane = tid & 63;
  int wid = tid >> 6, wm = wid >> 1, wn = wid & 1;
  int rlo = lane & 15, gk = lane >> 4;

  const float* xs = x + m0 * 768;
  const unsigned short* wp = Wt + (long)n0 * 768;

  int arow0 = tid >> 3, ak4 = (tid & 7) << 2;
  int bn = tid >> 1, bg = (tid & 1) << 1;

  f32x4 acc[4][4];
#pragma unroll
  for (int i = 0; i < 4; ++i)
#pragma unroll
    for (int j = 0; j < 4; ++j) acc[i][j] = (f32x4){0.f, 0.f, 0.f, 0.f};

  float4 fA[4]; short8 wB[2];
#pragma unroll
  for (int it = 0; it < 4; ++it) {
    int row = it * 32 + arow0;
    fA[it] = *(const float4*)(xs + (long)row * 768 + ak4);
  }
#pragma unroll
  for (int i = 0; i < 2; ++i)
    wB[i] = *(const short8*)(wp + (long)bn * 768 + (bg + i) * 8);
#pragma unroll
  for (int it = 0; it < 4; ++it) {
    int row = it * 32 + arow0;
    short4v h;
    h[0] = (short)f2bf(fA[it].x); h[1] = (short)f2bf(fA[it].y);
    h[2] = (short)f2bf(fA[it].z); h[3] = (short)f2bf(fA[it].w);
    *(short4v*)(lds + row * 64 + ((ak4 * 2) ^ (((row >> 1) & 3) << 4))) = h;
  }
#pragma unroll
  for (int i = 0; i < 2; ++i)
    *(short8*)(lds + 16384 + bn * 64 + (((bg + i) * 16) ^ (((bn >> 1) & 3) << 4))) = wB[i];
  __syncthreads();

#pragma unroll 2
  for (int ks = 0; ks < 24; ++ks) {
    char* Ab = lds + (ks & 1) * 8192;
    char* Bb = lds + 16384 + (ks & 1) * 8192;
    bool pf = (ks + 1 < 24);
    if (pf) {
#pragma unroll
      for (int it = 0; it < 4; ++it) {
        int row = it * 32 + arow0;
        fA[it] = *(const float4*)(xs + (long)row * 768 + (ks + 1) * 32 + ak4);
      }
#pragma unroll
      for (int i = 0; i < 2; ++i)
        wB[i] = *(const short8*)(wp + (long)bn * 768 + (ks + 1) * 32 + (bg + i) * 8);
    }
    short8 af[4], bfr[4];
#pragma unroll
    for (int mi = 0; mi < 4; ++mi) {
      int row = wm * 64 + mi * 16 + rlo;
      af[mi] = *(const short8*)(Ab + row * 64 + ((gk * 16) ^ (((row >> 1) & 3) << 4)));
    }
#pragma unroll
    for (int ni = 0; ni < 4; ++ni) {
      int n = wn * 64 + ni * 16 + rlo;
      bfr[ni] = *(const short8*)(Bb + n * 64 + ((gk * 16) ^ (((n >> 1) & 3) << 4)));
    }
#pragma unroll
    for (int mi = 0; mi < 4; ++mi)
#pragma unroll
      for (int ni = 0; ni < 4; ++ni)
        acc[mi][ni] = __builtin_amdgcn_mfma_f32_16x16x32_bf16(af[mi], bfr[ni], acc[mi][ni], 0, 0, 0);
    if (pf) {
      char* An = lds + ((ks + 1) & 1) * 8192;
      char* Bn = lds + 16384 + ((ks + 1) & 1) * 8192;
#pragma unroll
      for (int it = 0; it < 4; ++it) {
        int row = it * 32 + arow0;
        short4v h;
        h[0] = (short)f2bf(fA[it].x); h[1] = (short)f2bf(fA[it].y);
        h[2] = (short)f2bf(fA[it].z); h[3] = (short)f2bf(fA[it].w);
        *(short4v*)(An + row * 64 + ((ak4 * 2) ^ (((row >> 1) & 3) << 4))) = h;
      }
#pragma unroll
      for (int i = 0; i < 2; ++i)
        *(short8*)(Bn + bn * 64 + (((bg + i) * 16) ^ (((bn >> 1) & 3) << 4))) = wB[i];
    }
    __syncthreads();
  }

  bool is_k = (n0 < 768);
  int cb = is_k ? n0 : n0 - 768;
#pragma unroll
  for (int ni = 0; ni < 4; ++ni) {
    int cc = cb + wn * 64 + ni * 16 + rlo;
    int h = cc >> 6, d = cc & 63;
#pragma unroll
    for (int mi = 0; mi < 4; ++mi) {
#pragma unroll
      for (int r = 0; r < 4; ++r) {
        long m = m0 + wm * 64 + mi * 16 + gk * 4 + r;
        int b = (int)(m >> 12), n = (int)(m & 4095);
        long off = ((long)(b * 12 + h) * 4096 + n) * 64 + d;
        float val = acc[mi][ni][r];
        if (is_k) k_ws[off] = f2bf(val);
        else      v_out[off] = val;
      }
    }
  }
}

// ---------------------------------------------------------------------------
// Kernel 4: fused attention per (b,h). 512 threads / 8 waves.
// ---------------------------------------------------------------------------
__global__ __launch_bounds__(512) void attn_fused(const unsigned short* __restrict__ k_ws,
                                                  const unsigned short* __restrict__ q_ws,
                                                  const float* __restrict__ v_glob,
                                                  float* __restrict__ attn_out,
                                                  float* __restrict__ preproj) {
  __shared__ float red[8][16];
  __shared__ float rowmax[16];
  __shared__ float rowinv[16];
  __shared__ float scratch[8 * 256];

  int tid = threadIdx.x, lane = tid & 63, w = tid >> 6;
  int bh = blockIdx.x;
  int r16 = lane & 15, gk = lane >> 4;
  int trc = (r16 < 10) ? r16 : 9;

  const unsigned short* kp = k_ws + (long)bh * (4096 * 64);
  const unsigned short* qp = q_ws + (long)bh * 1024;
  float* sraw = attn_out + (long)bh * 40960;
  const float* vp = v_glob + (long)bh * (4096 * 64);

  short8 qf0 = *(const short8*)(qp + r16 * 64 + gk * 8);
  short8 qf1 = *(const short8*)(qp + r16 * 64 + 32 + gk * 8);

  // ---- Phase 1: scores + row max ----
  float pmax = -3.0e38f;
  for (int ch = 0; ch < 32; ++ch) {
    int n0 = (w * 32 + ch) << 4;
    short8 kf0 = *(const short8*)(kp + (long)(n0 + r16) * 64 + gk * 8);
    short8 kf1 = *(const short8*)(kp + (long)(n0 + r16) * 64 + 32 + gk * 8);
    f32x4 d4 = (f32x4){0.f, 0.f, 0.f, 0.f};
    d4 = __builtin_amdgcn_mfma_f32_16x16x32_bf16(kf0, qf0, d4, 0, 0, 0);
    d4 = __builtin_amdgcn_mfma_f32_16x16x32_bf16(kf1, qf1, d4, 0, 0, 0);
    float sv[4];
#pragma unroll
    for (int r = 0; r < 4; ++r) {
      int n = n0 + gk * 4 + r;
      float s = d4[r];
      if (n < 10 && n != r16) s = -1e30f;
      sv[r] = s;
      pmax = fmaxf(pmax, s);
    }
    if (r16 < 10)
      *(float4*)(sraw + r16 * 4096 + n0 + gk * 4) = make_float4(sv[0], sv[1], sv[2], sv[3]);
  }
  pmax = fmaxf(pmax, __shfl_xor(pmax, 16));
  pmax = fmaxf(pmax, __shfl_xor(pmax, 32));
  if (lane < 16) red[w][lane] = pmax;
  __syncthreads();
  if (tid < 16) {
    float m = red[0][tid];
#pragma unroll
    for (int i = 1; i < 8; ++i) m = fmaxf(m, red[i][tid]);
    rowmax[tid] = m;
  }
  __syncthreads();

  // ---- Phase 2: row sum ----
  float mx = rowmax[trc];
  float psum = 0.f;
  for (int ch = 0; ch < 16; ++ch) {
    int n0 = ((w * 16 + ch) << 5) + gk * 8;
    float4 a = *(const float4*)(sraw + trc * 4096 + n0);
    float4 b2 = *(const float4*)(sraw + trc * 4096 + n0 + 4);
    psum += __expf(a.x - mx) + __expf(a.y - mx) + __expf(a.z - mx) + __expf(a.w - mx)
          + __expf(b2.x - mx) + __expf(b2.y - mx) + __expf(b2.z - mx) + __expf(b2.w - mx);
  }
  psum += __shfl_xor(psum, 16);
  psum += __shfl_xor(psum, 32);
  if (lane < 16) red[w][lane] = psum;
  __syncthreads();
  if (tid < 16) {
    float s = 0.f;
#pragma unroll
    for (int i = 0; i < 8; ++i) s += red[i][tid];
    rowinv[tid] = 1.0f / s;
  }
  __syncthreads();

  // ---- Phase 3: PV + in-place normalized write (final attn) ----
  int dc = w & 3, half = w >> 2;
  int d0 = dc << 4;
  float inv = rowinv[trc];
  f32x4 acc = (f32x4){0.f, 0.f, 0.f, 0.f};
  for (int kk = 0; kk < 64; ++kk) {
    int nr = half * 2048 + kk * 32 + gk * 8;
    float* sp = sraw + trc * 4096 + nr;
    float4 s0 = *(const float4*)(sp);
    float4 s1 = *(const float4*)(sp + 4);
    float p0 = __expf(s0.x - mx) * inv, p1 = __expf(s0.y - mx) * inv;
    float p2 = __expf(s0.z - mx) * inv, p3 = __expf(s0.w - mx) * inv;
    float p4 = __expf(s1.x - mx) * inv, p5 = __expf(s1.y - mx) * inv;
    float p6 = __expf(s1.z - mx) * inv, p7 = __expf(s1.w - mx) * inv;
    if (r16 < 10) {
      *(float4*)(sp)     = make_float4(p0, p1, p2, p3);
      *(float4*)(sp + 4) = make_float4(p4, p5, p6, p7);
    }
    short8 pa;
    pa[0] = (short)f2bf(p0); pa[1] = (short)f2bf(p1);
    pa[2] = (short)f2bf(p2); pa[3] = (short)f2bf(p3);
    pa[4] = (short)f2bf(p4); pa[5] = (short)f2bf(p5);
    pa[6] = (short)f2bf(p6); pa[7] = (short)f2bf(p7);
    short8 vb;
    const float* vrow = vp + (long)nr * 64 + d0 + r16;
#pragma unroll
    for (int j = 0; j < 8; ++j) vb[j] = (short)f2bf(vrow[j * 64]);
    acc = __builtin_amdgcn_mfma_f32_16x16x32_bf16(pa, vb, acc, 0, 0, 0);
  }
#pragma unroll
  for (int r = 0; r < 4; ++r)
    scratch[w * 256 + (gk * 4 + r) * 16 + r16] = acc[r];
  __syncthreads();

  int b = bh / 12, h = bh - b * 12;
  for (int idx = tid; idx < 640; idx += 512) {
    int tt = idx >> 6, d = idx & 63;
    int c = d >> 4, dl = d & 15;
    float s = scratch[c * 256 + tt * 16 + dl] + scratch[(c + 4) * 256 + tt * 16 + dl];
    preproj[((long)b * 10 + tt) * 768 + h * 64 + d] = s;
  }
}

// ---------------------------------------------------------------------------
// Kernel 5: x_cls = preproj @ Wp + bp
// ---------------------------------------------------------------------------
__global__ __launch_bounds__(256) void proj_out_k(const float* __restrict__ preproj,
                                                  const float* __restrict__ Wp,
                                                  const float* __restrict__ bp,
                                                  float* __restrict__ out0) {
  int b = blockIdx.x, tid = threadIdx.x;
  __shared__ float xr[7680];
  const float* pp = preproj + (long)b * 7680;
  for (int i = tid; i < 7680; i += 256) xr[i] = pp[i];
  __syncthreads();
  float acc[10][3];
#pragma unroll
  for (int t = 0; t < 10; ++t) { acc[t][0] = 0.f; acc[t][1] = 0.f; acc[t][2] = 0.f; }
  for (int k = 0; k < 768; ++k) {
    const float* wr = Wp + (long)k * 768;
    float w0 = wr[tid], w1 = wr[tid + 256], w2 = wr[tid + 512];
#pragma unroll
    for (int t = 0; t < 10; ++t) {
      float xv = xr[t * 768 + k];
      acc[t][0] += xv * w0; acc[t][1] += xv * w1; acc[t][2] += xv * w2;
    }
  }
  float b0 = bp[tid], b1 = bp[tid + 256], b2 = bp[tid + 512];
  float* op = out0 + (long)b * 7680;
#pragma unroll
  for (int t = 0; t < 10; ++t) {
    op[t * 768 + tid]       = acc[t][0] + b0;
    op[t * 768 + tid + 256] = acc[t][1] + b1;
    op[t * 768 + tid + 512] = acc[t][2] + b2;
  }
}

// ---------------------------------------------------------------------------
extern "C" void kernel_launch(void* const* d_in, const int* in_sizes, int n_in,
                              void* d_out, int out_size, void* d_ws, size_t ws_size,
                              hipStream_t stream) {
  (void)in_sizes; (void)n_in; (void)out_size;
  const float* x  = (const float*)d_in[0];
  const float* Wq = (const float*)d_in[1];
  const float* Wk = (const float*)d_in[2];
  const float* Wv = (const float*)d_in[3];
  const float* Wp = (const float*)d_in[4];
  const float* bp = (const float*)d_in[5];

  float* out      = (float*)d_out;
  float* attn_out = out + 491520;                 // [64,12,10,4096]
  float* v_out    = out + 31948800;               // [64,12,4096,64]

  char* ws = (char*)d_ws;
  const size_t NEED_BIG = 811204608;              // x_bf16 + k_ws + small

  if (ws_size >= NEED_BIG) {
    unsigned short* x_bf16 = (unsigned short*)(ws);               // 402,653,184 B
    unsigned short* k_ws = (unsigned short*)(ws + 402653184);     // 402,653,184 B
    unsigned short* q_ws = (unsigned short*)(ws + 805306368);     //   1,572,864 B
    unsigned short* Wt   = (unsigned short*)(ws + 806879232);     //   2,359,296 B
    float* preproj       = (float*)(ws + 809238528);              //   1,966,080 B

    conv_x<<<dim3(2048), dim3(256), 0, stream>>>(x, x_bf16);
    prep_w<<<dim3(4608), dim3(256), 0, stream>>>(Wk, Wv, Wt);
    q_proj<<<dim3(64), dim3(256), 0, stream>>>(x, Wq, q_ws);
    gemm_kv5<<<dim3(24576), dim3(256), 0, stream>>>(x_bf16, Wt, k_ws, v_out);
    attn_fused<<<dim3(768), dim3(512), 0, stream>>>(k_ws, q_ws, v_out, attn_out, preproj);
    proj_out_k<<<dim3(64), dim3(256), 0, stream>>>(preproj, Wp, bp, out);
  } else {
    unsigned short* k_ws = (unsigned short*)(ws);                 // 402,653,184 B
    unsigned short* q_ws = (unsigned short*)(ws + 402653184);
    unsigned short* Wt   = (unsigned short*)(ws + 404226048);
    float* preproj       = (float*)(ws + 406585344);

    prep_w<<<dim3(4608), dim3(256), 0, stream>>>(Wk, Wv, Wt);
    q_proj<<<dim3(64), dim3(256), 0, stream>>>(x, Wq, q_ws);
    gemm_kv<<<dim3(24576), dim3(256), 0, stream>>>(x, Wt, k_ws, v_out);
    attn_fused<<<dim3(768), dim3(512), 0, stream>>>(k_ws, q_ws, v_out, attn_out, preproj);
    proj_out_k<<<dim3(64), dim3(256), 0, stream>>>(preproj, Wp, bp, out);
  }
}

// Round 6
// 1627.725 us; speedup vs baseline: 1.1885x; 1.0903x over previous
//
#include <hip/hip_runtime.h>

typedef __attribute__((ext_vector_type(8))) short short8;
typedef __attribute__((ext_vector_type(4))) short short4v;
typedef __attribute__((ext_vector_type(4))) float f32x4;

__device__ __forceinline__ unsigned short f2bf(float f) {
  union { float f; unsigned u; } v; v.f = f;
  unsigned r = v.u + 0x7FFFu + ((v.u >> 16) & 1u);
  return (unsigned short)(r >> 16);
}

__device__ __forceinline__ void gload16(const void* g, void* l) {
  __builtin_amdgcn_global_load_lds(
      (const __attribute__((address_space(1))) void*)g,
      (__attribute__((address_space(3))) void*)l, 16, 0, 0);
}

// ---------------------------------------------------------------------------
// Kernel 0: x (fp32) -> x_bf16, vectorized 8 elems/thread
// ---------------------------------------------------------------------------
__global__ __launch_bounds__(256) void conv_x(const float* __restrict__ x,
                                              unsigned short* __restrict__ xb) {
  const long total = 25165824;                        // 201326592 / 8
  long stride = (long)gridDim.x * 256;
  for (long u = blockIdx.x * 256 + threadIdx.x; u < total; u += stride) {
    const float* p = x + u * 8;
    float4 a = *(const float4*)p;
    float4 b = *(const float4*)(p + 4);
    short8 h;
    h[0] = (short)f2bf(a.x); h[1] = (short)f2bf(a.y);
    h[2] = (short)f2bf(a.z); h[3] = (short)f2bf(a.w);
    h[4] = (short)f2bf(b.x); h[5] = (short)f2bf(b.y);
    h[6] = (short)f2bf(b.z); h[7] = (short)f2bf(b.w);
    *(short8*)(xb + u * 8) = h;
  }
}

// ---------------------------------------------------------------------------
// Kernel 1: Wt[n][k] = bf16( [Wk | Wv](k, n) )   (B^T layout, n in [0,1536))
// ---------------------------------------------------------------------------
__global__ __launch_bounds__(256) void prep_w(const float* __restrict__ Wk,
                                              const float* __restrict__ Wv,
                                              unsigned short* __restrict__ Wt) {
  int idx = blockIdx.x * 256 + threadIdx.x;           // 1536*768 elements
  int n = idx / 768, k = idx - n * 768;
  float w = (n < 768) ? Wk[k * 768 + n] : Wv[k * 768 + (n - 768)];
  Wt[idx] = f2bf(w);
}

// ---------------------------------------------------------------------------
// Kernel 2: q = scale * x[:, :10] @ Wq  -> q_ws[b][h][16][64] bf16 (rows 10..15 = 0)
// ---------------------------------------------------------------------------
__global__ __launch_bounds__(256) void q_proj(const float* __restrict__ x,
                                              const float* __restrict__ Wq,
                                              unsigned short* __restrict__ q_ws) {
  int b = blockIdx.x, tid = threadIdx.x;
  __shared__ float xr[7680];
  const float* xp = x + (long)b * 4096 * 768;
  for (int i = tid; i < 7680; i += 256) xr[i] = xp[i];
  for (int i = tid; i < 12 * 6 * 64; i += 256) {
    int h = i / 384, rem = i - h * 384;
    int t = 10 + rem / 64, d = rem & 63;
    q_ws[(((long)(b * 12 + h) * 16 + t) << 6) + d] = 0;
  }
  __syncthreads();
  float acc[10][3];
#pragma unroll
  for (int t = 0; t < 10; ++t) { acc[t][0] = 0.f; acc[t][1] = 0.f; acc[t][2] = 0.f; }
  for (int k = 0; k < 768; ++k) {
    const float* wr = Wq + (long)k * 768;
    float w0 = wr[tid], w1 = wr[tid + 256], w2 = wr[tid + 512];
#pragma unroll
    for (int t = 0; t < 10; ++t) {
      float xv = xr[t * 768 + k];
      acc[t][0] += xv * w0; acc[t][1] += xv * w1; acc[t][2] += xv * w2;
    }
  }
#pragma unroll
  for (int t = 0; t < 10; ++t) {
#pragma unroll
    for (int j = 0; j < 3; ++j) {
      int c = tid + j * 256;
      int h = c >> 6, d = c & 63;
      q_ws[(((long)(b * 12 + h) * 16 + t) << 6) + d] = f2bf(acc[t][j] * 0.125f);
    }
  }
}

// ---------------------------------------------------------------------------
// Kernel 3 (R6): 256x256 tile, BK=32, 8 waves (2Mx4N), TRIPLE-buffered
// gload_lds, counted vmcnt(4) barriers, conflict-free chunk swizzle
// (chunk ^ row&3 on source AND read), padded-LDS coalesced epilogue.
// ---------------------------------------------------------------------------
__global__ __launch_bounds__(512, 2) void gemm_kv6(const unsigned short* __restrict__ xb,
                                                   const unsigned short* __restrict__ Wt,
                                                   unsigned short* __restrict__ k_ws,
                                                   float* __restrict__ v_out) {
  __shared__ char smem[98304];                        // 6 x 16KB: A0 B0 A1 B1 A2 B2
#define AB(i) ((unsigned short*)(smem + (i) * 16384))

  int bid = blockIdx.x;
  int lb = (bid & 7) * 768 + (bid >> 3);              // XCD swizzle (6144 % 8 == 0)
  int mt = lb / 6, nt = lb - mt * 6;
  long m0 = (long)mt * 256; int n0 = nt * 256;
  int tid = threadIdx.x, lane = tid & 63;
  int uw = __builtin_amdgcn_readfirstlane(tid >> 6);  // uniform wave id 0..7
  int wm = uw >> 2, wn = uw & 3;                      // 2 M-waves x 4 N-waves
  int r16 = lane & 15, gk = lane >> 4;

  const unsigned short* xs = xb + m0 * 768;
  const unsigned short* wp = Wt + (long)n0 * 768;

  // staging: lane l covers (row = base + (l>>2), chunk = l&3); source chunk
  // pre-swizzled so LDS chunk c holds global chunk c ^ (row&3)
  int srow = lane >> 2;                               // row&3 == srow&3 (base%16==0)
  int schunk = ((lane & 3) ^ (srow & 3)) << 3;        // source offset in elems
  const unsigned short* pA = xs + (long)(uw * 16 + srow) * 768 + schunk;
  const unsigned short* pB = wp + (long)(uw * 16 + srow) * 768 + schunk;
  const long JROW = 128 * 768;                        // second 128-row group

  // frag read swizzle: chunk = gk ^ (r16&3)
  int rc = (gk ^ (r16 & 3)) << 3;                     // elem offset within row

  f32x4 acc[8][4];
#pragma unroll
  for (int i = 0; i < 8; ++i)
#pragma unroll
    for (int j = 0; j < 4; ++j) acc[i][j] = (f32x4){0.f, 0.f, 0.f, 0.f};

#define STAGE(BUF, OFF)                                                         \
  {                                                                             \
    gload16(pA + (OFF), AB(2 * (BUF)) + uw * 512);                              \
    gload16(pA + (OFF) + JROW, AB(2 * (BUF)) + uw * 512 + 4096);                \
    gload16(pB + (OFF), AB(2 * (BUF) + 1) + uw * 512);                          \
    gload16(pB + (OFF) + JROW, AB(2 * (BUF) + 1) + uw * 512 + 4096);            \
  }
#define COMPUTE(BUF)                                                            \
  {                                                                             \
    const unsigned short* Ab = AB(2 * (BUF));                                   \
    const unsigned short* Bb = AB(2 * (BUF) + 1);                               \
    short8 af[8], bfr[4];                                                       \
    _Pragma("unroll")                                                           \
    for (int mi = 0; mi < 8; ++mi)                                              \
      af[mi] = *(const short8*)&Ab[(wm * 128 + mi * 16 + r16) * 32 + rc];       \
    _Pragma("unroll")                                                           \
    for (int ni = 0; ni < 4; ++ni)                                              \
      bfr[ni] = *(const short8*)&Bb[(wn * 64 + ni * 16 + r16) * 32 + rc];       \
    _Pragma("unroll")                                                           \
    for (int mi = 0; mi < 8; ++mi)                                              \
      _Pragma("unroll")                                                         \
      for (int ni = 0; ni < 4; ++ni)                                            \
        acc[mi][ni] = __builtin_amdgcn_mfma_f32_16x16x32_bf16(af[mi], bfr[ni],  \
                                                              acc[mi][ni], 0, 0, 0); \
  }
#define WB4 asm volatile("s_waitcnt vmcnt(4) lgkmcnt(0)\n\ts_barrier" ::: "memory")
#define WB0 asm volatile("s_waitcnt vmcnt(0) lgkmcnt(0)\n\ts_barrier" ::: "memory")

  // prologue: tiles 0,1 staged; tile 0 guaranteed landed
  STAGE(0, 0);
  STAGE(1, 32);
  WB4;

#pragma unroll 1
  for (int g = 0; g < 7; ++g) {                       // kt = 3g .. 3g+2 (0..20)
    STAGE(2, 64);  COMPUTE(0); WB4;                   // stage 3g+2
    STAGE(0, 96);  COMPUTE(1); WB4;                   // stage 3g+3
    STAGE(1, 128); COMPUTE(2); WB4;                   // stage 3g+4
    pA += 96; pB += 96;
  }
  STAGE(2, 64); COMPUTE(0); WB4;                      // kt=21, stage 23
  COMPUTE(1); WB0;                                    // kt=22, drain 23
  COMPUTE(2);                                         // kt=23

#undef STAGE
#undef COMPUTE
#undef WB4
#undef WB0

  // ---- epilogue: per-wave padded LDS scratch (stride 68), coalesced stores.
  // col = n0 + wn*64 + (ni*16+r16): h uniform per wave, d = ni*16+r16.
  float* scr = (float*)smem + uw * 1088;              // 16 rows x 68 floats
  bool is_k = (n0 < 768);
  int h = (is_k ? (n0 >> 6) : ((n0 - 768) >> 6)) + wn;
  int bq = (int)(m0 >> 12);                           // uniform (4096 % 256 == 0)
  int nb = (int)(m0 & 4095) + wm * 128;

#pragma unroll
  for (int mi = 0; mi < 8; ++mi) {
#pragma unroll
    for (int ni = 0; ni < 4; ++ni)
#pragma unroll
      for (int r = 0; r < 4; ++r)
        scr[(gk * 4 + r) * 68 + ni * 16 + r16] = acc[mi][ni][r];
    int nbase = nb + mi * 16;
    if (is_k) {
#pragma unroll
      for (int p = 0; p < 2; ++p) {
        int row = p * 8 + (lane >> 3), d0 = (lane & 7) << 3;
        float4 aa = *(const float4*)&scr[row * 68 + d0];
        float4 bb = *(const float4*)&scr[row * 68 + d0 + 4];
        short8 hh;
        hh[0] = (short)f2bf(aa.x); hh[1] = (short)f2bf(aa.y);
        hh[2] = (short)f2bf(aa.z); hh[3] = (short)f2bf(aa.w);
        hh[4] = (short)f2bf(bb.x); hh[5] = (short)f2bf(bb.y);
        hh[6] = (short)f2bf(bb.z); hh[7] = (short)f2bf(bb.w);
        *(short8*)&k_ws[((long)(bq * 12 + h) * 4096 + nbase + row) * 64 + d0] = hh;
      }
    } else {
#pragma unroll
      for (int p = 0; p < 4; ++p) {
        int row = p * 4 + (lane >> 4), d0 = (lane & 15) << 2;
        float4 aa = *(const float4*)&scr[row * 68 + d0];
        *(float4*)&v_out[((long)(bq * 12 + h) * 4096 + nbase + row) * 64 + d0] = aa;
      }
    }
  }
#undef AB
}

// ---------------------------------------------------------------------------
// Kernel 3-FALLBACK (R1 version, used when ws_size is too small)
// ---------------------------------------------------------------------------
__global__ __launch_bounds__(256) void gemm_kv(const float* __restrict__ x,
                                               const unsigned short* __restrict__ Wt,
                                               unsigned short* __restrict__ k_ws,
                                               float* __restrict__ v_out) {
  __shared__ char lds[32768];
  int bid = blockIdx.x;
  int lb = (bid & 7) * 3072 + (bid >> 3);
  int mt = lb / 12, nt = lb - mt * 12;
  long m0 = (long)mt * 128; int n0 = nt * 128;
  int tid = threadIdx.x, lane = tid & 63;
  int wid = tid >> 6, wm = wid >> 1, wn = wid & 1;
  int rlo = lane & 15, gk = lane >> 4;

  const float* xs = x + m0 * 768;
  const unsigned short* wp = Wt + (long)n0 * 768;

  int arow0 = tid >> 3, ak4 = (tid & 7) << 2;
  int bn = tid >> 1, bg = (tid & 1) << 1;

  f32x4 acc[4][4];
#pragma unroll
  for (int i = 0; i < 4; ++i)
#pragma unroll
    for (int j = 0; j < 4; ++j) acc[i][j] = (f32x4){0.f, 0.f, 0.f, 0.f};

  float4 fA[4]; short8 wB[2];
#pragma unroll
  for (int it = 0; it < 4; ++it) {
    int row = it * 32 + arow0;
    fA[it] = *(const float4*)(xs + (long)row * 768 + ak4);
  }
#pragma unroll
  for (int i = 0; i < 2; ++i)
    wB[i] = *(const short8*)(wp + (long)bn * 768 + (bg + i) * 8);
#pragma unroll
  for (int it = 0; it < 4; ++it) {
    int row = it * 32 + arow0;
    short4v h;
    h[0] = (short)f2bf(fA[it].x); h[1] = (short)f2bf(fA[it].y);
    h[2] = (short)f2bf(fA[it].z); h[3] = (short)f2bf(fA[it].w);
    *(short4v*)(lds + row * 64 + ((ak4 * 2) ^ (((row >> 1) & 3) << 4))) = h;
  }
#pragma unroll
  for (int i = 0; i < 2; ++i)
    *(short8*)(lds + 16384 + bn * 64 + (((bg + i) * 16) ^ (((bn >> 1) & 3) << 4))) = wB[i];
  __syncthreads();

#pragma unroll 2
  for (int ks = 0; ks < 24; ++ks) {
    char* Ab = lds + (ks & 1) * 8192;
    char* Bb = lds + 16384 + (ks & 1) * 8192;
    bool pf = (ks + 1 < 24);
    if (pf) {
#pragma unroll
      for (int it = 0; it < 4; ++it) {
        int row = it * 32 + arow0;
        fA[it] = *(const float4*)(xs + (long)row * 768 + (ks + 1) * 32 + ak4);
      }
#pragma unroll
      for (int i = 0; i < 2; ++i)
        wB[i] = *(const short8*)(wp + (long)bn * 768 + (ks + 1) * 32 + (bg + i) * 8);
    }
    short8 af[4], bfr[4];
#pragma unroll
    for (int mi = 0; mi < 4; ++mi) {
      int row = wm * 64 + mi * 16 + rlo;
      af[mi] = *(const short8*)(Ab + row * 64 + ((gk * 16) ^ (((row >> 1) & 3) << 4)));
    }
#pragma unroll
    for (int ni = 0; ni < 4; ++ni) {
      int n = wn * 64 + ni * 16 + rlo;
      bfr[ni] = *(const short8*)(Bb + n * 64 + ((gk * 16) ^ (((n >> 1) & 3) << 4)));
    }
#pragma unroll
    for (int mi = 0; mi < 4; ++mi)
#pragma unroll
      for (int ni = 0; ni < 4; ++ni)
        acc[mi][ni] = __builtin_amdgcn_mfma_f32_16x16x32_bf16(af[mi], bfr[ni], acc[mi][ni], 0, 0, 0);
    if (pf) {
      char* An = lds + ((ks + 1) & 1) * 8192;
      char* Bn = lds + 16384 + ((ks + 1) & 1) * 8192;
#pragma unroll
      for (int it = 0; it < 4; ++it) {
        int row = it * 32 + arow0;
        short4v h;
        h[0] = (short)f2bf(fA[it].x); h[1] = (short)f2bf(fA[it].y);
        h[2] = (short)f2bf(fA[it].z); h[3] = (short)f2bf(fA[it].w);
        *(short4v*)(An + row * 64 + ((ak4 * 2) ^ (((row >> 1) & 3) << 4))) = h;
      }
#pragma unroll
      for (int i = 0; i < 2; ++i)
        *(short8*)(Bn + bn * 64 + (((bg + i) * 16) ^ (((bn >> 1) & 3) << 4))) = wB[i];
    }
    __syncthreads();
  }

  bool is_k = (n0 < 768);
  int cb = is_k ? n0 : n0 - 768;
#pragma unroll
  for (int ni = 0; ni < 4; ++ni) {
    int cc = cb + wn * 64 + ni * 16 + rlo;
    int h = cc >> 6, d = cc & 63;
#pragma unroll
    for (int mi = 0; mi < 4; ++mi) {
#pragma unroll
      for (int r = 0; r < 4; ++r) {
        long m = m0 + wm * 64 + mi * 16 + gk * 4 + r;
        int b = (int)(m >> 12), n = (int)(m & 4095);
        long off = ((long)(b * 12 + h) * 4096 + n) * 64 + d;
        float val = acc[mi][ni][r];
        if (is_k) k_ws[off] = f2bf(val);
        else      v_out[off] = val;
      }
    }
  }
}

// ---------------------------------------------------------------------------
// Kernel 4: fused attention per (b,h). 512 threads / 8 waves.
// Phase 3 writes the normalized attn in-place.
// ---------------------------------------------------------------------------
__global__ __launch_bounds__(512) void attn_fused(const unsigned short* __restrict__ k_ws,
                                                  const unsigned short* __restrict__ q_ws,
                                                  const float* __restrict__ v_glob,
                                                  float* __restrict__ attn_out,
                                                  float* __restrict__ preproj) {
  __shared__ float red[8][16];
  __shared__ float rowmax[16];
  __shared__ float rowinv[16];
  __shared__ float scratch[8 * 256];

  int tid = threadIdx.x, lane = tid & 63, w = tid >> 6;
  int bh = blockIdx.x;
  int r16 = lane & 15, gk = lane >> 4;
  int trc = (r16 < 10) ? r16 : 9;

  const unsigned short* kp = k_ws + (long)bh * (4096 * 64);
  const unsigned short* qp = q_ws + (long)bh * 1024;
  float* sraw = attn_out + (long)bh * 40960;
  const float* vp = v_glob + (long)bh * (4096 * 64);

  short8 qf0 = *(const short8*)(qp + r16 * 64 + gk * 8);
  short8 qf1 = *(const short8*)(qp + r16 * 64 + 32 + gk * 8);

  // ---- Phase 1: scores + row max ----
  float pmax = -3.0e38f;
  for (int ch = 0; ch < 32; ++ch) {
    int n0 = (w * 32 + ch) << 4;
    short8 kf0 = *(const short8*)(kp + (long)(n0 + r16) * 64 + gk * 8);
    short8 kf1 = *(const short8*)(kp + (long)(n0 + r16) * 64 + 32 + gk * 8);
    f32x4 d4 = (f32x4){0.f, 0.f, 0.f, 0.f};
    d4 = __builtin_amdgcn_mfma_f32_16x16x32_bf16(kf0, qf0, d4, 0, 0, 0);
    d4 = __builtin_amdgcn_mfma_f32_16x16x32_bf16(kf1, qf1, d4, 0, 0, 0);
    float sv[4];
#pragma unroll
    for (int r = 0; r < 4; ++r) {
      int n = n0 + gk * 4 + r;
      float s = d4[r];
      if (n < 10 && n != r16) s = -1e30f;
      sv[r] = s;
      pmax = fmaxf(pmax, s);
    }
    if (r16 < 10)
      *(float4*)(sraw + r16 * 4096 + n0 + gk * 4) = make_float4(sv[0], sv[1], sv[2], sv[3]);
  }
  pmax = fmaxf(pmax, __shfl_xor(pmax, 16));
  pmax = fmaxf(pmax, __shfl_xor(pmax, 32));
  if (lane < 16) red[w][lane] = pmax;
  __syncthreads();
  if (tid < 16) {
    float m = red[0][tid];
#pragma unroll
    for (int i = 1; i < 8; ++i) m = fmaxf(m, red[i][tid]);
    rowmax[tid] = m;
  }
  __syncthreads();

  // ---- Phase 2: row sum ----
  float mx = rowmax[trc];
  float psum = 0.f;
  for (int ch = 0; ch < 16; ++ch) {
    int n0 = ((w * 16 + ch) << 5) + gk * 8;
    float4 a = *(const float4*)(sraw + trc * 4096 + n0);
    float4 b2 = *(const float4*)(sraw + trc * 4096 + n0 + 4);
    psum += __expf(a.x - mx) + __expf(a.y - mx) + __expf(a.z - mx) + __expf(a.w - mx)
          + __expf(b2.x - mx) + __expf(b2.y - mx) + __expf(b2.z - mx) + __expf(b2.w - mx);
  }
  psum += __shfl_xor(psum, 16);
  psum += __shfl_xor(psum, 32);
  if (lane < 16) red[w][lane] = psum;
  __syncthreads();
  if (tid < 16) {
    float s = 0.f;
#pragma unroll
    for (int i = 0; i < 8; ++i) s += red[i][tid];
    rowinv[tid] = 1.0f / s;
  }
  __syncthreads();

  // ---- Phase 3: PV + in-place normalized write (final attn) ----
  int dc = w & 3, half = w >> 2;
  int d0 = dc << 4;
  float inv = rowinv[trc];
  f32x4 acc = (f32x4){0.f, 0.f, 0.f, 0.f};
  for (int kk = 0; kk < 64; ++kk) {
    int nr = half * 2048 + kk * 32 + gk * 8;
    float* sp = sraw + trc * 4096 + nr;
    float4 s0 = *(const float4*)(sp);
    float4 s1 = *(const float4*)(sp + 4);
    float p0 = __expf(s0.x - mx) * inv, p1 = __expf(s0.y - mx) * inv;
    float p2 = __expf(s0.z - mx) * inv, p3 = __expf(s0.w - mx) * inv;
    float p4 = __expf(s1.x - mx) * inv, p5 = __expf(s1.y - mx) * inv;
    float p6 = __expf(s1.z - mx) * inv, p7 = __expf(s1.w - mx) * inv;
    if (r16 < 10) {
      *(float4*)(sp)     = make_float4(p0, p1, p2, p3);
      *(float4*)(sp + 4) = make_float4(p4, p5, p6, p7);
    }
    short8 pa;
    pa[0] = (short)f2bf(p0); pa[1] = (short)f2bf(p1);
    pa[2] = (short)f2bf(p2); pa[3] = (short)f2bf(p3);
    pa[4] = (short)f2bf(p4); pa[5] = (short)f2bf(p5);
    pa[6] = (short)f2bf(p6); pa[7] = (short)f2bf(p7);
    short8 vb;
    const float* vrow = vp + (long)nr * 64 + d0 + r16;
#pragma unroll
    for (int j = 0; j < 8; ++j) vb[j] = (short)f2bf(vrow[j * 64]);
    acc = __builtin_amdgcn_mfma_f32_16x16x32_bf16(pa, vb, acc, 0, 0, 0);
  }
#pragma unroll
  for (int r = 0; r < 4; ++r)
    scratch[w * 256 + (gk * 4 + r) * 16 + r16] = acc[r];
  __syncthreads();

  int b = bh / 12, h = bh - b * 12;
  for (int idx = tid; idx < 640; idx += 512) {
    int tt = idx >> 6, d = idx & 63;
    int c = d >> 4, dl = d & 15;
    float s = scratch[c * 256 + tt * 16 + dl] + scratch[(c + 4) * 256 + tt * 16 + dl];
    preproj[((long)b * 10 + tt) * 768 + h * 64 + d] = s;
  }
}

// ---------------------------------------------------------------------------
// Kernel 5: x_cls = preproj @ Wp + bp
// ---------------------------------------------------------------------------
__global__ __launch_bounds__(256) void proj_out_k(const float* __restrict__ preproj,
                                                  const float* __restrict__ Wp,
                                                  const float* __restrict__ bp,
                                                  float* __restrict__ out0) {
  int b = blockIdx.x, tid = threadIdx.x;
  __shared__ float xr[7680];
  const float* pp = preproj + (long)b * 7680;
  for (int i = tid; i < 7680; i += 256) xr[i] = pp[i];
  __syncthreads();
  float acc[10][3];
#pragma unroll
  for (int t = 0; t < 10; ++t) { acc[t][0] = 0.f; acc[t][1] = 0.f; acc[t][2] = 0.f; }
  for (int k = 0; k < 768; ++k) {
    const float* wr = Wp + (long)k * 768;
    float w0 = wr[tid], w1 = wr[tid + 256], w2 = wr[tid + 512];
#pragma unroll
    for (int t = 0; t < 10; ++t) {
      float xv = xr[t * 768 + k];
      acc[t][0] += xv * w0; acc[t][1] += xv * w1; acc[t][2] += xv * w2;
    }
  }
  float b0 = bp[tid], b1 = bp[tid + 256], b2 = bp[tid + 512];
  float* op = out0 + (long)b * 7680;
#pragma unroll
  for (int t = 0; t < 10; ++t) {
    op[t * 768 + tid]       = acc[t][0] + b0;
    op[t * 768 + tid + 256] = acc[t][1] + b1;
    op[t * 768 + tid + 512] = acc[t][2] + b2;
  }
}

// ---------------------------------------------------------------------------
extern "C" void kernel_launch(void* const* d_in, const int* in_sizes, int n_in,
                              void* d_out, int out_size, void* d_ws, size_t ws_size,
                              hipStream_t stream) {
  (void)in_sizes; (void)n_in; (void)out_size;
  const float* x  = (const float*)d_in[0];
  const float* Wq = (const float*)d_in[1];
  const float* Wk = (const float*)d_in[2];
  const float* Wv = (const float*)d_in[3];
  const float* Wp = (const float*)d_in[4];
  const float* bp = (const float*)d_in[5];

  float* out      = (float*)d_out;
  float* attn_out = out + 491520;                 // [64,12,10,4096]
  float* v_out    = out + 31948800;               // [64,12,4096,64]

  char* ws = (char*)d_ws;
  const size_t NEED_BIG = 811204608;              // x_bf16 + k_ws + small

  if (ws_size >= NEED_BIG) {
    unsigned short* x_bf16 = (unsigned short*)(ws);               // 402,653,184 B
    unsigned short* k_ws = (unsigned short*)(ws + 402653184);     // 402,653,184 B
    unsigned short* q_ws = (unsigned short*)(ws + 805306368);     //   1,572,864 B
    unsigned short* Wt   = (unsigned short*)(ws + 806879232);     //   2,359,296 B
    float* preproj       = (float*)(ws + 809238528);              //   1,966,080 B

    conv_x<<<dim3(2048), dim3(256), 0, stream>>>(x, x_bf16);
    prep_w<<<dim3(4608), dim3(256), 0, stream>>>(Wk, Wv, Wt);
    q_proj<<<dim3(64), dim3(256), 0, stream>>>(x, Wq, q_ws);
    gemm_kv6<<<dim3(6144), dim3(512), 0, stream>>>(x_bf16, Wt, k_ws, v_out);
    attn_fused<<<dim3(768), dim3(512), 0, stream>>>(k_ws, q_ws, v_out, attn_out, preproj);
    proj_out_k<<<dim3(64), dim3(256), 0, stream>>>(preproj, Wp, bp, out);
  } else {
    unsigned short* k_ws = (unsigned short*)(ws);                 // 402,653,184 B
    unsigned short* q_ws = (unsigned short*)(ws + 402653184);
    unsigned short* Wt   = (unsigned short*)(ws + 404226048);
    float* preproj       = (float*)(ws + 406585344);

    prep_w<<<dim3(4608), dim3(256), 0, stream>>>(Wk, Wv, Wt);
    q_proj<<<dim3(64), dim3(256), 0, stream>>>(x, Wq, q_ws);
    gemm_kv<<<dim3(24576), dim3(256), 0, stream>>>(x, Wt, k_ws, v_out);
    attn_fused<<<dim3(768), dim3(512), 0, stream>>>(k_ws, q_ws, v_out, attn_out, preproj);
    proj_out_k<<<dim3(64), dim3(256), 0, stream>>>(preproj, Wp, bp, out);
  }
}

// Round 7
// 1617.329 us; speedup vs baseline: 1.1961x; 1.0064x over previous
//
#include <hip/hip_runtime.h>

typedef __attribute__((ext_vector_type(8))) short short8;
typedef __attribute__((ext_vector_type(4))) short short4v;
typedef __attribute__((ext_vector_type(4))) float f32x4;

__device__ __forceinline__ unsigned short f2bf(float f) {
  union { float f; unsigned u; } v; v.f = f;
  unsigned r = v.u + 0x7FFFu + ((v.u >> 16) & 1u);
  return (unsigned short)(r >> 16);
}

__device__ __forceinline__ void gload16(const void* g, void* l) {
  __builtin_amdgcn_global_load_lds(
      (const __attribute__((address_space(1))) void*)g,
      (__attribute__((address_space(3))) void*)l, 16, 0, 0);
}

// ---------------------------------------------------------------------------
// Kernel 0: x (fp32) -> x_bf16, vectorized 8 elems/thread
// ---------------------------------------------------------------------------
__global__ __launch_bounds__(256) void conv_x(const float* __restrict__ x,
                                              unsigned short* __restrict__ xb) {
  const long total = 25165824;                        // 201326592 / 8
  long stride = (long)gridDim.x * 256;
  for (long u = blockIdx.x * 256 + threadIdx.x; u < total; u += stride) {
    const float* p = x + u * 8;
    float4 a = *(const float4*)p;
    float4 b = *(const float4*)(p + 4);
    short8 h;
    h[0] = (short)f2bf(a.x); h[1] = (short)f2bf(a.y);
    h[2] = (short)f2bf(a.z); h[3] = (short)f2bf(a.w);
    h[4] = (short)f2bf(b.x); h[5] = (short)f2bf(b.y);
    h[6] = (short)f2bf(b.z); h[7] = (short)f2bf(b.w);
    *(short8*)(xb + u * 8) = h;
  }
}

// ---------------------------------------------------------------------------
// Kernel 1: Wt[n][k] = bf16( [Wk | Wv](k, n) )   (B^T layout, n in [0,1536))
// ---------------------------------------------------------------------------
__global__ __launch_bounds__(256) void prep_w(const float* __restrict__ Wk,
                                              const float* __restrict__ Wv,
                                              unsigned short* __restrict__ Wt) {
  int idx = blockIdx.x * 256 + threadIdx.x;           // 1536*768 elements
  int n = idx / 768, k = idx - n * 768;
  float w = (n < 768) ? Wk[k * 768 + n] : Wv[k * 768 + (n - 768)];
  Wt[idx] = f2bf(w);
}

// ---------------------------------------------------------------------------
// Kernel 2: q = scale * x[:, :10] @ Wq  -> q_ws[b][h][16][64] bf16 (rows 10..15 = 0)
// ---------------------------------------------------------------------------
__global__ __launch_bounds__(256) void q_proj(const float* __restrict__ x,
                                              const float* __restrict__ Wq,
                                              unsigned short* __restrict__ q_ws) {
  int b = blockIdx.x, tid = threadIdx.x;
  __shared__ float xr[7680];
  const float* xp = x + (long)b * 4096 * 768;
  for (int i = tid; i < 7680; i += 256) xr[i] = xp[i];
  for (int i = tid; i < 12 * 6 * 64; i += 256) {
    int h = i / 384, rem = i - h * 384;
    int t = 10 + rem / 64, d = rem & 63;
    q_ws[(((long)(b * 12 + h) * 16 + t) << 6) + d] = 0;
  }
  __syncthreads();
  float acc[10][3];
#pragma unroll
  for (int t = 0; t < 10; ++t) { acc[t][0] = 0.f; acc[t][1] = 0.f; acc[t][2] = 0.f; }
  for (int k = 0; k < 768; ++k) {
    const float* wr = Wq + (long)k * 768;
    float w0 = wr[tid], w1 = wr[tid + 256], w2 = wr[tid + 512];
#pragma unroll
    for (int t = 0; t < 10; ++t) {
      float xv = xr[t * 768 + k];
      acc[t][0] += xv * w0; acc[t][1] += xv * w1; acc[t][2] += xv * w2;
    }
  }
#pragma unroll
  for (int t = 0; t < 10; ++t) {
#pragma unroll
    for (int j = 0; j < 3; ++j) {
      int c = tid + j * 256;
      int h = c >> 6, d = c & 63;
      q_ws[(((long)(b * 12 + h) * 16 + t) << 6) + d] = f2bf(acc[t][j] * 0.125f);
    }
  }
}

// ---------------------------------------------------------------------------
// Kernel 3 (R7): 256x256 tile, BK=32, 8 waves (2Mx4N), TRIPLE-buffered
// gload_lds, counted vmcnt(4) barriers, CORRECT conflict-free swizzle
// key = (row>>1)&3 (R6's row&3 key was 4-way conflicted: bank_start =
// 16*(r16&1)+4*(gk^key) needs key bits disjoint from the parity term).
// ---------------------------------------------------------------------------
__global__ __launch_bounds__(512, 2) void gemm_kv7(const unsigned short* __restrict__ xb,
                                                   const unsigned short* __restrict__ Wt,
                                                   unsigned short* __restrict__ k_ws,
                                                   float* __restrict__ v_out) {
  __shared__ char smem[98304];                        // 6 x 16KB: A0 B0 A1 B1 A2 B2
#define AB(i) ((unsigned short*)(smem + (i) * 16384))

  int bid = blockIdx.x;
  int lb = (bid & 7) * 768 + (bid >> 3);              // XCD swizzle (6144 % 8 == 0)
  int mt = lb / 6, nt = lb - mt * 6;
  long m0 = (long)mt * 256; int n0 = nt * 256;
  int tid = threadIdx.x, lane = tid & 63;
  int uw = __builtin_amdgcn_readfirstlane(tid >> 6);  // uniform wave id 0..7
  int wm = uw >> 2, wn = uw & 3;                      // 2 M-waves x 4 N-waves
  int r16 = lane & 15, gk = lane >> 4;

  const unsigned short* xs = xb + m0 * 768;
  const unsigned short* wp = Wt + (long)n0 * 768;

  // staging: lane l covers (row = uw*16 + (l>>2), chunk = l&3); source chunk
  // pre-swizzled so LDS chunk c holds global chunk c ^ ((row>>1)&3)
  int srow = lane >> 2;
  int schunk = ((lane & 3) ^ ((srow >> 1) & 3)) << 3; // source offset in elems
  const unsigned short* pA = xs + (long)(uw * 16 + srow) * 768 + schunk;
  const unsigned short* pB = wp + (long)(uw * 16 + srow) * 768 + schunk;
  const long JROW = 128 * 768;                        // second 128-row group

  // frag read swizzle: chunk = gk ^ ((r16>>1)&3)  (row bits 1-2, conflict-free)
  int rc = (gk ^ ((r16 >> 1) & 3)) << 3;              // elem offset within row

  f32x4 acc[8][4];
#pragma unroll
  for (int i = 0; i < 8; ++i)
#pragma unroll
    for (int j = 0; j < 4; ++j) acc[i][j] = (f32x4){0.f, 0.f, 0.f, 0.f};

#define STAGE(BUF, OFF)                                                         \
  {                                                                             \
    gload16(pA + (OFF), AB(2 * (BUF)) + uw * 512);                              \
    gload16(pA + (OFF) + JROW, AB(2 * (BUF)) + uw * 512 + 4096);                \
    gload16(pB + (OFF), AB(2 * (BUF) + 1) + uw * 512);                          \
    gload16(pB + (OFF) + JROW, AB(2 * (BUF) + 1) + uw * 512 + 4096);            \
  }
#define COMPUTE(BUF)                                                            \
  {                                                                             \
    const unsigned short* Ab = AB(2 * (BUF));                                   \
    const unsigned short* Bb = AB(2 * (BUF) + 1);                               \
    short8 af[8], bfr[4];                                                       \
    _Pragma("unroll")                                                           \
    for (int mi = 0; mi < 8; ++mi)                                              \
      af[mi] = *(const short8*)&Ab[(wm * 128 + mi * 16 + r16) * 32 + rc];       \
    _Pragma("unroll")                                                           \
    for (int ni = 0; ni < 4; ++ni)                                              \
      bfr[ni] = *(const short8*)&Bb[(wn * 64 + ni * 16 + r16) * 32 + rc];       \
    _Pragma("unroll")                                                           \
    for (int mi = 0; mi < 8; ++mi)                                              \
      _Pragma("unroll")                                                         \
      for (int ni = 0; ni < 4; ++ni)                                            \
        acc[mi][ni] = __builtin_amdgcn_mfma_f32_16x16x32_bf16(af[mi], bfr[ni],  \
                                                              acc[mi][ni], 0, 0, 0); \
  }
#define WB4 asm volatile("s_waitcnt vmcnt(4) lgkmcnt(0)\n\ts_barrier" ::: "memory")
#define WB0 asm volatile("s_waitcnt vmcnt(0) lgkmcnt(0)\n\ts_barrier" ::: "memory")

  // prologue: tiles 0,1 staged; tile 0 guaranteed landed
  STAGE(0, 0);
  STAGE(1, 32);
  WB4;

#pragma unroll 1
  for (int g = 0; g < 7; ++g) {                       // kt = 3g .. 3g+2 (0..20)
    STAGE(2, 64);  COMPUTE(0); WB4;                   // stage 3g+2
    STAGE(0, 96);  COMPUTE(1); WB4;                   // stage 3g+3
    STAGE(1, 128); COMPUTE(2); WB4;                   // stage 3g+4
    pA += 96; pB += 96;
  }
  STAGE(2, 64); COMPUTE(0); WB4;                      // kt=21, stage 23
  COMPUTE(1); WB0;                                    // kt=22, drain 23
  COMPUTE(2);                                         // kt=23

#undef STAGE
#undef COMPUTE
#undef WB4
#undef WB0

  // ---- epilogue: per-wave padded LDS scratch (stride 68), coalesced stores ----
  float* scr = (float*)smem + uw * 1088;              // 16 rows x 68 floats
  bool is_k = (n0 < 768);
  int h = (is_k ? (n0 >> 6) : ((n0 - 768) >> 6)) + wn;
  int bq = (int)(m0 >> 12);                           // uniform (4096 % 256 == 0)
  int nb = (int)(m0 & 4095) + wm * 128;

#pragma unroll
  for (int mi = 0; mi < 8; ++mi) {
#pragma unroll
    for (int ni = 0; ni < 4; ++ni)
#pragma unroll
      for (int r = 0; r < 4; ++r)
        scr[(gk * 4 + r) * 68 + ni * 16 + r16] = acc[mi][ni][r];
    int nbase = nb + mi * 16;
    if (is_k) {
#pragma unroll
      for (int p = 0; p < 2; ++p) {
        int row = p * 8 + (lane >> 3), d0 = (lane & 7) << 3;
        float4 aa = *(const float4*)&scr[row * 68 + d0];
        float4 bb = *(const float4*)&scr[row * 68 + d0 + 4];
        short8 hh;
        hh[0] = (short)f2bf(aa.x); hh[1] = (short)f2bf(aa.y);
        hh[2] = (short)f2bf(aa.z); hh[3] = (short)f2bf(aa.w);
        hh[4] = (short)f2bf(bb.x); hh[5] = (short)f2bf(bb.y);
        hh[6] = (short)f2bf(bb.z); hh[7] = (short)f2bf(bb.w);
        *(short8*)&k_ws[((long)(bq * 12 + h) * 4096 + nbase + row) * 64 + d0] = hh;
      }
    } else {
#pragma unroll
      for (int p = 0; p < 4; ++p) {
        int row = p * 4 + (lane >> 4), d0 = (lane & 15) << 2;
        float4 aa = *(const float4*)&scr[row * 68 + d0];
        *(float4*)&v_out[((long)(bq * 12 + h) * 4096 + nbase + row) * 64 + d0] = aa;
      }
    }
  }
#undef AB
}

// ---------------------------------------------------------------------------
// Kernel 3-FALLBACK (R1 version, used when ws_size is too small)
// ---------------------------------------------------------------------------
__global__ __launch_bounds__(256) void gemm_kv(const float* __restrict__ x,
                                               const unsigned short* __restrict__ Wt,
                                               unsigned short* __restrict__ k_ws,
                                               float* __restrict__ v_out) {
  __shared__ char lds[32768];
  int bid = blockIdx.x;
  int lb = (bid & 7) * 3072 + (bid >> 3);
  int mt = lb / 12, nt = lb - mt * 12;
  long m0 = (long)mt * 128; int n0 = nt * 128;
  int tid = threadIdx.x, lane = tid & 63;
  int wid = tid >> 6, wm = wid >> 1, wn = wid & 1;
  int rlo = lane & 15, gk = lane >> 4;

  const float* xs = x + m0 * 768;
  const unsigned short* wp = Wt + (long)n0 * 768;

  int arow0 = tid >> 3, ak4 = (tid & 7) << 2;
  int bn = tid >> 1, bg = (tid & 1) << 1;

  f32x4 acc[4][4];
#pragma unroll
  for (int i = 0; i < 4; ++i)
#pragma unroll
    for (int j = 0; j < 4; ++j) acc[i][j] = (f32x4){0.f, 0.f, 0.f, 0.f};

  float4 fA[4]; short8 wB[2];
#pragma unroll
  for (int it = 0; it < 4; ++it) {
    int row = it * 32 + arow0;
    fA[it] = *(const float4*)(xs + (long)row * 768 + ak4);
  }
#pragma unroll
  for (int i = 0; i < 2; ++i)
    wB[i] = *(const short8*)(wp + (long)bn * 768 + (bg + i) * 8);
#pragma unroll
  for (int it = 0; it < 4; ++it) {
    int row = it * 32 + arow0;
    short4v h;
    h[0] = (short)f2bf(fA[it].x); h[1] = (short)f2bf(fA[it].y);
    h[2] = (short)f2bf(fA[it].z); h[3] = (short)f2bf(fA[it].w);
    *(short4v*)(lds + row * 64 + ((ak4 * 2) ^ (((row >> 1) & 3) << 4))) = h;
  }
#pragma unroll
  for (int i = 0; i < 2; ++i)
    *(short8*)(lds + 16384 + bn * 64 + (((bg + i) * 16) ^ (((bn >> 1) & 3) << 4))) = wB[i];
  __syncthreads();

#pragma unroll 2
  for (int ks = 0; ks < 24; ++ks) {
    char* Ab = lds + (ks & 1) * 8192;
    char* Bb = lds + 16384 + (ks & 1) * 8192;
    bool pf = (ks + 1 < 24);
    if (pf) {
#pragma unroll
      for (int it = 0; it < 4; ++it) {
        int row = it * 32 + arow0;
        fA[it] = *(const float4*)(xs + (long)row * 768 + (ks + 1) * 32 + ak4);
      }
#pragma unroll
      for (int i = 0; i < 2; ++i)
        wB[i] = *(const short8*)(wp + (long)bn * 768 + (ks + 1) * 32 + (bg + i) * 8);
    }
    short8 af[4], bfr[4];
#pragma unroll
    for (int mi = 0; mi < 4; ++mi) {
      int row = wm * 64 + mi * 16 + rlo;
      af[mi] = *(const short8*)(Ab + row * 64 + ((gk * 16) ^ (((row >> 1) & 3) << 4)));
    }
#pragma unroll
    for (int ni = 0; ni < 4; ++ni) {
      int n = wn * 64 + ni * 16 + rlo;
      bfr[ni] = *(const short8*)(Bb + n * 64 + ((gk * 16) ^ (((n >> 1) & 3) << 4)));
    }
#pragma unroll
    for (int mi = 0; mi < 4; ++mi)
#pragma unroll
      for (int ni = 0; ni < 4; ++ni)
        acc[mi][ni] = __builtin_amdgcn_mfma_f32_16x16x32_bf16(af[mi], bfr[ni], acc[mi][ni], 0, 0, 0);
    if (pf) {
      char* An = lds + ((ks + 1) & 1) * 8192;
      char* Bn = lds + 16384 + ((ks + 1) & 1) * 8192;
#pragma unroll
      for (int it = 0; it < 4; ++it) {
        int row = it * 32 + arow0;
        short4v h;
        h[0] = (short)f2bf(fA[it].x); h[1] = (short)f2bf(fA[it].y);
        h[2] = (short)f2bf(fA[it].z); h[3] = (short)f2bf(fA[it].w);
        *(short4v*)(An + row * 64 + ((ak4 * 2) ^ (((row >> 1) & 3) << 4))) = h;
      }
#pragma unroll
      for (int i = 0; i < 2; ++i)
        *(short8*)(Bn + bn * 64 + (((bg + i) * 16) ^ (((bn >> 1) & 3) << 4))) = wB[i];
    }
    __syncthreads();
  }

  bool is_k = (n0 < 768);
  int cb = is_k ? n0 : n0 - 768;
#pragma unroll
  for (int ni = 0; ni < 4; ++ni) {
    int cc = cb + wn * 64 + ni * 16 + rlo;
    int h = cc >> 6, d = cc & 63;
#pragma unroll
    for (int mi = 0; mi < 4; ++mi) {
#pragma unroll
      for (int r = 0; r < 4; ++r) {
        long m = m0 + wm * 64 + mi * 16 + gk * 4 + r;
        int b = (int)(m >> 12), n = (int)(m & 4095);
        long off = ((long)(b * 12 + h) * 4096 + n) * 64 + d;
        float val = acc[mi][ni][r];
        if (is_k) k_ws[off] = f2bf(val);
        else      v_out[off] = val;
      }
    }
  }
}

// ---------------------------------------------------------------------------
// Kernel 4: fused attention per (b,h). 512 threads / 8 waves.
// Phase 3 writes the normalized attn in-place.
// ---------------------------------------------------------------------------
__global__ __launch_bounds__(512) void attn_fused(const unsigned short* __restrict__ k_ws,
                                                  const unsigned short* __restrict__ q_ws,
                                                  const float* __restrict__ v_glob,
                                                  float* __restrict__ attn_out,
                                                  float* __restrict__ preproj) {
  __shared__ float red[8][16];
  __shared__ float rowmax[16];
  __shared__ float rowinv[16];
  __shared__ float scratch[8 * 256];

  int tid = threadIdx.x, lane = tid & 63, w = tid >> 6;
  int bh = blockIdx.x;
  int r16 = lane & 15, gk = lane >> 4;
  int trc = (r16 < 10) ? r16 : 9;

  const unsigned short* kp = k_ws + (long)bh * (4096 * 64);
  const unsigned short* qp = q_ws + (long)bh * 1024;
  float* sraw = attn_out + (long)bh * 40960;
  const float* vp = v_glob + (long)bh * (4096 * 64);

  short8 qf0 = *(const short8*)(qp + r16 * 64 + gk * 8);
  short8 qf1 = *(const short8*)(qp + r16 * 64 + 32 + gk * 8);

  // ---- Phase 1: scores + row max ----
  float pmax = -3.0e38f;
  for (int ch = 0; ch < 32; ++ch) {
    int n0 = (w * 32 + ch) << 4;
    short8 kf0 = *(const short8*)(kp + (long)(n0 + r16) * 64 + gk * 8);
    short8 kf1 = *(const short8*)(kp + (long)(n0 + r16) * 64 + 32 + gk * 8);
    f32x4 d4 = (f32x4){0.f, 0.f, 0.f, 0.f};
    d4 = __builtin_amdgcn_mfma_f32_16x16x32_bf16(kf0, qf0, d4, 0, 0, 0);
    d4 = __builtin_amdgcn_mfma_f32_16x16x32_bf16(kf1, qf1, d4, 0, 0, 0);
    float sv[4];
#pragma unroll
    for (int r = 0; r < 4; ++r) {
      int n = n0 + gk * 4 + r;
      float s = d4[r];
      if (n < 10 && n != r16) s = -1e30f;
      sv[r] = s;
      pmax = fmaxf(pmax, s);
    }
    if (r16 < 10)
      *(float4*)(sraw + r16 * 4096 + n0 + gk * 4) = make_float4(sv[0], sv[1], sv[2], sv[3]);
  }
  pmax = fmaxf(pmax, __shfl_xor(pmax, 16));
  pmax = fmaxf(pmax, __shfl_xor(pmax, 32));
  if (lane < 16) red[w][lane] = pmax;
  __syncthreads();
  if (tid < 16) {
    float m = red[0][tid];
#pragma unroll
    for (int i = 1; i < 8; ++i) m = fmaxf(m, red[i][tid]);
    rowmax[tid] = m;
  }
  __syncthreads();

  // ---- Phase 2: row sum ----
  float mx = rowmax[trc];
  float psum = 0.f;
  for (int ch = 0; ch < 16; ++ch) {
    int n0 = ((w * 16 + ch) << 5) + gk * 8;
    float4 a = *(const float4*)(sraw + trc * 4096 + n0);
    float4 b2 = *(const float4*)(sraw + trc * 4096 + n0 + 4);
    psum += __expf(a.x - mx) + __expf(a.y - mx) + __expf(a.z - mx) + __expf(a.w - mx)
          + __expf(b2.x - mx) + __expf(b2.y - mx) + __expf(b2.z - mx) + __expf(b2.w - mx);
  }
  psum += __shfl_xor(psum, 16);
  psum += __shfl_xor(psum, 32);
  if (lane < 16) red[w][lane] = psum;
  __syncthreads();
  if (tid < 16) {
    float s = 0.f;
#pragma unroll
    for (int i = 0; i < 8; ++i) s += red[i][tid];
    rowinv[tid] = 1.0f / s;
  }
  __syncthreads();

  // ---- Phase 3: PV + in-place normalized write (final attn) ----
  int dc = w & 3, half = w >> 2;
  int d0 = dc << 4;
  float inv = rowinv[trc];
  f32x4 acc = (f32x4){0.f, 0.f, 0.f, 0.f};
  for (int kk = 0; kk < 64; ++kk) {
    int nr = half * 2048 + kk * 32 + gk * 8;
    float* sp = sraw + trc * 4096 + nr;
    float4 s0 = *(const float4*)(sp);
    float4 s1 = *(const float4*)(sp + 4);
    float p0 = __expf(s0.x - mx) * inv, p1 = __expf(s0.y - mx) * inv;
    float p2 = __expf(s0.z - mx) * inv, p3 = __expf(s0.w - mx) * inv;
    float p4 = __expf(s1.x - mx) * inv, p5 = __expf(s1.y - mx) * inv;
    float p6 = __expf(s1.z - mx) * inv, p7 = __expf(s1.w - mx) * inv;
    if (r16 < 10) {
      *(float4*)(sp)     = make_float4(p0, p1, p2, p3);
      *(float4*)(sp + 4) = make_float4(p4, p5, p6, p7);
    }
    short8 pa;
    pa[0] = (short)f2bf(p0); pa[1] = (short)f2bf(p1);
    pa[2] = (short)f2bf(p2); pa[3] = (short)f2bf(p3);
    pa[4] = (short)f2bf(p4); pa[5] = (short)f2bf(p5);
    pa[6] = (short)f2bf(p6); pa[7] = (short)f2bf(p7);
    short8 vb;
    const float* vrow = vp + (long)nr * 64 + d0 + r16;
#pragma unroll
    for (int j = 0; j < 8; ++j) vb[j] = (short)f2bf(vrow[j * 64]);
    acc = __builtin_amdgcn_mfma_f32_16x16x32_bf16(pa, vb, acc, 0, 0, 0);
  }
#pragma unroll
  for (int r = 0; r < 4; ++r)
    scratch[w * 256 + (gk * 4 + r) * 16 + r16] = acc[r];
  __syncthreads();

  int b = bh / 12, h = bh - b * 12;
  for (int idx = tid; idx < 640; idx += 512) {
    int tt = idx >> 6, d = idx & 63;
    int c = d >> 4, dl = d & 15;
    float s = scratch[c * 256 + tt * 16 + dl] + scratch[(c + 4) * 256 + tt * 16 + dl];
    preproj[((long)b * 10 + tt) * 768 + h * 64 + d] = s;
  }
}

// ---------------------------------------------------------------------------
// Kernel 5: x_cls = preproj @ Wp + bp
// ---------------------------------------------------------------------------
__global__ __launch_bounds__(256) void proj_out_k(const float* __restrict__ preproj,
                                                  const float* __restrict__ Wp,
                                                  const float* __restrict__ bp,
                                                  float* __restrict__ out0) {
  int b = blockIdx.x, tid = threadIdx.x;
  __shared__ float xr[7680];
  const float* pp = preproj + (long)b * 7680;
  for (int i = tid; i < 7680; i += 256) xr[i] = pp[i];
  __syncthreads();
  float acc[10][3];
#pragma unroll
  for (int t = 0; t < 10; ++t) { acc[t][0] = 0.f; acc[t][1] = 0.f; acc[t][2] = 0.f; }
  for (int k = 0; k < 768; ++k) {
    const float* wr = Wp + (long)k * 768;
    float w0 = wr[tid], w1 = wr[tid + 256], w2 = wr[tid + 512];
#pragma unroll
    for (int t = 0; t < 10; ++t) {
      float xv = xr[t * 768 + k];
      acc[t][0] += xv * w0; acc[t][1] += xv * w1; acc[t][2] += xv * w2;
    }
  }
  float b0 = bp[tid], b1 = bp[tid + 256], b2 = bp[tid + 512];
  float* op = out0 + (long)b * 7680;
#pragma unroll
  for (int t = 0; t < 10; ++t) {
    op[t * 768 + tid]       = acc[t][0] + b0;
    op[t * 768 + tid + 256] = acc[t][1] + b1;
    op[t * 768 + tid + 512] = acc[t][2] + b2;
  }
}

// ---------------------------------------------------------------------------
extern "C" void kernel_launch(void* const* d_in, const int* in_sizes, int n_in,
                              void* d_out, int out_size, void* d_ws, size_t ws_size,
                              hipStream_t stream) {
  (void)in_sizes; (void)n_in; (void)out_size;
  const float* x  = (const float*)d_in[0];
  const float* Wq = (const float*)d_in[1];
  const float* Wk = (const float*)d_in[2];
  const float* Wv = (const float*)d_in[3];
  const float* Wp = (const float*)d_in[4];
  const float* bp = (const float*)d_in[5];

  float* out      = (float*)d_out;
  float* attn_out = out + 491520;                 // [64,12,10,4096]
  float* v_out    = out + 31948800;               // [64,12,4096,64]

  char* ws = (char*)d_ws;
  const size_t NEED_BIG = 811204608;              // x_bf16 + k_ws + small

  if (ws_size >= NEED_BIG) {
    unsigned short* x_bf16 = (unsigned short*)(ws);               // 402,653,184 B
    unsigned short* k_ws = (unsigned short*)(ws + 402653184);     // 402,653,184 B
    unsigned short* q_ws = (unsigned short*)(ws + 805306368);     //   1,572,864 B
    unsigned short* Wt   = (unsigned short*)(ws + 806879232);     //   2,359,296 B
    float* preproj       = (float*)(ws + 809238528);              //   1,966,080 B

    conv_x<<<dim3(2048), dim3(256), 0, stream>>>(x, x_bf16);
    prep_w<<<dim3(4608), dim3(256), 0, stream>>>(Wk, Wv, Wt);
    q_proj<<<dim3(64), dim3(256), 0, stream>>>(x, Wq, q_ws);
    gemm_kv7<<<dim3(6144), dim3(512), 0, stream>>>(x_bf16, Wt, k_ws, v_out);
    attn_fused<<<dim3(768), dim3(512), 0, stream>>>(k_ws, q_ws, v_out, attn_out, preproj);
    proj_out_k<<<dim3(64), dim3(256), 0, stream>>>(preproj, Wp, bp, out);
  } else {
    unsigned short* k_ws = (unsigned short*)(ws);                 // 402,653,184 B
    unsigned short* q_ws = (unsigned short*)(ws + 402653184);
    unsigned short* Wt   = (unsigned short*)(ws + 404226048);
    float* preproj       = (float*)(ws + 406585344);

    prep_w<<<dim3(4608), dim3(256), 0, stream>>>(Wk, Wv, Wt);
    q_proj<<<dim3(64), dim3(256), 0, stream>>>(x, Wq, q_ws);
    gemm_kv<<<dim3(24576), dim3(256), 0, stream>>>(x, Wt, k_ws, v_out);
    attn_fused<<<dim3(768), dim3(512), 0, stream>>>(k_ws, q_ws, v_out, attn_out, preproj);
    proj_out_k<<<dim3(64), dim3(256), 0, stream>>>(preproj, Wp, bp, out);
  }
}

// Round 8
// 1605.762 us; speedup vs baseline: 1.2047x; 1.0072x over previous
//
#include <hip/hip_runtime.h>

typedef __attribute__((ext_vector_type(8))) short short8;
typedef __attribute__((ext_vector_type(4))) short short4v;
typedef __attribute__((ext_vector_type(4))) float f32x4;

__device__ __forceinline__ unsigned short f2bf(float f) {
  union { float f; unsigned u; } v; v.f = f;
  unsigned r = v.u + 0x7FFFu + ((v.u >> 16) & 1u);
  return (unsigned short)(r >> 16);
}

__device__ __forceinline__ void gload16(const void* g, void* l) {
  __builtin_amdgcn_global_load_lds(
      (const __attribute__((address_space(1))) void*)g,
      (__attribute__((address_space(3))) void*)l, 16, 0, 0);
}

// ---------------------------------------------------------------------------
// Kernel 0: x (fp32) -> x_bf16, vectorized 8 elems/thread
// ---------------------------------------------------------------------------
__global__ __launch_bounds__(256) void conv_x(const float* __restrict__ x,
                                              unsigned short* __restrict__ xb) {
  const long total = 25165824;                        // 201326592 / 8
  long stride = (long)gridDim.x * 256;
  for (long u = blockIdx.x * 256 + threadIdx.x; u < total; u += stride) {
    const float* p = x + u * 8;
    float4 a = *(const float4*)p;
    float4 b = *(const float4*)(p + 4);
    short8 h;
    h[0] = (short)f2bf(a.x); h[1] = (short)f2bf(a.y);
    h[2] = (short)f2bf(a.z); h[3] = (short)f2bf(a.w);
    h[4] = (short)f2bf(b.x); h[5] = (short)f2bf(b.y);
    h[6] = (short)f2bf(b.z); h[7] = (short)f2bf(b.w);
    *(short8*)(xb + u * 8) = h;
  }
}

// ---------------------------------------------------------------------------
// Kernel 1: Wt[n][k] = bf16( [Wk | Wv](k, n) )   (B^T layout, n in [0,1536))
// ---------------------------------------------------------------------------
__global__ __launch_bounds__(256) void prep_w(const float* __restrict__ Wk,
                                              const float* __restrict__ Wv,
                                              unsigned short* __restrict__ Wt) {
  int idx = blockIdx.x * 256 + threadIdx.x;           // 1536*768 elements
  int n = idx / 768, k = idx - n * 768;
  float w = (n < 768) ? Wk[k * 768 + n] : Wv[k * 768 + (n - 768)];
  Wt[idx] = f2bf(w);
}

// ---------------------------------------------------------------------------
// Kernel 2: q = scale * x[:, :10] @ Wq  -> q_ws[b][h][16][64] bf16 (rows 10..15 = 0)
// ---------------------------------------------------------------------------
__global__ __launch_bounds__(256) void q_proj(const float* __restrict__ x,
                                              const float* __restrict__ Wq,
                                              unsigned short* __restrict__ q_ws) {
  int b = blockIdx.x, tid = threadIdx.x;
  __shared__ float xr[7680];
  const float* xp = x + (long)b * 4096 * 768;
  for (int i = tid; i < 7680; i += 256) xr[i] = xp[i];
  for (int i = tid; i < 12 * 6 * 64; i += 256) {
    int h = i / 384, rem = i - h * 384;
    int t = 10 + rem / 64, d = rem & 63;
    q_ws[(((long)(b * 12 + h) * 16 + t) << 6) + d] = 0;
  }
  __syncthreads();
  float acc[10][3];
#pragma unroll
  for (int t = 0; t < 10; ++t) { acc[t][0] = 0.f; acc[t][1] = 0.f; acc[t][2] = 0.f; }
  for (int k = 0; k < 768; ++k) {
    const float* wr = Wq + (long)k * 768;
    float w0 = wr[tid], w1 = wr[tid + 256], w2 = wr[tid + 512];
#pragma unroll
    for (int t = 0; t < 10; ++t) {
      float xv = xr[t * 768 + k];
      acc[t][0] += xv * w0; acc[t][1] += xv * w1; acc[t][2] += xv * w2;
    }
  }
#pragma unroll
  for (int t = 0; t < 10; ++t) {
#pragma unroll
    for (int j = 0; j < 3; ++j) {
      int c = tid + j * 256;
      int h = c >> 6, d = c & 63;
      q_ws[(((long)(b * 12 + h) * 16 + t) << 6) + d] = f2bf(acc[t][j] * 0.125f);
    }
  }
}

// ---------------------------------------------------------------------------
// Kernel 3 (R8): 256x256 tile, BK=64, 8 waves (2Mx4N), 4-phase schedule per
// K-tile (m201 template): per phase {stage-issue || ds_read subtile ->
// s_barrier -> setprio(1) -> 16 MFMA -> setprio(0) -> s_barrier}, quadrant
// rotation M0N0/M0N1/M1N1/M1N0. Double-buffered 128KB LDS, one
// vmcnt(0)+barrier per K-tile boundary. Swizzle key = row&7 (8 chunks/row).
// ---------------------------------------------------------------------------
__global__ __launch_bounds__(512, 2) void gemm_kv8(const unsigned short* __restrict__ xb,
                                                   const unsigned short* __restrict__ Wt,
                                                   unsigned short* __restrict__ k_ws,
                                                   float* __restrict__ v_out) {
  __shared__ char smem[131072];                       // A0 B0 A1 B1, 32KB each
#define A0T ((unsigned short*)(smem))
#define B0T ((unsigned short*)(smem + 32768))
#define A1T ((unsigned short*)(smem + 65536))
#define B1T ((unsigned short*)(smem + 98304))

  int bid = blockIdx.x;
  int lb = (bid & 7) * 768 + (bid >> 3);              // XCD swizzle (6144 % 8 == 0)
  int mt = lb / 6, nt = lb - mt * 6;
  long m0 = (long)mt * 256; int n0 = nt * 256;
  int tid = threadIdx.x, lane = tid & 63;
  int uw = __builtin_amdgcn_readfirstlane(tid >> 6);  // uniform wave id 0..7
  int wm = uw >> 2, wn = uw & 3;                      // 2 M-waves x 4 N-waves
  int r16 = lane & 15, gk = lane >> 4;

  const unsigned short* xs = xb + m0 * 768;
  const unsigned short* wp = Wt + (long)n0 * 768;

  // staging: instr i covers rows [i*64 + uw*8, +8); lane l -> row_local l>>3,
  // phys chunk l&7 holds global chunk (l&7)^(row&7)  (row&7 == (l>>3)&7)
  int srow8 = lane >> 3;
  int sch = ((lane & 7) ^ (srow8 & 7)) << 3;          // source elem offset
  const unsigned short* sA = xs + (long)(uw * 8 + srow8) * 768 + sch;
  const unsigned short* sB = wp + (long)(uw * 8 + srow8) * 768 + sch;

  // frag read: row&7 == r16&7; chunk(kk) = (kk*4+gk)^(r16&7)
  int ck0 = ((gk ^ (r16 & 7)) << 3);
  int ck1 = (((4 + gk) ^ (r16 & 7)) << 3);
  int arb = (wm * 128 + r16) * 64;                    // A row base (elems)
  int brb = (wn * 64 + r16) * 64;                     // B row base (elems)

  f32x4 acc[8][4];
#pragma unroll
  for (int i = 0; i < 8; ++i)
#pragma unroll
    for (int j = 0; j < 4; ++j) acc[i][j] = (f32x4){0.f, 0.f, 0.f, 0.f};

#define SGA(AT, I, KO) gload16(sA + (long)(I) * 49152 + (KO), (AT) + ((I) * 64 + uw * 8) * 64)
#define SGB(BT, I, KO) gload16(sB + (long)(I) * 49152 + (KO), (BT) + ((I) * 64 + uw * 8) * 64)
#define WBND asm volatile("s_waitcnt vmcnt(0)\n\ts_barrier" ::: "memory")
#define PBAR __builtin_amdgcn_s_barrier()

#define BODY(AC, BC, AN, BN, KOS, DOST)                                         \
  {                                                                             \
    short8 fa[4][2], fb0[2][2], fb1[2][2];                                      \
    /* ---- P1: stage half, read A-M0 + B-N0, MFMA M0xN0 ---- */                \
    if (DOST) { SGA(AN, 0, KOS); SGA(AN, 1, KOS); SGB(BN, 0, KOS); SGB(BN, 1, KOS); } \
    _Pragma("unroll")                                                           \
    for (int mi = 0; mi < 4; ++mi) {                                            \
      fa[mi][0] = *(const short8*)&AC[arb + mi * 1024 + ck0];                   \
      fa[mi][1] = *(const short8*)&AC[arb + mi * 1024 + ck1];                   \
    }                                                                           \
    _Pragma("unroll")                                                           \
    for (int ni = 0; ni < 2; ++ni) {                                            \
      fb0[ni][0] = *(const short8*)&BC[brb + ni * 1024 + ck0];                  \
      fb0[ni][1] = *(const short8*)&BC[brb + ni * 1024 + ck1];                  \
    }                                                                           \
    PBAR;                                                                       \
    __builtin_amdgcn_s_setprio(1);                                              \
    _Pragma("unroll")                                                           \
    for (int mi = 0; mi < 4; ++mi)                                              \
      _Pragma("unroll")                                                         \
      for (int ni = 0; ni < 2; ++ni) {                                          \
        acc[mi][ni] = __builtin_amdgcn_mfma_f32_16x16x32_bf16(fa[mi][0], fb0[ni][0], acc[mi][ni], 0, 0, 0); \
        acc[mi][ni] = __builtin_amdgcn_mfma_f32_16x16x32_bf16(fa[mi][1], fb0[ni][1], acc[mi][ni], 0, 0, 0); \
      }                                                                         \
    __builtin_amdgcn_s_setprio(0);                                              \
    PBAR;                                                                       \
    /* ---- P2: stage half, read B-N1, MFMA M0xN1 ---- */                       \
    if (DOST) { SGA(AN, 2, KOS); SGA(AN, 3, KOS); SGB(BN, 2, KOS); SGB(BN, 3, KOS); } \
    _Pragma("unroll")                                                           \
    for (int ni = 0; ni < 2; ++ni) {                                            \
      fb1[ni][0] = *(const short8*)&BC[brb + (ni + 2) * 1024 + ck0];            \
      fb1[ni][1] = *(const short8*)&BC[brb + (ni + 2) * 1024 + ck1];            \
    }                                                                           \
    PBAR;                                                                       \
    __builtin_amdgcn_s_setprio(1);                                              \
    _Pragma("unroll")                                                           \
    for (int mi = 0; mi < 4; ++mi)                                              \
      _Pragma("unroll")                                                         \
      for (int ni = 0; ni < 2; ++ni) {                                          \
        acc[mi][ni + 2] = __builtin_amdgcn_mfma_f32_16x16x32_bf16(fa[mi][0], fb1[ni][0], acc[mi][ni + 2], 0, 0, 0); \
        acc[mi][ni + 2] = __builtin_amdgcn_mfma_f32_16x16x32_bf16(fa[mi][1], fb1[ni][1], acc[mi][ni + 2], 0, 0, 0); \
      }                                                                         \
    __builtin_amdgcn_s_setprio(0);                                              \
    PBAR;                                                                       \
    /* ---- P3: read A-M1, MFMA M1xN1 ---- */                                   \
    _Pragma("unroll")                                                           \
    for (int mi = 0; mi < 4; ++mi) {                                            \
      fa[mi][0] = *(const short8*)&AC[arb + (mi + 4) * 1024 + ck0];             \
      fa[mi][1] = *(const short8*)&AC[arb + (mi + 4) * 1024 + ck1];             \
    }                                                                           \
    PBAR;                                                                       \
    __builtin_amdgcn_s_setprio(1);                                              \
    _Pragma("unroll")                                                           \
    for (int mi = 0; mi < 4; ++mi)                                              \
      _Pragma("unroll")                                                         \
      for (int ni = 0; ni < 2; ++ni) {                                          \
        acc[mi + 4][ni + 2] = __builtin_amdgcn_mfma_f32_16x16x32_bf16(fa[mi][0], fb1[ni][0], acc[mi + 4][ni + 2], 0, 0, 0); \
        acc[mi + 4][ni + 2] = __builtin_amdgcn_mfma_f32_16x16x32_bf16(fa[mi][1], fb1[ni][1], acc[mi + 4][ni + 2], 0, 0, 0); \
      }                                                                         \
    __builtin_amdgcn_s_setprio(0);                                              \
    PBAR;                                                                       \
    /* ---- P4: MFMA M1xN0 (fb0 still live) ---- */                             \
    __builtin_amdgcn_s_setprio(1);                                              \
    _Pragma("unroll")                                                           \
    for (int mi = 0; mi < 4; ++mi)                                              \
      _Pragma("unroll")                                                         \
      for (int ni = 0; ni < 2; ++ni) {                                          \
        acc[mi + 4][ni] = __builtin_amdgcn_mfma_f32_16x16x32_bf16(fa[mi][0], fb0[ni][0], acc[mi + 4][ni], 0, 0, 0); \
        acc[mi + 4][ni] = __builtin_amdgcn_mfma_f32_16x16x32_bf16(fa[mi][1], fb0[ni][1], acc[mi + 4][ni], 0, 0, 0); \
      }                                                                         \
    __builtin_amdgcn_s_setprio(0);                                              \
  }

  // prologue: stage K-tile 0 into buf0
  SGA(A0T, 0, 0); SGA(A0T, 1, 0); SGA(A0T, 2, 0); SGA(A0T, 3, 0);
  SGB(B0T, 0, 0); SGB(B0T, 1, 0); SGB(B0T, 2, 0); SGB(B0T, 3, 0);
  WBND;

#pragma unroll 1
  for (int t = 0; t < 12; t += 2) {
    BODY(A0T, B0T, A1T, B1T, (t + 1) * 64, true);     // tile t; stage t+1
    WBND;
    BODY(A1T, B1T, A0T, B0T, (t + 2) * 64, (t + 2) < 12); // tile t+1; stage t+2
    WBND;
  }
#undef BODY
#undef SGA
#undef SGB
#undef WBND
#undef PBAR

  // ---- epilogue: per-wave padded LDS scratch (stride 68), coalesced stores ----
  float* scr = (float*)smem + uw * 1088;              // 16 rows x 68 floats
  bool is_k = (n0 < 768);
  int h = (is_k ? (n0 >> 6) : ((n0 - 768) >> 6)) + wn;
  int bq = (int)(m0 >> 12);                           // uniform (4096 % 256 == 0)
  int nb = (int)(m0 & 4095) + wm * 128;

#pragma unroll
  for (int mi = 0; mi < 8; ++mi) {
#pragma unroll
    for (int ni = 0; ni < 4; ++ni)
#pragma unroll
      for (int r = 0; r < 4; ++r)
        scr[(gk * 4 + r) * 68 + ni * 16 + r16] = acc[mi][ni][r];
    int nbase = nb + mi * 16;
    if (is_k) {
#pragma unroll
      for (int p = 0; p < 2; ++p) {
        int row = p * 8 + (lane >> 3), d0 = (lane & 7) << 3;
        float4 aa = *(const float4*)&scr[row * 68 + d0];
        float4 bb = *(const float4*)&scr[row * 68 + d0 + 4];
        short8 hh;
        hh[0] = (short)f2bf(aa.x); hh[1] = (short)f2bf(aa.y);
        hh[2] = (short)f2bf(aa.z); hh[3] = (short)f2bf(aa.w);
        hh[4] = (short)f2bf(bb.x); hh[5] = (short)f2bf(bb.y);
        hh[6] = (short)f2bf(bb.z); hh[7] = (short)f2bf(bb.w);
        *(short8*)&k_ws[((long)(bq * 12 + h) * 4096 + nbase + row) * 64 + d0] = hh;
      }
    } else {
#pragma unroll
      for (int p = 0; p < 4; ++p) {
        int row = p * 4 + (lane >> 4), d0 = (lane & 15) << 2;
        float4 aa = *(const float4*)&scr[row * 68 + d0];
        *(float4*)&v_out[((long)(bq * 12 + h) * 4096 + nbase + row) * 64 + d0] = aa;
      }
    }
  }
#undef A0T
#undef B0T
#undef A1T
#undef B1T
}

// ---------------------------------------------------------------------------
// Kernel 3-FALLBACK (R1 version, used when ws_size is too small)
// ---------------------------------------------------------------------------
__global__ __launch_bounds__(256) void gemm_kv(const float* __restrict__ x,
                                               const unsigned short* __restrict__ Wt,
                                               unsigned short* __restrict__ k_ws,
                                               float* __restrict__ v_out) {
  __shared__ char lds[32768];
  int bid = blockIdx.x;
  int lb = (bid & 7) * 3072 + (bid >> 3);
  int mt = lb / 12, nt = lb - mt * 12;
  long m0 = (long)mt * 128; int n0 = nt * 128;
  int tid = threadIdx.x, lane = tid & 63;
  int wid = tid >> 6, wm = wid >> 1, wn = wid & 1;
  int rlo = lane & 15, gk = lane >> 4;

  const float* xs = x + m0 * 768;
  const unsigned short* wp = Wt + (long)n0 * 768;

  int arow0 = tid >> 3, ak4 = (tid & 7) << 2;
  int bn = tid >> 1, bg = (tid & 1) << 1;

  f32x4 acc[4][4];
#pragma unroll
  for (int i = 0; i < 4; ++i)
#pragma unroll
    for (int j = 0; j < 4; ++j) acc[i][j] = (f32x4){0.f, 0.f, 0.f, 0.f};

  float4 fA[4]; short8 wB[2];
#pragma unroll
  for (int it = 0; it < 4; ++it) {
    int row = it * 32 + arow0;
    fA[it] = *(const float4*)(xs + (long)row * 768 + ak4);
  }
#pragma unroll
  for (int i = 0; i < 2; ++i)
    wB[i] = *(const short8*)(wp + (long)bn * 768 + (bg + i) * 8);
#pragma unroll
  for (int it = 0; it < 4; ++it) {
    int row = it * 32 + arow0;
    short4v h;
    h[0] = (short)f2bf(fA[it].x); h[1] = (short)f2bf(fA[it].y);
    h[2] = (short)f2bf(fA[it].z); h[3] = (short)f2bf(fA[it].w);
    *(short4v*)(lds + row * 64 + ((ak4 * 2) ^ (((row >> 1) & 3) << 4))) = h;
  }
#pragma unroll
  for (int i = 0; i < 2; ++i)
    *(short8*)(lds + 16384 + bn * 64 + (((bg + i) * 16) ^ (((bn >> 1) & 3) << 4))) = wB[i];
  __syncthreads();

#pragma unroll 2
  for (int ks = 0; ks < 24; ++ks) {
    char* Ab = lds + (ks & 1) * 8192;
    char* Bb = lds + 16384 + (ks & 1) * 8192;
    bool pf = (ks + 1 < 24);
    if (pf) {
#pragma unroll
      for (int it = 0; it < 4; ++it) {
        int row = it * 32 + arow0;
        fA[it] = *(const float4*)(xs + (long)row * 768 + (ks + 1) * 32 + ak4);
      }
#pragma unroll
      for (int i = 0; i < 2; ++i)
        wB[i] = *(const short8*)(wp + (long)bn * 768 + (ks + 1) * 32 + (bg + i) * 8);
    }
    short8 af[4], bfr[4];
#pragma unroll
    for (int mi = 0; mi < 4; ++mi) {
      int row = wm * 64 + mi * 16 + rlo;
      af[mi] = *(const short8*)(Ab + row * 64 + ((gk * 16) ^ (((row >> 1) & 3) << 4)));
    }
#pragma unroll
    for (int ni = 0; ni < 4; ++ni) {
      int n = wn * 64 + ni * 16 + rlo;
      bfr[ni] = *(const short8*)(Bb + n * 64 + ((gk * 16) ^ (((n >> 1) & 3) << 4)));
    }
#pragma unroll
    for (int mi = 0; mi < 4; ++mi)
#pragma unroll
      for (int ni = 0; ni < 4; ++ni)
        acc[mi][ni] = __builtin_amdgcn_mfma_f32_16x16x32_bf16(af[mi], bfr[ni], acc[mi][ni], 0, 0, 0);
    if (pf) {
      char* An = lds + ((ks + 1) & 1) * 8192;
      char* Bn = lds + 16384 + ((ks + 1) & 1) * 8192;
#pragma unroll
      for (int it = 0; it < 4; ++it) {
        int row = it * 32 + arow0;
        short4v h;
        h[0] = (short)f2bf(fA[it].x); h[1] = (short)f2bf(fA[it].y);
        h[2] = (short)f2bf(fA[it].z); h[3] = (short)f2bf(fA[it].w);
        *(short4v*)(An + row * 64 + ((ak4 * 2) ^ (((row >> 1) & 3) << 4))) = h;
      }
#pragma unroll
      for (int i = 0; i < 2; ++i)
        *(short8*)(Bn + bn * 64 + (((bg + i) * 16) ^ (((bn >> 1) & 3) << 4))) = wB[i];
    }
    __syncthreads();
  }

  bool is_k = (n0 < 768);
  int cb = is_k ? n0 : n0 - 768;
#pragma unroll
  for (int ni = 0; ni < 4; ++ni) {
    int cc = cb + wn * 64 + ni * 16 + rlo;
    int h = cc >> 6, d = cc & 63;
#pragma unroll
    for (int mi = 0; mi < 4; ++mi) {
#pragma unroll
      for (int r = 0; r < 4; ++r) {
        long m = m0 + wm * 64 + mi * 16 + gk * 4 + r;
        int b = (int)(m >> 12), n = (int)(m & 4095);
        long off = ((long)(b * 12 + h) * 4096 + n) * 64 + d;
        float val = acc[mi][ni][r];
        if (is_k) k_ws[off] = f2bf(val);
        else      v_out[off] = val;
      }
    }
  }
}

// ---------------------------------------------------------------------------
// Kernel 4: fused attention per (b,h). 512 threads / 8 waves.
// Phase 3 writes the normalized attn in-place.
// ---------------------------------------------------------------------------
__global__ __launch_bounds__(512) void attn_fused(const unsigned short* __restrict__ k_ws,
                                                  const unsigned short* __restrict__ q_ws,
                                                  const float* __restrict__ v_glob,
                                                  float* __restrict__ attn_out,
                                                  float* __restrict__ preproj) {
  __shared__ float red[8][16];
  __shared__ float rowmax[16];
  __shared__ float rowinv[16];
  __shared__ float scratch[8 * 256];

  int tid = threadIdx.x, lane = tid & 63, w = tid >> 6;
  int bh = blockIdx.x;
  int r16 = lane & 15, gk = lane >> 4;
  int trc = (r16 < 10) ? r16 : 9;

  const unsigned short* kp = k_ws + (long)bh * (4096 * 64);
  const unsigned short* qp = q_ws + (long)bh * 1024;
  float* sraw = attn_out + (long)bh * 40960;
  const float* vp = v_glob + (long)bh * (4096 * 64);

  short8 qf0 = *(const short8*)(qp + r16 * 64 + gk * 8);
  short8 qf1 = *(const short8*)(qp + r16 * 64 + 32 + gk * 8);

  // ---- Phase 1: scores + row max ----
  float pmax = -3.0e38f;
  for (int ch = 0; ch < 32; ++ch) {
    int n0 = (w * 32 + ch) << 4;
    short8 kf0 = *(const short8*)(kp + (long)(n0 + r16) * 64 + gk * 8);
    short8 kf1 = *(const short8*)(kp + (long)(n0 + r16) * 64 + 32 + gk * 8);
    f32x4 d4 = (f32x4){0.f, 0.f, 0.f, 0.f};
    d4 = __builtin_amdgcn_mfma_f32_16x16x32_bf16(kf0, qf0, d4, 0, 0, 0);
    d4 = __builtin_amdgcn_mfma_f32_16x16x32_bf16(kf1, qf1, d4, 0, 0, 0);
    float sv[4];
#pragma unroll
    for (int r = 0; r < 4; ++r) {
      int n = n0 + gk * 4 + r;
      float s = d4[r];
      if (n < 10 && n != r16) s = -1e30f;
      sv[r] = s;
      pmax = fmaxf(pmax, s);
    }
    if (r16 < 10)
      *(float4*)(sraw + r16 * 4096 + n0 + gk * 4) = make_float4(sv[0], sv[1], sv[2], sv[3]);
  }
  pmax = fmaxf(pmax, __shfl_xor(pmax, 16));
  pmax = fmaxf(pmax, __shfl_xor(pmax, 32));
  if (lane < 16) red[w][lane] = pmax;
  __syncthreads();
  if (tid < 16) {
    float m = red[0][tid];
#pragma unroll
    for (int i = 1; i < 8; ++i) m = fmaxf(m, red[i][tid]);
    rowmax[tid] = m;
  }
  __syncthreads();

  // ---- Phase 2: row sum ----
  float mx = rowmax[trc];
  float psum = 0.f;
  for (int ch = 0; ch < 16; ++ch) {
    int n0 = ((w * 16 + ch) << 5) + gk * 8;
    float4 a = *(const float4*)(sraw + trc * 4096 + n0);
    float4 b2 = *(const float4*)(sraw + trc * 4096 + n0 + 4);
    psum += __expf(a.x - mx) + __expf(a.y - mx) + __expf(a.z - mx) + __expf(a.w - mx)
          + __expf(b2.x - mx) + __expf(b2.y - mx) + __expf(b2.z - mx) + __expf(b2.w - mx);
  }
  psum += __shfl_xor(psum, 16);
  psum += __shfl_xor(psum, 32);
  if (lane < 16) red[w][lane] = psum;
  __syncthreads();
  if (tid < 16) {
    float s = 0.f;
#pragma unroll
    for (int i = 0; i < 8; ++i) s += red[i][tid];
    rowinv[tid] = 1.0f / s;
  }
  __syncthreads();

  // ---- Phase 3: PV + in-place normalized write (final attn) ----
  int dc = w & 3, half = w >> 2;
  int d0 = dc << 4;
  float inv = rowinv[trc];
  f32x4 acc = (f32x4){0.f, 0.f, 0.f, 0.f};
  for (int kk = 0; kk < 64; ++kk) {
    int nr = half * 2048 + kk * 32 + gk * 8;
    float* sp = sraw + trc * 4096 + nr;
    float4 s0 = *(const float4*)(sp);
    float4 s1 = *(const float4*)(sp + 4);
    float p0 = __expf(s0.x - mx) * inv, p1 = __expf(s0.y - mx) * inv;
    float p2 = __expf(s0.z - mx) * inv, p3 = __expf(s0.w - mx) * inv;
    float p4 = __expf(s1.x - mx) * inv, p5 = __expf(s1.y - mx) * inv;
    float p6 = __expf(s1.z - mx) * inv, p7 = __expf(s1.w - mx) * inv;
    if (r16 < 10) {
      *(float4*)(sp)     = make_float4(p0, p1, p2, p3);
      *(float4*)(sp + 4) = make_float4(p4, p5, p6, p7);
    }
    short8 pa;
    pa[0] = (short)f2bf(p0); pa[1] = (short)f2bf(p1);
    pa[2] = (short)f2bf(p2); pa[3] = (short)f2bf(p3);
    pa[4] = (short)f2bf(p4); pa[5] = (short)f2bf(p5);
    pa[6] = (short)f2bf(p6); pa[7] = (short)f2bf(p7);
    short8 vb;
    const float* vrow = vp + (long)nr * 64 + d0 + r16;
#pragma unroll
    for (int j = 0; j < 8; ++j) vb[j] = (short)f2bf(vrow[j * 64]);
    acc = __builtin_amdgcn_mfma_f32_16x16x32_bf16(pa, vb, acc, 0, 0, 0);
  }
#pragma unroll
  for (int r = 0; r < 4; ++r)
    scratch[w * 256 + (gk * 4 + r) * 16 + r16] = acc[r];
  __syncthreads();

  int b = bh / 12, h = bh - b * 12;
  for (int idx = tid; idx < 640; idx += 512) {
    int tt = idx >> 6, d = idx & 63;
    int c = d >> 4, dl = d & 15;
    float s = scratch[c * 256 + tt * 16 + dl] + scratch[(c + 4) * 256 + tt * 16 + dl];
    preproj[((long)b * 10 + tt) * 768 + h * 64 + d] = s;
  }
}

// ---------------------------------------------------------------------------
// Kernel 5: x_cls = preproj @ Wp + bp
// ---------------------------------------------------------------------------
__global__ __launch_bounds__(256) void proj_out_k(const float* __restrict__ preproj,
                                                  const float* __restrict__ Wp,
                                                  const float* __restrict__ bp,
                                                  float* __restrict__ out0) {
  int b = blockIdx.x, tid = threadIdx.x;
  __shared__ float xr[7680];
  const float* pp = preproj + (long)b * 7680;
  for (int i = tid; i < 7680; i += 256) xr[i] = pp[i];
  __syncthreads();
  float acc[10][3];
#pragma unroll
  for (int t = 0; t < 10; ++t) { acc[t][0] = 0.f; acc[t][1] = 0.f; acc[t][2] = 0.f; }
  for (int k = 0; k < 768; ++k) {
    const float* wr = Wp + (long)k * 768;
    float w0 = wr[tid], w1 = wr[tid + 256], w2 = wr[tid + 512];
#pragma unroll
    for (int t = 0; t < 10; ++t) {
      float xv = xr[t * 768 + k];
      acc[t][0] += xv * w0; acc[t][1] += xv * w1; acc[t][2] += xv * w2;
    }
  }
  float b0 = bp[tid], b1 = bp[tid + 256], b2 = bp[tid + 512];
  float* op = out0 + (long)b * 7680;
#pragma unroll
  for (int t = 0; t < 10; ++t) {
    op[t * 768 + tid]       = acc[t][0] + b0;
    op[t * 768 + tid + 256] = acc[t][1] + b1;
    op[t * 768 + tid + 512] = acc[t][2] + b2;
  }
}

// ---------------------------------------------------------------------------
extern "C" void kernel_launch(void* const* d_in, const int* in_sizes, int n_in,
                              void* d_out, int out_size, void* d_ws, size_t ws_size,
                              hipStream_t stream) {
  (void)in_sizes; (void)n_in; (void)out_size;
  const float* x  = (const float*)d_in[0];
  const float* Wq = (const float*)d_in[1];
  const float* Wk = (const float*)d_in[2];
  const float* Wv = (const float*)d_in[3];
  const float* Wp = (const float*)d_in[4];
  const float* bp = (const float*)d_in[5];

  float* out      = (float*)d_out;
  float* attn_out = out + 491520;                 // [64,12,10,4096]
  float* v_out    = out + 31948800;               // [64,12,4096,64]

  char* ws = (char*)d_ws;
  const size_t NEED_BIG = 811204608;              // x_bf16 + k_ws + small

  if (ws_size >= NEED_BIG) {
    unsigned short* x_bf16 = (unsigned short*)(ws);               // 402,653,184 B
    unsigned short* k_ws = (unsigned short*)(ws + 402653184);     // 402,653,184 B
    unsigned short* q_ws = (unsigned short*)(ws + 805306368);     //   1,572,864 B
    unsigned short* Wt   = (unsigned short*)(ws + 806879232);     //   2,359,296 B
    float* preproj       = (float*)(ws + 809238528);              //   1,966,080 B

    conv_x<<<dim3(2048), dim3(256), 0, stream>>>(x, x_bf16);
    prep_w<<<dim3(4608), dim3(256), 0, stream>>>(Wk, Wv, Wt);
    q_proj<<<dim3(64), dim3(256), 0, stream>>>(x, Wq, q_ws);
    gemm_kv8<<<dim3(6144), dim3(512), 0, stream>>>(x_bf16, Wt, k_ws, v_out);
    attn_fused<<<dim3(768), dim3(512), 0, stream>>>(k_ws, q_ws, v_out, attn_out, preproj);
    proj_out_k<<<dim3(64), dim3(256), 0, stream>>>(preproj, Wp, bp, out);
  } else {
    unsigned short* k_ws = (unsigned short*)(ws);                 // 402,653,184 B
    unsigned short* q_ws = (unsigned short*)(ws + 402653184);
    unsigned short* Wt   = (unsigned short*)(ws + 404226048);
    float* preproj       = (float*)(ws + 406585344);

    prep_w<<<dim3(4608), dim3(256), 0, stream>>>(Wk, Wv, Wt);
    q_proj<<<dim3(64), dim3(256), 0, stream>>>(x, Wq, q_ws);
    gemm_kv<<<dim3(24576), dim3(256), 0, stream>>>(x, Wt, k_ws, v_out);
    attn_fused<<<dim3(768), dim3(512), 0, stream>>>(k_ws, q_ws, v_out, attn_out, preproj);
    proj_out_k<<<dim3(64), dim3(256), 0, stream>>>(preproj, Wp, bp, out);
  }
}

// Round 9
// 1495.423 us; speedup vs baseline: 1.2936x; 1.0738x over previous
//
#include <hip/hip_runtime.h>

typedef __attribute__((ext_vector_type(8))) short short8;
typedef __attribute__((ext_vector_type(4))) short short4v;
typedef __attribute__((ext_vector_type(4))) float f32x4;

__device__ __forceinline__ unsigned short f2bf(float f) {
  union { float f; unsigned u; } v; v.f = f;
  unsigned r = v.u + 0x7FFFu + ((v.u >> 16) & 1u);
  return (unsigned short)(r >> 16);
}

__device__ __forceinline__ void gload16(const void* g, void* l) {
  __builtin_amdgcn_global_load_lds(
      (const __attribute__((address_space(1))) void*)g,
      (__attribute__((address_space(3))) void*)l, 16, 0, 0);
}

// ---------------------------------------------------------------------------
// Kernel 0: x (fp32) -> x_bf16, vectorized 8 elems/thread
// ---------------------------------------------------------------------------
__global__ __launch_bounds__(256) void conv_x(const float* __restrict__ x,
                                              unsigned short* __restrict__ xb) {
  const long total = 25165824;                        // 201326592 / 8
  long stride = (long)gridDim.x * 256;
  for (long u = blockIdx.x * 256 + threadIdx.x; u < total; u += stride) {
    const float* p = x + u * 8;
    float4 a = *(const float4*)p;
    float4 b = *(const float4*)(p + 4);
    short8 h;
    h[0] = (short)f2bf(a.x); h[1] = (short)f2bf(a.y);
    h[2] = (short)f2bf(a.z); h[3] = (short)f2bf(a.w);
    h[4] = (short)f2bf(b.x); h[5] = (short)f2bf(b.y);
    h[6] = (short)f2bf(b.z); h[7] = (short)f2bf(b.w);
    *(short8*)(xb + u * 8) = h;
  }
}

// ---------------------------------------------------------------------------
// Kernel 1: Wt[n][k] = bf16( [Wk | Wv](k, n) )   (B^T layout, n in [0,1536))
// ---------------------------------------------------------------------------
__global__ __launch_bounds__(256) void prep_w(const float* __restrict__ Wk,
                                              const float* __restrict__ Wv,
                                              unsigned short* __restrict__ Wt) {
  int idx = blockIdx.x * 256 + threadIdx.x;           // 1536*768 elements
  int n = idx / 768, k = idx - n * 768;
  float w = (n < 768) ? Wk[k * 768 + n] : Wv[k * 768 + (n - 768)];
  Wt[idx] = f2bf(w);
}

// ---------------------------------------------------------------------------
// Kernel 2: q = scale * x[:, :10] @ Wq  -> q_ws[b][h][16][64] bf16 (rows 10..15 = 0)
// ---------------------------------------------------------------------------
__global__ __launch_bounds__(256) void q_proj(const float* __restrict__ x,
                                              const float* __restrict__ Wq,
                                              unsigned short* __restrict__ q_ws) {
  int b = blockIdx.x, tid = threadIdx.x;
  __shared__ float xr[7680];
  const float* xp = x + (long)b * 4096 * 768;
  for (int i = tid; i < 7680; i += 256) xr[i] = xp[i];
  for (int i = tid; i < 12 * 6 * 64; i += 256) {
    int h = i / 384, rem = i - h * 384;
    int t = 10 + rem / 64, d = rem & 63;
    q_ws[(((long)(b * 12 + h) * 16 + t) << 6) + d] = 0;
  }
  __syncthreads();
  float acc[10][3];
#pragma unroll
  for (int t = 0; t < 10; ++t) { acc[t][0] = 0.f; acc[t][1] = 0.f; acc[t][2] = 0.f; }
  for (int k = 0; k < 768; ++k) {
    const float* wr = Wq + (long)k * 768;
    float w0 = wr[tid], w1 = wr[tid + 256], w2 = wr[tid + 512];
#pragma unroll
    for (int t = 0; t < 10; ++t) {
      float xv = xr[t * 768 + k];
      acc[t][0] += xv * w0; acc[t][1] += xv * w1; acc[t][2] += xv * w2;
    }
  }
#pragma unroll
  for (int t = 0; t < 10; ++t) {
#pragma unroll
    for (int j = 0; j < 3; ++j) {
      int c = tid + j * 256;
      int h = c >> 6, d = c & 63;
      q_ws[(((long)(b * 12 + h) * 16 + t) << 6) + d] = f2bf(acc[t][j] * 0.125f);
    }
  }
}

// ---------------------------------------------------------------------------
// Kernel 3 (R8, kept): 256x256 tile, BK=64, 8 waves, 4-phase schedule.
// ---------------------------------------------------------------------------
__global__ __launch_bounds__(512, 2) void gemm_kv8(const unsigned short* __restrict__ xb,
                                                   const unsigned short* __restrict__ Wt,
                                                   unsigned short* __restrict__ k_ws,
                                                   float* __restrict__ v_out) {
  __shared__ char smem[131072];                       // A0 B0 A1 B1, 32KB each
#define A0T ((unsigned short*)(smem))
#define B0T ((unsigned short*)(smem + 32768))
#define A1T ((unsigned short*)(smem + 65536))
#define B1T ((unsigned short*)(smem + 98304))

  int bid = blockIdx.x;
  int lb = (bid & 7) * 768 + (bid >> 3);              // XCD swizzle (6144 % 8 == 0)
  int mt = lb / 6, nt = lb - mt * 6;
  long m0 = (long)mt * 256; int n0 = nt * 256;
  int tid = threadIdx.x, lane = tid & 63;
  int uw = __builtin_amdgcn_readfirstlane(tid >> 6);  // uniform wave id 0..7
  int wm = uw >> 2, wn = uw & 3;                      // 2 M-waves x 4 N-waves
  int r16 = lane & 15, gk = lane >> 4;

  const unsigned short* xs = xb + m0 * 768;
  const unsigned short* wp = Wt + (long)n0 * 768;

  int srow8 = lane >> 3;
  int sch = ((lane & 7) ^ (srow8 & 7)) << 3;          // source elem offset
  const unsigned short* sA = xs + (long)(uw * 8 + srow8) * 768 + sch;
  const unsigned short* sB = wp + (long)(uw * 8 + srow8) * 768 + sch;

  int ck0 = ((gk ^ (r16 & 7)) << 3);
  int ck1 = (((4 + gk) ^ (r16 & 7)) << 3);
  int arb = (wm * 128 + r16) * 64;                    // A row base (elems)
  int brb = (wn * 64 + r16) * 64;                     // B row base (elems)

  f32x4 acc[8][4];
#pragma unroll
  for (int i = 0; i < 8; ++i)
#pragma unroll
    for (int j = 0; j < 4; ++j) acc[i][j] = (f32x4){0.f, 0.f, 0.f, 0.f};

#define SGA(AT, I, KO) gload16(sA + (long)(I) * 49152 + (KO), (AT) + ((I) * 64 + uw * 8) * 64)
#define SGB(BT, I, KO) gload16(sB + (long)(I) * 49152 + (KO), (BT) + ((I) * 64 + uw * 8) * 64)
#define WBND asm volatile("s_waitcnt vmcnt(0)\n\ts_barrier" ::: "memory")
#define PBAR __builtin_amdgcn_s_barrier()

#define BODY(AC, BC, AN, BN, KOS, DOST)                                         \
  {                                                                             \
    short8 fa[4][2], fb0[2][2], fb1[2][2];                                      \
    if (DOST) { SGA(AN, 0, KOS); SGA(AN, 1, KOS); SGB(BN, 0, KOS); SGB(BN, 1, KOS); } \
    _Pragma("unroll")                                                           \
    for (int mi = 0; mi < 4; ++mi) {                                            \
      fa[mi][0] = *(const short8*)&AC[arb + mi * 1024 + ck0];                   \
      fa[mi][1] = *(const short8*)&AC[arb + mi * 1024 + ck1];                   \
    }                                                                           \
    _Pragma("unroll")                                                           \
    for (int ni = 0; ni < 2; ++ni) {                                            \
      fb0[ni][0] = *(const short8*)&BC[brb + ni * 1024 + ck0];                  \
      fb0[ni][1] = *(const short8*)&BC[brb + ni * 1024 + ck1];                  \
    }                                                                           \
    PBAR;                                                                       \
    __builtin_amdgcn_s_setprio(1);                                              \
    _Pragma("unroll")                                                           \
    for (int mi = 0; mi < 4; ++mi)                                              \
      _Pragma("unroll")                                                         \
      for (int ni = 0; ni < 2; ++ni) {                                          \
        acc[mi][ni] = __builtin_amdgcn_mfma_f32_16x16x32_bf16(fa[mi][0], fb0[ni][0], acc[mi][ni], 0, 0, 0); \
        acc[mi][ni] = __builtin_amdgcn_mfma_f32_16x16x32_bf16(fa[mi][1], fb0[ni][1], acc[mi][ni], 0, 0, 0); \
      }                                                                         \
    __builtin_amdgcn_s_setprio(0);                                              \
    PBAR;                                                                       \
    if (DOST) { SGA(AN, 2, KOS); SGA(AN, 3, KOS); SGB(BN, 2, KOS); SGB(BN, 3, KOS); } \
    _Pragma("unroll")                                                           \
    for (int ni = 0; ni < 2; ++ni) {                                            \
      fb1[ni][0] = *(const short8*)&BC[brb + (ni + 2) * 1024 + ck0];            \
      fb1[ni][1] = *(const short8*)&BC[brb + (ni + 2) * 1024 + ck1];            \
    }                                                                           \
    PBAR;                                                                       \
    __builtin_amdgcn_s_setprio(1);                                              \
    _Pragma("unroll")                                                           \
    for (int mi = 0; mi < 4; ++mi)                                              \
      _Pragma("unroll")                                                         \
      for (int ni = 0; ni < 2; ++ni) {                                          \
        acc[mi][ni + 2] = __builtin_amdgcn_mfma_f32_16x16x32_bf16(fa[mi][0], fb1[ni][0], acc[mi][ni + 2], 0, 0, 0); \
        acc[mi][ni + 2] = __builtin_amdgcn_mfma_f32_16x16x32_bf16(fa[mi][1], fb1[ni][1], acc[mi][ni + 2], 0, 0, 0); \
      }                                                                         \
    __builtin_amdgcn_s_setprio(0);                                              \
    PBAR;                                                                       \
    _Pragma("unroll")                                                           \
    for (int mi = 0; mi < 4; ++mi) {                                            \
      fa[mi][0] = *(const short8*)&AC[arb + (mi + 4) * 1024 + ck0];             \
      fa[mi][1] = *(const short8*)&AC[arb + (mi + 4) * 1024 + ck1];             \
    }                                                                           \
    PBAR;                                                                       \
    __builtin_amdgcn_s_setprio(1);                                              \
    _Pragma("unroll")                                                           \
    for (int mi = 0; mi < 4; ++mi)                                              \
      _Pragma("unroll")                                                         \
      for (int ni = 0; ni < 2; ++ni) {                                          \
        acc[mi + 4][ni + 2] = __builtin_amdgcn_mfma_f32_16x16x32_bf16(fa[mi][0], fb1[ni][0], acc[mi + 4][ni + 2], 0, 0, 0); \
        acc[mi + 4][ni + 2] = __builtin_amdgcn_mfma_f32_16x16x32_bf16(fa[mi][1], fb1[ni][1], acc[mi + 4][ni + 2], 0, 0, 0); \
      }                                                                         \
    __builtin_amdgcn_s_setprio(0);                                              \
    PBAR;                                                                       \
    __builtin_amdgcn_s_setprio(1);                                              \
    _Pragma("unroll")                                                           \
    for (int mi = 0; mi < 4; ++mi)                                              \
      _Pragma("unroll")                                                         \
      for (int ni = 0; ni < 2; ++ni) {                                          \
        acc[mi + 4][ni] = __builtin_amdgcn_mfma_f32_16x16x32_bf16(fa[mi][0], fb0[ni][0], acc[mi + 4][ni], 0, 0, 0); \
        acc[mi + 4][ni] = __builtin_amdgcn_mfma_f32_16x16x32_bf16(fa[mi][1], fb0[ni][1], acc[mi + 4][ni], 0, 0, 0); \
      }                                                                         \
    __builtin_amdgcn_s_setprio(0);                                              \
  }

  SGA(A0T, 0, 0); SGA(A0T, 1, 0); SGA(A0T, 2, 0); SGA(A0T, 3, 0);
  SGB(B0T, 0, 0); SGB(B0T, 1, 0); SGB(B0T, 2, 0); SGB(B0T, 3, 0);
  WBND;

#pragma unroll 1
  for (int t = 0; t < 12; t += 2) {
    BODY(A0T, B0T, A1T, B1T, (t + 1) * 64, true);
    WBND;
    BODY(A1T, B1T, A0T, B0T, (t + 2) * 64, (t + 2) < 12);
    WBND;
  }
#undef BODY
#undef SGA
#undef SGB
#undef WBND
#undef PBAR

  float* scr = (float*)smem + uw * 1088;              // 16 rows x 68 floats
  bool is_k = (n0 < 768);
  int h = (is_k ? (n0 >> 6) : ((n0 - 768) >> 6)) + wn;
  int bq = (int)(m0 >> 12);
  int nb = (int)(m0 & 4095) + wm * 128;

#pragma unroll
  for (int mi = 0; mi < 8; ++mi) {
#pragma unroll
    for (int ni = 0; ni < 4; ++ni)
#pragma unroll
      for (int r = 0; r < 4; ++r)
        scr[(gk * 4 + r) * 68 + ni * 16 + r16] = acc[mi][ni][r];
    int nbase = nb + mi * 16;
    if (is_k) {
#pragma unroll
      for (int p = 0; p < 2; ++p) {
        int row = p * 8 + (lane >> 3), d0 = (lane & 7) << 3;
        float4 aa = *(const float4*)&scr[row * 68 + d0];
        float4 bb = *(const float4*)&scr[row * 68 + d0 + 4];
        short8 hh;
        hh[0] = (short)f2bf(aa.x); hh[1] = (short)f2bf(aa.y);
        hh[2] = (short)f2bf(aa.z); hh[3] = (short)f2bf(aa.w);
        hh[4] = (short)f2bf(bb.x); hh[5] = (short)f2bf(bb.y);
        hh[6] = (short)f2bf(bb.z); hh[7] = (short)f2bf(bb.w);
        *(short8*)&k_ws[((long)(bq * 12 + h) * 4096 + nbase + row) * 64 + d0] = hh;
      }
    } else {
#pragma unroll
      for (int p = 0; p < 4; ++p) {
        int row = p * 4 + (lane >> 4), d0 = (lane & 15) << 2;
        float4 aa = *(const float4*)&scr[row * 68 + d0];
        *(float4*)&v_out[((long)(bq * 12 + h) * 4096 + nbase + row) * 64 + d0] = aa;
      }
    }
  }
#undef A0T
#undef B0T
#undef A1T
#undef B1T
}

// ---------------------------------------------------------------------------
// Kernel 3-FALLBACK (R1 version, used when ws_size is too small)
// ---------------------------------------------------------------------------
__global__ __launch_bounds__(256) void gemm_kv(const float* __restrict__ x,
                                               const unsigned short* __restrict__ Wt,
                                               unsigned short* __restrict__ k_ws,
                                               float* __restrict__ v_out) {
  __shared__ char lds[32768];
  int bid = blockIdx.x;
  int lb = (bid & 7) * 3072 + (bid >> 3);
  int mt = lb / 12, nt = lb - mt * 12;
  long m0 = (long)mt * 128; int n0 = nt * 128;
  int tid = threadIdx.x, lane = tid & 63;
  int wid = tid >> 6, wm = wid >> 1, wn = wid & 1;
  int rlo = lane & 15, gk = lane >> 4;

  const float* xs = x + m0 * 768;
  const unsigned short* wp = Wt + (long)n0 * 768;

  int arow0 = tid >> 3, ak4 = (tid & 7) << 2;
  int bn = tid >> 1, bg = (tid & 1) << 1;

  f32x4 acc[4][4];
#pragma unroll
  for (int i = 0; i < 4; ++i)
#pragma unroll
    for (int j = 0; j < 4; ++j) acc[i][j] = (f32x4){0.f, 0.f, 0.f, 0.f};

  float4 fA[4]; short8 wB[2];
#pragma unroll
  for (int it = 0; it < 4; ++it) {
    int row = it * 32 + arow0;
    fA[it] = *(const float4*)(xs + (long)row * 768 + ak4);
  }
#pragma unroll
  for (int i = 0; i < 2; ++i)
    wB[i] = *(const short8*)(wp + (long)bn * 768 + (bg + i) * 8);
#pragma unroll
  for (int it = 0; it < 4; ++it) {
    int row = it * 32 + arow0;
    short4v h;
    h[0] = (short)f2bf(fA[it].x); h[1] = (short)f2bf(fA[it].y);
    h[2] = (short)f2bf(fA[it].z); h[3] = (short)f2bf(fA[it].w);
    *(short4v*)(lds + row * 64 + ((ak4 * 2) ^ (((row >> 1) & 3) << 4))) = h;
  }
#pragma unroll
  for (int i = 0; i < 2; ++i)
    *(short8*)(lds + 16384 + bn * 64 + (((bg + i) * 16) ^ (((bn >> 1) & 3) << 4))) = wB[i];
  __syncthreads();

#pragma unroll 2
  for (int ks = 0; ks < 24; ++ks) {
    char* Ab = lds + (ks & 1) * 8192;
    char* Bb = lds + 16384 + (ks & 1) * 8192;
    bool pf = (ks + 1 < 24);
    if (pf) {
#pragma unroll
      for (int it = 0; it < 4; ++it) {
        int row = it * 32 + arow0;
        fA[it] = *(const float4*)(xs + (long)row * 768 + (ks + 1) * 32 + ak4);
      }
#pragma unroll
      for (int i = 0; i < 2; ++i)
        wB[i] = *(const short8*)(wp + (long)bn * 768 + (ks + 1) * 32 + (bg + i) * 8);
    }
    short8 af[4], bfr[4];
#pragma unroll
    for (int mi = 0; mi < 4; ++mi) {
      int row = wm * 64 + mi * 16 + rlo;
      af[mi] = *(const short8*)(Ab + row * 64 + ((gk * 16) ^ (((row >> 1) & 3) << 4)));
    }
#pragma unroll
    for (int ni = 0; ni < 4; ++ni) {
      int n = wn * 64 + ni * 16 + rlo;
      bfr[ni] = *(const short8*)(Bb + n * 64 + ((gk * 16) ^ (((n >> 1) & 3) << 4)));
    }
#pragma unroll
    for (int mi = 0; mi < 4; ++mi)
#pragma unroll
      for (int ni = 0; ni < 4; ++ni)
        acc[mi][ni] = __builtin_amdgcn_mfma_f32_16x16x32_bf16(af[mi], bfr[ni], acc[mi][ni], 0, 0, 0);
    if (pf) {
      char* An = lds + ((ks + 1) & 1) * 8192;
      char* Bn = lds + 16384 + ((ks + 1) & 1) * 8192;
#pragma unroll
      for (int it = 0; it < 4; ++it) {
        int row = it * 32 + arow0;
        short4v h;
        h[0] = (short)f2bf(fA[it].x); h[1] = (short)f2bf(fA[it].y);
        h[2] = (short)f2bf(fA[it].z); h[3] = (short)f2bf(fA[it].w);
        *(short4v*)(An + row * 64 + ((ak4 * 2) ^ (((row >> 1) & 3) << 4))) = h;
      }
#pragma unroll
      for (int i = 0; i < 2; ++i)
        *(short8*)(Bn + bn * 64 + (((bg + i) * 16) ^ (((bn >> 1) & 3) << 4))) = wB[i];
    }
    __syncthreads();
  }

  bool is_k = (n0 < 768);
  int cb = is_k ? n0 : n0 - 768;
#pragma unroll
  for (int ni = 0; ni < 4; ++ni) {
    int cc = cb + wn * 64 + ni * 16 + rlo;
    int h = cc >> 6, d = cc & 63;
#pragma unroll
    for (int mi = 0; mi < 4; ++mi) {
#pragma unroll
      for (int r = 0; r < 4; ++r) {
        long m = m0 + wm * 64 + mi * 16 + gk * 4 + r;
        int b = (int)(m >> 12), n = (int)(m & 4095);
        long off = ((long)(b * 12 + h) * 4096 + n) * 64 + d;
        float val = acc[mi][ni][r];
        if (is_k) k_ws[off] = f2bf(val);
        else      v_out[off] = val;
      }
    }
  }
}

// ---------------------------------------------------------------------------
// Kernel 4 (R9): attention, wave-owns-n-eighth, register-resident scores.
// P1: QK->regs (s[32] f32x4) + max; P2: exp+sum in regs; P3: ONE normalized
// fp32 write + bf16 p -> swizzled LDS pbuf; PV A-frags from own-wave pbuf;
// cross-wave partial reduce in LDS. Eliminates ~1 GB of redundant sraw traffic.
// ---------------------------------------------------------------------------
__global__ __launch_bounds__(512) void attn_fused2(const unsigned short* __restrict__ k_ws,
                                                   const unsigned short* __restrict__ q_ws,
                                                   const float* __restrict__ v_glob,
                                                   float* __restrict__ attn_out,
                                                   float* __restrict__ preproj) {
  // one blob so OOB pbuf-row reads (r16 in 10..15, discarded D rows) stay in-bounds
  __shared__ char blob[81920 + 32768 + 1024];
  unsigned short* pbuf = (unsigned short*)blob;       // [8 waves][10 rows][512] bf16, swizzled
  float* part = (float*)(blob + 81920);               // [8 waves][1024] fp32
  float* redm = (float*)(blob + 114688);              // [8][16]
  float* rowmax16 = redm + 128;                       // [16]
  float* rowinv16 = rowmax16 + 16;                    // [16]

  int tid = threadIdx.x, lane = tid & 63, w = tid >> 6;
  int bh = blockIdx.x;
  int r16 = lane & 15, gk = lane >> 4;
  int nW = w << 9;                                    // wave's n-base (512 cols each)

  const unsigned short* kp = k_ws + (long)bh * (4096 * 64);
  const unsigned short* qp = q_ws + (long)bh * 1024;
  float* sraw = attn_out + (long)bh * 40960;
  const float* vp = v_glob + (long)bh * (4096 * 64);

  short8 qf0 = *(const short8*)(qp + r16 * 64 + gk * 8);
  short8 qf1 = *(const short8*)(qp + r16 * 64 + 32 + gk * 8);

  // ---- P1: scores into registers + row max ----
  f32x4 s[32];
  float pmax = -3.0e38f;
#pragma unroll
  for (int ch = 0; ch < 32; ++ch) {
    int n0 = nW + (ch << 4);
    short8 kf0 = *(const short8*)(kp + (long)(n0 + r16) * 64 + gk * 8);
    short8 kf1 = *(const short8*)(kp + (long)(n0 + r16) * 64 + 32 + gk * 8);
    f32x4 d4 = (f32x4){0.f, 0.f, 0.f, 0.f};
    d4 = __builtin_amdgcn_mfma_f32_16x16x32_bf16(kf0, qf0, d4, 0, 0, 0);
    d4 = __builtin_amdgcn_mfma_f32_16x16x32_bf16(kf1, qf1, d4, 0, 0, 0);
#pragma unroll
    for (int r = 0; r < 4; ++r) {
      int n = n0 + gk * 4 + r;
      float v = d4[r];
      if (n < 10 && n != r16) v = -1e30f;
      d4[r] = v;
      pmax = fmaxf(pmax, v);
    }
    s[ch] = d4;
  }
  pmax = fmaxf(pmax, __shfl_xor(pmax, 16));
  pmax = fmaxf(pmax, __shfl_xor(pmax, 32));
  if (lane < 16) redm[w * 16 + lane] = pmax;
  __syncthreads();
  if (tid < 16) {
    float m = redm[tid];
#pragma unroll
    for (int i = 1; i < 8; ++i) m = fmaxf(m, redm[i * 16 + tid]);
    rowmax16[tid] = m;
  }
  __syncthreads();
  float mx = rowmax16[r16];

  // ---- P2: exp in regs + row sum ----
  float psum = 0.f;
#pragma unroll
  for (int ch = 0; ch < 32; ++ch) {
    f32x4 e;
#pragma unroll
    for (int r = 0; r < 4; ++r) {
      e[r] = __expf(s[ch][r] - mx);
      psum += e[r];
    }
    s[ch] = e;
  }
  psum += __shfl_xor(psum, 16);
  psum += __shfl_xor(psum, 32);
  if (lane < 16) redm[w * 16 + lane] = psum;
  __syncthreads();
  if (tid < 16) {
    float t = 0.f;
#pragma unroll
    for (int i = 0; i < 8; ++i) t += redm[i * 16 + tid];
    rowinv16[tid] = 1.0f / t;
  }
  __syncthreads();
  float inv = rowinv16[r16];

  // ---- P3a: single normalized write + bf16 p -> swizzled pbuf ----
  char* pb = (char*)pbuf + w * 10240 + r16 * 1024;    // own row base (bytes)
  int swz = (r16 & 7) << 4;                           // 16B-unit XOR key
#pragma unroll
  for (int ch = 0; ch < 32; ++ch) {
    float p0 = s[ch][0] * inv, p1 = s[ch][1] * inv;
    float p2 = s[ch][2] * inv, p3 = s[ch][3] * inv;
    if (r16 < 10) {
      *(float4*)(sraw + r16 * 4096 + nW + (ch << 4) + gk * 4) = make_float4(p0, p1, p2, p3);
      short4v h4;
      h4[0] = (short)f2bf(p0); h4[1] = (short)f2bf(p1);
      h4[2] = (short)f2bf(p2); h4[3] = (short)f2bf(p3);
      *(short4v*)(pb + ((((ch << 4) + gk * 4) * 2) ^ swz)) = h4;
    }
  }
  // own-wave pbuf write->read: in-wave lgkm ordering (compiler-inserted waits)

  // ---- P3b: PV from pbuf (A) x strided v (B) ----
  f32x4 pacc[4];
#pragma unroll
  for (int dc = 0; dc < 4; ++dc) pacc[dc] = (f32x4){0.f, 0.f, 0.f, 0.f};
#pragma unroll 2
  for (int ks = 0; ks < 16; ++ks) {
    short8 pa = *(const short8*)(pb + (((ks * 32 + gk * 8) * 2) ^ swz));
    const float* vbase = vp + (long)(nW + ks * 32 + gk * 8) * 64 + r16;
#pragma unroll
    for (int dc = 0; dc < 4; ++dc) {
      short8 vb;
      const float* vrow = vbase + dc * 16;
#pragma unroll
      for (int j = 0; j < 8; ++j) vb[j] = (short)f2bf(vrow[j * 64]);
      pacc[dc] = __builtin_amdgcn_mfma_f32_16x16x32_bf16(pa, vb, pacc[dc], 0, 0, 0);
    }
  }
#pragma unroll
  for (int dc = 0; dc < 4; ++dc)
#pragma unroll
    for (int r = 0; r < 4; ++r)
      part[w * 1024 + dc * 256 + (gk * 4 + r) * 16 + r16] = pacc[dc][r];
  __syncthreads();

  // ---- P4: cross-wave reduce + preproj write ----
  int b = bh / 12, h = bh - b * 12;
  for (int idx = tid; idx < 640; idx += 512) {
    int tt = idx >> 6, d = idx & 63;
    int dc = d >> 4, dl = d & 15;
    float sum = 0.f;
#pragma unroll
    for (int i = 0; i < 8; ++i) sum += part[i * 1024 + dc * 256 + tt * 16 + dl];
    preproj[((long)b * 10 + tt) * 768 + h * 64 + d] = sum;
  }
}

// ---------------------------------------------------------------------------
// Kernel 5: x_cls = preproj @ Wp + bp
// ---------------------------------------------------------------------------
__global__ __launch_bounds__(256) void proj_out_k(const float* __restrict__ preproj,
                                                  const float* __restrict__ Wp,
                                                  const float* __restrict__ bp,
                                                  float* __restrict__ out0) {
  int b = blockIdx.x, tid = threadIdx.x;
  __shared__ float xr[7680];
  const float* pp = preproj + (long)b * 7680;
  for (int i = tid; i < 7680; i += 256) xr[i] = pp[i];
  __syncthreads();
  float acc[10][3];
#pragma unroll
  for (int t = 0; t < 10; ++t) { acc[t][0] = 0.f; acc[t][1] = 0.f; acc[t][2] = 0.f; }
  for (int k = 0; k < 768; ++k) {
    const float* wr = Wp + (long)k * 768;
    float w0 = wr[tid], w1 = wr[tid + 256], w2 = wr[tid + 512];
#pragma unroll
    for (int t = 0; t < 10; ++t) {
      float xv = xr[t * 768 + k];
      acc[t][0] += xv * w0; acc[t][1] += xv * w1; acc[t][2] += xv * w2;
    }
  }
  float b0 = bp[tid], b1 = bp[tid + 256], b2 = bp[tid + 512];
  float* op = out0 + (long)b * 7680;
#pragma unroll
  for (int t = 0; t < 10; ++t) {
    op[t * 768 + tid]       = acc[t][0] + b0;
    op[t * 768 + tid + 256] = acc[t][1] + b1;
    op[t * 768 + tid + 512] = acc[t][2] + b2;
  }
}

// ---------------------------------------------------------------------------
extern "C" void kernel_launch(void* const* d_in, const int* in_sizes, int n_in,
                              void* d_out, int out_size, void* d_ws, size_t ws_size,
                              hipStream_t stream) {
  (void)in_sizes; (void)n_in; (void)out_size;
  const float* x  = (const float*)d_in[0];
  const float* Wq = (const float*)d_in[1];
  const float* Wk = (const float*)d_in[2];
  const float* Wv = (const float*)d_in[3];
  const float* Wp = (const float*)d_in[4];
  const float* bp = (const float*)d_in[5];

  float* out      = (float*)d_out;
  float* attn_out = out + 491520;                 // [64,12,10,4096]
  float* v_out    = out + 31948800;               // [64,12,4096,64]

  char* ws = (char*)d_ws;
  const size_t NEED_BIG = 811204608;              // x_bf16 + k_ws + small

  if (ws_size >= NEED_BIG) {
    unsigned short* x_bf16 = (unsigned short*)(ws);               // 402,653,184 B
    unsigned short* k_ws = (unsigned short*)(ws + 402653184);     // 402,653,184 B
    unsigned short* q_ws = (unsigned short*)(ws + 805306368);     //   1,572,864 B
    unsigned short* Wt   = (unsigned short*)(ws + 806879232);     //   2,359,296 B
    float* preproj       = (float*)(ws + 809238528);              //   1,966,080 B

    conv_x<<<dim3(2048), dim3(256), 0, stream>>>(x, x_bf16);
    prep_w<<<dim3(4608), dim3(256), 0, stream>>>(Wk, Wv, Wt);
    q_proj<<<dim3(64), dim3(256), 0, stream>>>(x, Wq, q_ws);
    gemm_kv8<<<dim3(6144), dim3(512), 0, stream>>>(x_bf16, Wt, k_ws, v_out);
    attn_fused2<<<dim3(768), dim3(512), 0, stream>>>(k_ws, q_ws, v_out, attn_out, preproj);
    proj_out_k<<<dim3(64), dim3(256), 0, stream>>>(preproj, Wp, bp, out);
  } else {
    unsigned short* k_ws = (unsigned short*)(ws);                 // 402,653,184 B
    unsigned short* q_ws = (unsigned short*)(ws + 402653184);
    unsigned short* Wt   = (unsigned short*)(ws + 404226048);
    float* preproj       = (float*)(ws + 406585344);

    prep_w<<<dim3(4608), dim3(256), 0, stream>>>(Wk, Wv, Wt);
    q_proj<<<dim3(64), dim3(256), 0, stream>>>(x, Wq, q_ws);
    gemm_kv<<<dim3(24576), dim3(256), 0, stream>>>(x, Wt, k_ws, v_out);
    attn_fused2<<<dim3(768), dim3(512), 0, stream>>>(k_ws, q_ws, v_out, attn_out, preproj);
    proj_out_k<<<dim3(64), dim3(256), 0, stream>>>(preproj, Wp, bp, out);
  }
}

// Round 10
// 1491.211 us; speedup vs baseline: 1.2973x; 1.0028x over previous
//
#include <hip/hip_runtime.h>

typedef __attribute__((ext_vector_type(8))) short short8;
typedef __attribute__((ext_vector_type(4))) short short4v;
typedef __attribute__((ext_vector_type(4))) float f32x4;

__device__ __forceinline__ unsigned short f2bf(float f) {
  union { float f; unsigned u; } v; v.f = f;
  unsigned r = v.u + 0x7FFFu + ((v.u >> 16) & 1u);
  return (unsigned short)(r >> 16);
}

__device__ __forceinline__ float bf2f(unsigned short h) {
  union { unsigned u; float f; } v; v.u = ((unsigned)h) << 16;
  return v.f;
}

__device__ __forceinline__ void gload16(const void* g, void* l) {
  __builtin_amdgcn_global_load_lds(
      (const __attribute__((address_space(1))) void*)g,
      (__attribute__((address_space(3))) void*)l, 16, 0, 0);
}

// ---------------------------------------------------------------------------
// Kernel 0: x (fp32) -> x_bf16, vectorized 8 elems/thread
// ---------------------------------------------------------------------------
__global__ __launch_bounds__(256) void conv_x(const float* __restrict__ x,
                                              unsigned short* __restrict__ xb) {
  const long total = 25165824;                        // 201326592 / 8
  long stride = (long)gridDim.x * 256;
  for (long u = blockIdx.x * 256 + threadIdx.x; u < total; u += stride) {
    const float* p = x + u * 8;
    float4 a = *(const float4*)p;
    float4 b = *(const float4*)(p + 4);
    short8 h;
    h[0] = (short)f2bf(a.x); h[1] = (short)f2bf(a.y);
    h[2] = (short)f2bf(a.z); h[3] = (short)f2bf(a.w);
    h[4] = (short)f2bf(b.x); h[5] = (short)f2bf(b.y);
    h[6] = (short)f2bf(b.z); h[7] = (short)f2bf(b.w);
    *(short8*)(xb + u * 8) = h;
  }
}

// ---------------------------------------------------------------------------
// Kernel 1: Wt[n][k] = bf16( [Wk | Wv](k, n) )   (B^T layout, n in [0,1536))
// ---------------------------------------------------------------------------
__global__ __launch_bounds__(256) void prep_w(const float* __restrict__ Wk,
                                              const float* __restrict__ Wv,
                                              unsigned short* __restrict__ Wt) {
  int idx = blockIdx.x * 256 + threadIdx.x;           // 1536*768 elements
  int n = idx / 768, k = idx - n * 768;
  float w = (n < 768) ? Wk[k * 768 + n] : Wv[k * 768 + (n - 768)];
  Wt[idx] = f2bf(w);
}

// ---------------------------------------------------------------------------
// Kernel 2: q = scale * x[:, :10] @ Wq  -> q_ws[b][h][16][64] bf16 (rows 10..15 = 0)
// ---------------------------------------------------------------------------
__global__ __launch_bounds__(256) void q_proj(const float* __restrict__ x,
                                              const float* __restrict__ Wq,
                                              unsigned short* __restrict__ q_ws) {
  int b = blockIdx.x, tid = threadIdx.x;
  __shared__ float xr[7680];
  const float* xp = x + (long)b * 4096 * 768;
  for (int i = tid; i < 7680; i += 256) xr[i] = xp[i];
  for (int i = tid; i < 12 * 6 * 64; i += 256) {
    int h = i / 384, rem = i - h * 384;
    int t = 10 + rem / 64, d = rem & 63;
    q_ws[(((long)(b * 12 + h) * 16 + t) << 6) + d] = 0;
  }
  __syncthreads();
  float acc[10][3];
#pragma unroll
  for (int t = 0; t < 10; ++t) { acc[t][0] = 0.f; acc[t][1] = 0.f; acc[t][2] = 0.f; }
  for (int k = 0; k < 768; ++k) {
    const float* wr = Wq + (long)k * 768;
    float w0 = wr[tid], w1 = wr[tid + 256], w2 = wr[tid + 512];
#pragma unroll
    for (int t = 0; t < 10; ++t) {
      float xv = xr[t * 768 + k];
      acc[t][0] += xv * w0; acc[t][1] += xv * w1; acc[t][2] += xv * w2;
    }
  }
#pragma unroll
  for (int t = 0; t < 10; ++t) {
#pragma unroll
    for (int j = 0; j < 3; ++j) {
      int c = tid + j * 256;
      int h = c >> 6, d = c & 63;
      q_ws[(((long)(b * 12 + h) * 16 + t) << 6) + d] = f2bf(acc[t][j] * 0.125f);
    }
  }
}

// ---------------------------------------------------------------------------
// Kernel 3 (R8, kept): 256x256 tile, BK=64, 8 waves, 4-phase schedule.
// ---------------------------------------------------------------------------
__global__ __launch_bounds__(512, 2) void gemm_kv8(const unsigned short* __restrict__ xb,
                                                   const unsigned short* __restrict__ Wt,
                                                   unsigned short* __restrict__ k_ws,
                                                   float* __restrict__ v_out) {
  __shared__ char smem[131072];                       // A0 B0 A1 B1, 32KB each
#define A0T ((unsigned short*)(smem))
#define B0T ((unsigned short*)(smem + 32768))
#define A1T ((unsigned short*)(smem + 65536))
#define B1T ((unsigned short*)(smem + 98304))

  int bid = blockIdx.x;
  int lb = (bid & 7) * 768 + (bid >> 3);              // XCD swizzle (6144 % 8 == 0)
  int mt = lb / 6, nt = lb - mt * 6;
  long m0 = (long)mt * 256; int n0 = nt * 256;
  int tid = threadIdx.x, lane = tid & 63;
  int uw = __builtin_amdgcn_readfirstlane(tid >> 6);  // uniform wave id 0..7
  int wm = uw >> 2, wn = uw & 3;                      // 2 M-waves x 4 N-waves
  int r16 = lane & 15, gk = lane >> 4;

  const unsigned short* xs = xb + m0 * 768;
  const unsigned short* wp = Wt + (long)n0 * 768;

  int srow8 = lane >> 3;
  int sch = ((lane & 7) ^ (srow8 & 7)) << 3;          // source elem offset
  const unsigned short* sA = xs + (long)(uw * 8 + srow8) * 768 + sch;
  const unsigned short* sB = wp + (long)(uw * 8 + srow8) * 768 + sch;

  int ck0 = ((gk ^ (r16 & 7)) << 3);
  int ck1 = (((4 + gk) ^ (r16 & 7)) << 3);
  int arb = (wm * 128 + r16) * 64;                    // A row base (elems)
  int brb = (wn * 64 + r16) * 64;                     // B row base (elems)

  f32x4 acc[8][4];
#pragma unroll
  for (int i = 0; i < 8; ++i)
#pragma unroll
    for (int j = 0; j < 4; ++j) acc[i][j] = (f32x4){0.f, 0.f, 0.f, 0.f};

#define SGA(AT, I, KO) gload16(sA + (long)(I) * 49152 + (KO), (AT) + ((I) * 64 + uw * 8) * 64)
#define SGB(BT, I, KO) gload16(sB + (long)(I) * 49152 + (KO), (BT) + ((I) * 64 + uw * 8) * 64)
#define WBND asm volatile("s_waitcnt vmcnt(0)\n\ts_barrier" ::: "memory")
#define PBAR __builtin_amdgcn_s_barrier()

#define BODY(AC, BC, AN, BN, KOS, DOST)                                         \
  {                                                                             \
    short8 fa[4][2], fb0[2][2], fb1[2][2];                                      \
    if (DOST) { SGA(AN, 0, KOS); SGA(AN, 1, KOS); SGB(BN, 0, KOS); SGB(BN, 1, KOS); } \
    _Pragma("unroll")                                                           \
    for (int mi = 0; mi < 4; ++mi) {                                            \
      fa[mi][0] = *(const short8*)&AC[arb + mi * 1024 + ck0];                   \
      fa[mi][1] = *(const short8*)&AC[arb + mi * 1024 + ck1];                   \
    }                                                                           \
    _Pragma("unroll")                                                           \
    for (int ni = 0; ni < 2; ++ni) {                                            \
      fb0[ni][0] = *(const short8*)&BC[brb + ni * 1024 + ck0];                  \
      fb0[ni][1] = *(const short8*)&BC[brb + ni * 1024 + ck1];                  \
    }                                                                           \
    PBAR;                                                                       \
    __builtin_amdgcn_s_setprio(1);                                              \
    _Pragma("unroll")                                                           \
    for (int mi = 0; mi < 4; ++mi)                                              \
      _Pragma("unroll")                                                         \
      for (int ni = 0; ni < 2; ++ni) {                                          \
        acc[mi][ni] = __builtin_amdgcn_mfma_f32_16x16x32_bf16(fa[mi][0], fb0[ni][0], acc[mi][ni], 0, 0, 0); \
        acc[mi][ni] = __builtin_amdgcn_mfma_f32_16x16x32_bf16(fa[mi][1], fb0[ni][1], acc[mi][ni], 0, 0, 0); \
      }                                                                         \
    __builtin_amdgcn_s_setprio(0);                                              \
    PBAR;                                                                       \
    if (DOST) { SGA(AN, 2, KOS); SGA(AN, 3, KOS); SGB(BN, 2, KOS); SGB(BN, 3, KOS); } \
    _Pragma("unroll")                                                           \
    for (int ni = 0; ni < 2; ++ni) {                                            \
      fb1[ni][0] = *(const short8*)&BC[brb + (ni + 2) * 1024 + ck0];            \
      fb1[ni][1] = *(const short8*)&BC[brb + (ni + 2) * 1024 + ck1];            \
    }                                                                           \
    PBAR;                                                                       \
    __builtin_amdgcn_s_setprio(1);                                              \
    _Pragma("unroll")                                                           \
    for (int mi = 0; mi < 4; ++mi)                                              \
      _Pragma("unroll")                                                         \
      for (int ni = 0; ni < 2; ++ni) {                                          \
        acc[mi][ni + 2] = __builtin_amdgcn_mfma_f32_16x16x32_bf16(fa[mi][0], fb1[ni][0], acc[mi][ni + 2], 0, 0, 0); \
        acc[mi][ni + 2] = __builtin_amdgcn_mfma_f32_16x16x32_bf16(fa[mi][1], fb1[ni][1], acc[mi][ni + 2], 0, 0, 0); \
      }                                                                         \
    __builtin_amdgcn_s_setprio(0);                                              \
    PBAR;                                                                       \
    _Pragma("unroll")                                                           \
    for (int mi = 0; mi < 4; ++mi) {                                            \
      fa[mi][0] = *(const short8*)&AC[arb + (mi + 4) * 1024 + ck0];             \
      fa[mi][1] = *(const short8*)&AC[arb + (mi + 4) * 1024 + ck1];             \
    }                                                                           \
    PBAR;                                                                       \
    __builtin_amdgcn_s_setprio(1);                                              \
    _Pragma("unroll")                                                           \
    for (int mi = 0; mi < 4; ++mi)                                              \
      _Pragma("unroll")                                                         \
      for (int ni = 0; ni < 2; ++ni) {                                          \
        acc[mi + 4][ni + 2] = __builtin_amdgcn_mfma_f32_16x16x32_bf16(fa[mi][0], fb1[ni][0], acc[mi + 4][ni + 2], 0, 0, 0); \
        acc[mi + 4][ni + 2] = __builtin_amdgcn_mfma_f32_16x16x32_bf16(fa[mi][1], fb1[ni][1], acc[mi + 4][ni + 2], 0, 0, 0); \
      }                                                                         \
    __builtin_amdgcn_s_setprio(0);                                              \
    PBAR;                                                                       \
    __builtin_amdgcn_s_setprio(1);                                              \
    _Pragma("unroll")                                                           \
    for (int mi = 0; mi < 4; ++mi)                                              \
      _Pragma("unroll")                                                         \
      for (int ni = 0; ni < 2; ++ni) {                                          \
        acc[mi + 4][ni] = __builtin_amdgcn_mfma_f32_16x16x32_bf16(fa[mi][0], fb0[ni][0], acc[mi + 4][ni], 0, 0, 0); \
        acc[mi + 4][ni] = __builtin_amdgcn_mfma_f32_16x16x32_bf16(fa[mi][1], fb0[ni][1], acc[mi + 4][ni], 0, 0, 0); \
      }                                                                         \
    __builtin_amdgcn_s_setprio(0);                                              \
  }

  SGA(A0T, 0, 0); SGA(A0T, 1, 0); SGA(A0T, 2, 0); SGA(A0T, 3, 0);
  SGB(B0T, 0, 0); SGB(B0T, 1, 0); SGB(B0T, 2, 0); SGB(B0T, 3, 0);
  WBND;

#pragma unroll 1
  for (int t = 0; t < 12; t += 2) {
    BODY(A0T, B0T, A1T, B1T, (t + 1) * 64, true);
    WBND;
    BODY(A1T, B1T, A0T, B0T, (t + 2) * 64, (t + 2) < 12);
    WBND;
  }
#undef BODY
#undef SGA
#undef SGB
#undef WBND
#undef PBAR

  float* scr = (float*)smem + uw * 1088;              // 16 rows x 68 floats
  bool is_k = (n0 < 768);
  int h = (is_k ? (n0 >> 6) : ((n0 - 768) >> 6)) + wn;
  int bq = (int)(m0 >> 12);
  int nb = (int)(m0 & 4095) + wm * 128;

#pragma unroll
  for (int mi = 0; mi < 8; ++mi) {
#pragma unroll
    for (int ni = 0; ni < 4; ++ni)
#pragma unroll
      for (int r = 0; r < 4; ++r)
        scr[(gk * 4 + r) * 68 + ni * 16 + r16] = acc[mi][ni][r];
    int nbase = nb + mi * 16;
    if (is_k) {
#pragma unroll
      for (int p = 0; p < 2; ++p) {
        int row = p * 8 + (lane >> 3), d0 = (lane & 7) << 3;
        float4 aa = *(const float4*)&scr[row * 68 + d0];
        float4 bb = *(const float4*)&scr[row * 68 + d0 + 4];
        short8 hh;
        hh[0] = (short)f2bf(aa.x); hh[1] = (short)f2bf(aa.y);
        hh[2] = (short)f2bf(aa.z); hh[3] = (short)f2bf(aa.w);
        hh[4] = (short)f2bf(bb.x); hh[5] = (short)f2bf(bb.y);
        hh[6] = (short)f2bf(bb.z); hh[7] = (short)f2bf(bb.w);
        *(short8*)&k_ws[((long)(bq * 12 + h) * 4096 + nbase + row) * 64 + d0] = hh;
      }
    } else {
#pragma unroll
      for (int p = 0; p < 4; ++p) {
        int row = p * 4 + (lane >> 4), d0 = (lane & 15) << 2;
        float4 aa = *(const float4*)&scr[row * 68 + d0];
        *(float4*)&v_out[((long)(bq * 12 + h) * 4096 + nbase + row) * 64 + d0] = aa;
      }
    }
  }
#undef A0T
#undef B0T
#undef A1T
#undef B1T
}

// ---------------------------------------------------------------------------
// Kernel 3-FALLBACK (R1 version, used when ws_size is too small)
// ---------------------------------------------------------------------------
__global__ __launch_bounds__(256) void gemm_kv(const float* __restrict__ x,
                                               const unsigned short* __restrict__ Wt,
                                               unsigned short* __restrict__ k_ws,
                                               float* __restrict__ v_out) {
  __shared__ char lds[32768];
  int bid = blockIdx.x;
  int lb = (bid & 7) * 3072 + (bid >> 3);
  int mt = lb / 12, nt = lb - mt * 12;
  long m0 = (long)mt * 128; int n0 = nt * 128;
  int tid = threadIdx.x, lane = tid & 63;
  int wid = tid >> 6, wm = wid >> 1, wn = wid & 1;
  int rlo = lane & 15, gk = lane >> 4;

  const float* xs = x + m0 * 768;
  const unsigned short* wp = Wt + (long)n0 * 768;

  int arow0 = tid >> 3, ak4 = (tid & 7) << 2;
  int bn = tid >> 1, bg = (tid & 1) << 1;

  f32x4 acc[4][4];
#pragma unroll
  for (int i = 0; i < 4; ++i)
#pragma unroll
    for (int j = 0; j < 4; ++j) acc[i][j] = (f32x4){0.f, 0.f, 0.f, 0.f};

  float4 fA[4]; short8 wB[2];
#pragma unroll
  for (int it = 0; it < 4; ++it) {
    int row = it * 32 + arow0;
    fA[it] = *(const float4*)(xs + (long)row * 768 + ak4);
  }
#pragma unroll
  for (int i = 0; i < 2; ++i)
    wB[i] = *(const short8*)(wp + (long)bn * 768 + (bg + i) * 8);
#pragma unroll
  for (int it = 0; it < 4; ++it) {
    int row = it * 32 + arow0;
    short4v h;
    h[0] = (short)f2bf(fA[it].x); h[1] = (short)f2bf(fA[it].y);
    h[2] = (short)f2bf(fA[it].z); h[3] = (short)f2bf(fA[it].w);
    *(short4v*)(lds + row * 64 + ((ak4 * 2) ^ (((row >> 1) & 3) << 4))) = h;
  }
#pragma unroll
  for (int i = 0; i < 2; ++i)
    *(short8*)(lds + 16384 + bn * 64 + (((bg + i) * 16) ^ (((bn >> 1) & 3) << 4))) = wB[i];
  __syncthreads();

#pragma unroll 2
  for (int ks = 0; ks < 24; ++ks) {
    char* Ab = lds + (ks & 1) * 8192;
    char* Bb = lds + 16384 + (ks & 1) * 8192;
    bool pf = (ks + 1 < 24);
    if (pf) {
#pragma unroll
      for (int it = 0; it < 4; ++it) {
        int row = it * 32 + arow0;
        fA[it] = *(const float4*)(xs + (long)row * 768 + (ks + 1) * 32 + ak4);
      }
#pragma unroll
      for (int i = 0; i < 2; ++i)
        wB[i] = *(const short8*)(wp + (long)bn * 768 + (ks + 1) * 32 + (bg + i) * 8);
    }
    short8 af[4], bfr[4];
#pragma unroll
    for (int mi = 0; mi < 4; ++mi) {
      int row = wm * 64 + mi * 16 + rlo;
      af[mi] = *(const short8*)(Ab + row * 64 + ((gk * 16) ^ (((row >> 1) & 3) << 4)));
    }
#pragma unroll
    for (int ni = 0; ni < 4; ++ni) {
      int n = wn * 64 + ni * 16 + rlo;
      bfr[ni] = *(const short8*)(Bb + n * 64 + ((gk * 16) ^ (((n >> 1) & 3) << 4)));
    }
#pragma unroll
    for (int mi = 0; mi < 4; ++mi)
#pragma unroll
      for (int ni = 0; ni < 4; ++ni)
        acc[mi][ni] = __builtin_amdgcn_mfma_f32_16x16x32_bf16(af[mi], bfr[ni], acc[mi][ni], 0, 0, 0);
    if (pf) {
      char* An = lds + ((ks + 1) & 1) * 8192;
      char* Bn = lds + 16384 + ((ks + 1) & 1) * 8192;
#pragma unroll
      for (int it = 0; it < 4; ++it) {
        int row = it * 32 + arow0;
        short4v h;
        h[0] = (short)f2bf(fA[it].x); h[1] = (short)f2bf(fA[it].y);
        h[2] = (short)f2bf(fA[it].z); h[3] = (short)f2bf(fA[it].w);
        *(short4v*)(An + row * 64 + ((ak4 * 2) ^ (((row >> 1) & 3) << 4))) = h;
      }
#pragma unroll
      for (int i = 0; i < 2; ++i)
        *(short8*)(Bn + bn * 64 + (((bg + i) * 16) ^ (((bn >> 1) & 3) << 4))) = wB[i];
    }
    __syncthreads();
  }

  bool is_k = (n0 < 768);
  int cb = is_k ? n0 : n0 - 768;
#pragma unroll
  for (int ni = 0; ni < 4; ++ni) {
    int cc = cb + wn * 64 + ni * 16 + rlo;
    int h = cc >> 6, d = cc & 63;
#pragma unroll
    for (int mi = 0; mi < 4; ++mi) {
#pragma unroll
      for (int r = 0; r < 4; ++r) {
        long m = m0 + wm * 64 + mi * 16 + gk * 4 + r;
        int b = (int)(m >> 12), n = (int)(m & 4095);
        long off = ((long)(b * 12 + h) * 4096 + n) * 64 + d;
        float val = acc[mi][ni][r];
        if (is_k) k_ws[off] = f2bf(val);
        else      v_out[off] = val;
      }
    }
  }
}

// ---------------------------------------------------------------------------
// Kernel 4 (R10): attention, wave-owns-n-eighth, bf16 raw scores in LDS.
// P1: QK -> masked bf16 scores -> swizzled pbuf + reg max. P2: read-back,
// exp+sum. P3a: ONE normalized fp32 global write. P3b: PV with p recomputed
// from pbuf on the fly. P4: cross-wave reduce. No register spill (~80 VGPR).
// ---------------------------------------------------------------------------
__global__ __launch_bounds__(512) void attn_fused3(const unsigned short* __restrict__ k_ws,
                                                   const unsigned short* __restrict__ q_ws,
                                                   const float* __restrict__ v_glob,
                                                   float* __restrict__ attn_out,
                                                   float* __restrict__ preproj) {
  __shared__ char blob[115712];
  unsigned short* pbuf = (unsigned short*)blob;       // [8 waves][10 rows][512] bf16, swizzled
  float* part = (float*)(blob + 81920);               // [8 waves][1024] fp32
  float* redm = (float*)(blob + 114688);              // [8][16]
  float* rowmax16 = redm + 128;                       // [16]
  float* rowinv16 = rowmax16 + 16;                    // [16]

  int tid = threadIdx.x, lane = tid & 63, w = tid >> 6;
  int bh = blockIdx.x;
  int r16 = lane & 15, gk = lane >> 4;
  int trc = (r16 < 10) ? r16 : 9;                     // clamped row
  int nW = w << 9;                                    // wave's n-base (512 cols)

  const unsigned short* kp = k_ws + (long)bh * (4096 * 64);
  const unsigned short* qp = q_ws + (long)bh * 1024;
  float* sraw = attn_out + (long)bh * 40960;
  const float* vp = v_glob + (long)bh * (4096 * 64);

  short8 qf0 = *(const short8*)(qp + r16 * 64 + gk * 8);
  short8 qf1 = *(const short8*)(qp + r16 * 64 + 32 + gk * 8);

  char* pbw = (char*)pbuf + w * 10240 + r16 * 1024;   // own-row write base
  int swz = (r16 & 7) << 4;                           // write-side XOR key (bytes)

  // ---- P1: QK -> masked bf16 scores to pbuf + row max ----
  float pmax = -3.0e38f;
#pragma unroll 4
  for (int ch = 0; ch < 32; ++ch) {
    int n0 = nW + (ch << 4);
    short8 kf0 = *(const short8*)(kp + (long)(n0 + r16) * 64 + gk * 8);
    short8 kf1 = *(const short8*)(kp + (long)(n0 + r16) * 64 + 32 + gk * 8);
    f32x4 d4 = (f32x4){0.f, 0.f, 0.f, 0.f};
    d4 = __builtin_amdgcn_mfma_f32_16x16x32_bf16(kf0, qf0, d4, 0, 0, 0);
    d4 = __builtin_amdgcn_mfma_f32_16x16x32_bf16(kf1, qf1, d4, 0, 0, 0);
#pragma unroll
    for (int r = 0; r < 4; ++r) {
      int n = n0 + gk * 4 + r;
      float v = d4[r];
      if (n < 10 && n != r16) v = -1e30f;
      d4[r] = v;
      pmax = fmaxf(pmax, v);
    }
    if (r16 < 10) {
      short4v h4;
      h4[0] = (short)f2bf(d4[0]); h4[1] = (short)f2bf(d4[1]);
      h4[2] = (short)f2bf(d4[2]); h4[3] = (short)f2bf(d4[3]);
      *(short4v*)(pbw + ((ch * 32 + gk * 8) ^ swz)) = h4;
    }
  }
  pmax = fmaxf(pmax, __shfl_xor(pmax, 16));
  pmax = fmaxf(pmax, __shfl_xor(pmax, 32));
  if (lane < 16) redm[w * 16 + lane] = pmax;
  __syncthreads();
  if (tid < 16) {
    float m = redm[tid];
#pragma unroll
    for (int i = 1; i < 8; ++i) m = fmaxf(m, redm[i * 16 + tid]);
    rowmax16[tid] = m;
  }
  __syncthreads();

  // ---- P2: read-back own row, exp + sum ----
  float mx = rowmax16[trc];
  char* pbr = (char*)pbuf + w * 10240 + trc * 1024;
  int swr = (trc & 7) << 4;                           // matches row trc's write key
  float psum = 0.f;
#pragma unroll 4
  for (int i = 0; i < 16; ++i) {
    short8 sv = *(const short8*)(pbr + ((i * 64 + gk * 16) ^ swr));
#pragma unroll
    for (int j = 0; j < 8; ++j) psum += __expf(bf2f((unsigned short)sv[j]) - mx);
  }
  psum += __shfl_xor(psum, 16);
  psum += __shfl_xor(psum, 32);
  if (lane < 16) redm[w * 16 + lane] = psum;
  __syncthreads();
  if (tid < 16) {
    float t = 0.f;
#pragma unroll
    for (int i = 0; i < 8; ++i) t += redm[i * 16 + tid];
    rowinv16[tid] = 1.0f / t;
  }
  __syncthreads();
  float inv = rowinv16[trc];

  // ---- P3a: single normalized fp32 global write ----
  if (r16 < 10) {
#pragma unroll 4
    for (int i = 0; i < 16; ++i) {
      short8 sv = *(const short8*)(pbw + ((i * 64 + gk * 16) ^ swz));
      float4 o0, o1;
      o0.x = __expf(bf2f((unsigned short)sv[0]) - mx) * inv;
      o0.y = __expf(bf2f((unsigned short)sv[1]) - mx) * inv;
      o0.z = __expf(bf2f((unsigned short)sv[2]) - mx) * inv;
      o0.w = __expf(bf2f((unsigned short)sv[3]) - mx) * inv;
      o1.x = __expf(bf2f((unsigned short)sv[4]) - mx) * inv;
      o1.y = __expf(bf2f((unsigned short)sv[5]) - mx) * inv;
      o1.z = __expf(bf2f((unsigned short)sv[6]) - mx) * inv;
      o1.w = __expf(bf2f((unsigned short)sv[7]) - mx) * inv;
      float* gp = sraw + r16 * 4096 + nW + i * 32 + gk * 8;
      *(float4*)gp = o0;
      *(float4*)(gp + 4) = o1;
    }
  }

  // ---- P3b: PV, p recomputed from pbuf row trc (dead lanes duplicate row 9) ----
  f32x4 pacc[4];
#pragma unroll
  for (int dc = 0; dc < 4; ++dc) pacc[dc] = (f32x4){0.f, 0.f, 0.f, 0.f};
#pragma unroll 2
  for (int ks = 0; ks < 16; ++ks) {
    short8 raw = *(const short8*)(pbr + ((ks * 64 + gk * 16) ^ swr));
    short8 pa;
#pragma unroll
    for (int j = 0; j < 8; ++j)
      pa[j] = (short)f2bf(__expf(bf2f((unsigned short)raw[j]) - mx) * inv);
    const float* vbase = vp + (long)(nW + ks * 32 + gk * 8) * 64 + r16;
#pragma unroll
    for (int dc = 0; dc < 4; ++dc) {
      short8 vb;
      const float* vrow = vbase + dc * 16;
#pragma unroll
      for (int j = 0; j < 8; ++j) vb[j] = (short)f2bf(vrow[j * 64]);
      pacc[dc] = __builtin_amdgcn_mfma_f32_16x16x32_bf16(pa, vb, pacc[dc], 0, 0, 0);
    }
  }
#pragma unroll
  for (int dc = 0; dc < 4; ++dc)
#pragma unroll
    for (int r = 0; r < 4; ++r)
      part[w * 1024 + dc * 256 + (gk * 4 + r) * 16 + r16] = pacc[dc][r];
  __syncthreads();

  // ---- P4: cross-wave reduce + preproj write ----
  int b = bh / 12, h = bh - b * 12;
  for (int idx = tid; idx < 640; idx += 512) {
    int tt = idx >> 6, d = idx & 63;
    int dc = d >> 4, dl = d & 15;
    float sum = 0.f;
#pragma unroll
    for (int i = 0; i < 8; ++i) sum += part[i * 1024 + dc * 256 + tt * 16 + dl];
    preproj[((long)b * 10 + tt) * 768 + h * 64 + d] = sum;
  }
}

// ---------------------------------------------------------------------------
// Kernel 5: x_cls = preproj @ Wp + bp
// ---------------------------------------------------------------------------
__global__ __launch_bounds__(256) void proj_out_k(const float* __restrict__ preproj,
                                                  const float* __restrict__ Wp,
                                                  const float* __restrict__ bp,
                                                  float* __restrict__ out0) {
  int b = blockIdx.x, tid = threadIdx.x;
  __shared__ float xr[7680];
  const float* pp = preproj + (long)b * 7680;
  for (int i = tid; i < 7680; i += 256) xr[i] = pp[i];
  __syncthreads();
  float acc[10][3];
#pragma unroll
  for (int t = 0; t < 10; ++t) { acc[t][0] = 0.f; acc[t][1] = 0.f; acc[t][2] = 0.f; }
  for (int k = 0; k < 768; ++k) {
    const float* wr = Wp + (long)k * 768;
    float w0 = wr[tid], w1 = wr[tid + 256], w2 = wr[tid + 512];
#pragma unroll
    for (int t = 0; t < 10; ++t) {
      float xv = xr[t * 768 + k];
      acc[t][0] += xv * w0; acc[t][1] += xv * w1; acc[t][2] += xv * w2;
    }
  }
  float b0 = bp[tid], b1 = bp[tid + 256], b2 = bp[tid + 512];
  float* op = out0 + (long)b * 7680;
#pragma unroll
  for (int t = 0; t < 10; ++t) {
    op[t * 768 + tid]       = acc[t][0] + b0;
    op[t * 768 + tid + 256] = acc[t][1] + b1;
    op[t * 768 + tid + 512] = acc[t][2] + b2;
  }
}

// ---------------------------------------------------------------------------
extern "C" void kernel_launch(void* const* d_in, const int* in_sizes, int n_in,
                              void* d_out, int out_size, void* d_ws, size_t ws_size,
                              hipStream_t stream) {
  (void)in_sizes; (void)n_in; (void)out_size;
  const float* x  = (const float*)d_in[0];
  const float* Wq = (const float*)d_in[1];
  const float* Wk = (const float*)d_in[2];
  const float* Wv = (const float*)d_in[3];
  const float* Wp = (const float*)d_in[4];
  const float* bp = (const float*)d_in[5];

  float* out      = (float*)d_out;
  float* attn_out = out + 491520;                 // [64,12,10,4096]
  float* v_out    = out + 31948800;               // [64,12,4096,64]

  char* ws = (char*)d_ws;
  const size_t NEED_BIG = 811204608;              // x_bf16 + k_ws + small

  if (ws_size >= NEED_BIG) {
    unsigned short* x_bf16 = (unsigned short*)(ws);               // 402,653,184 B
    unsigned short* k_ws = (unsigned short*)(ws + 402653184);     // 402,653,184 B
    unsigned short* q_ws = (unsigned short*)(ws + 805306368);     //   1,572,864 B
    unsigned short* Wt   = (unsigned short*)(ws + 806879232);     //   2,359,296 B
    float* preproj       = (float*)(ws + 809238528);              //   1,966,080 B

    conv_x<<<dim3(2048), dim3(256), 0, stream>>>(x, x_bf16);
    prep_w<<<dim3(4608), dim3(256), 0, stream>>>(Wk, Wv, Wt);
    q_proj<<<dim3(64), dim3(256), 0, stream>>>(x, Wq, q_ws);
    gemm_kv8<<<dim3(6144), dim3(512), 0, stream>>>(x_bf16, Wt, k_ws, v_out);
    attn_fused3<<<dim3(768), dim3(512), 0, stream>>>(k_ws, q_ws, v_out, attn_out, preproj);
    proj_out_k<<<dim3(64), dim3(256), 0, stream>>>(preproj, Wp, bp, out);
  } else {
    unsigned short* k_ws = (unsigned short*)(ws);                 // 402,653,184 B
    unsigned short* q_ws = (unsigned short*)(ws + 402653184);
    unsigned short* Wt   = (unsigned short*)(ws + 404226048);
    float* preproj       = (float*)(ws + 406585344);

    prep_w<<<dim3(4608), dim3(256), 0, stream>>>(Wk, Wv, Wt);
    q_proj<<<dim3(64), dim3(256), 0, stream>>>(x, Wq, q_ws);
    gemm_kv<<<dim3(24576), dim3(256), 0, stream>>>(x, Wt, k_ws, v_out);
    attn_fused3<<<dim3(768), dim3(512), 0, stream>>>(k_ws, q_ws, v_out, attn_out, preproj);
    proj_out_k<<<dim3(64), dim3(256), 0, stream>>>(preproj, Wp, bp, out);
  }
}